// Round 3
// baseline (1855.563 us; speedup 1.0000x reference)
//
#include <hip/hip_runtime.h>
#include <hip/hip_bf16.h>

#define DEV static __device__ __forceinline__

constexpr int BB = 4;        // batches
constexpr int TT = 12;       // timesteps
constexpr int NN = 10000;    // nodes per batch
constexpr int FD = 16;       // input features (8+8)
constexpr int HD = 128;      // hidden
constexpr int NH = 4;        // attn heads
constexpr int DH = 32;       // head dim
constexpr int FF = 256;      // ffn hidden
constexpr int GO = 64;       // gat2 out
constexpr int HR = 24;       // horizon
constexpr int EE = 160000;   // edges per batch
constexpr int MM = BB * NN;  // total nodes

typedef unsigned short bvec8 __attribute__((ext_vector_type(8)));
typedef float fvec4 __attribute__((ext_vector_type(4)));

DEV float cv(float x) { return x; }
DEV float cv(__hip_bfloat16 x) { return __bfloat162float(x); }
DEV void st(float* p, float v) { *p = v; }
DEV void st(__hip_bfloat16* p, float v) { *p = __float2bfloat16(v); }
DEV float lrelu(float x) { return x >= 0.f ? x : 0.2f * x; }

DEV float b2f(unsigned short u) {
  union { unsigned int i; float f; } x; x.i = ((unsigned int)u) << 16; return x.f;
}
DEV unsigned short f2b(float f) {
  union { float f; unsigned int i; } x; x.f = f;
  unsigned int r = x.i + 0x7FFFu + ((x.i >> 16) & 1u);
  return (unsigned short)(r >> 16);
}

// ---------------- dtype detection -------------------------------------------
// fp32 reinterpreted as bf16: low halves have random exponents -> ~25% insane.
// true bf16 N(0,1): all sane. Verified by round-2 profile: fp32 -> flag=0.
__global__ void k_detect(const void* x, int* flag)
{
  const __hip_bfloat16* p = (const __hip_bfloat16*)x;
  int sane = 0;
  for (int i = 0; i < 256; ++i) {
    float v = __bfloat162float(p[i]);
    if (fabsf(v) <= 1024.f) sane++;
  }
  *flag = (sane >= 250) ? 1 : 0;  // 1 = bf16 inputs, 0 = fp32 inputs
}

// ---------------- prep: fold attention weights ------------------------------
// Mt[(h*128+c)*128 + i] = sum_d Wq[i][h*32+d] * Wk[c][h*32+d]
// Pt[j*512 + h*128+i]   = sum_d Wv[i][h*32+d] * Wo[h*32+d][j]
template<typename TI>
__global__ __launch_bounds__(256) void k_prep_mp(
    const int* __restrict__ flag, int want,
    const void* Wq_, const void* Wk_, const void* Wv_, const void* Wo_,
    unsigned short* __restrict__ Mt, unsigned short* __restrict__ Pt)
{
  if (*flag != want) return;
  const TI* Wq = (const TI*)Wq_; const TI* Wk = (const TI*)Wk_;
  const TI* Wv = (const TI*)Wv_; const TI* Wo = (const TI*)Wo_;
  int g = blockIdx.x * 256 + threadIdx.x;
  if (g < 65536) {
    int q = g >> 7, i = g & 127, h = q >> 7, c = q & 127;
    float a = 0.f;
    #pragma unroll 8
    for (int d = 0; d < 32; ++d)
      a += cv(Wq[i*HD + h*DH + d]) * cv(Wk[c*HD + h*DH + d]);
    Mt[g] = f2b(a);
  } else {
    int g2 = g - 65536, jj = g2 >> 9, q = g2 & 511, h = q >> 7, i = q & 127;
    float a = 0.f;
    #pragma unroll 8
    for (int d = 0; d < 32; ++d)
      a += cv(Wv[i*HD + h*DH + d]) * cv(Wo[(h*DH + d)*HD + jj]);
    Pt[g2] = f2b(a);
  }
}

// ---------------- prep: transpose/convert other weights ---------------------
template<typename TI>
__global__ __launch_bounds__(256) void k_prep_w(
    const int* __restrict__ flag, int want,
    const void* encW_, const void* encB_, const void* W1_, const void* fb1_,
    const void* W2_, const void* fb2_,
    const void* l1g_, const void* l1b_, const void* l2g_, const void* l2b_,
    unsigned short* __restrict__ W1t, unsigned short* __restrict__ W2t,
    float* __restrict__ encWf, float* __restrict__ encBf,
    float* __restrict__ fb1f, float* __restrict__ fb2f,
    float* __restrict__ l1gf, float* __restrict__ l1bf,
    float* __restrict__ l2gf, float* __restrict__ l2bf)
{
  if (*flag != want) return;
  const TI* encW = (const TI*)encW_; const TI* encB = (const TI*)encB_;
  const TI* W1 = (const TI*)W1_;     const TI* fb1 = (const TI*)fb1_;
  const TI* W2 = (const TI*)W2_;     const TI* fb2 = (const TI*)fb2_;
  const TI* l1g = (const TI*)l1g_;   const TI* l1b = (const TI*)l1b_;
  const TI* l2g = (const TI*)l2g_;   const TI* l2b = (const TI*)l2b_;
  int idx = blockIdx.x * 256 + threadIdx.x;   // 268*256 = 68608 exactly
  if (idx < 32768) {                           // W1t[c][i] = W1[i][c]
    int c = idx >> 7, i = idx & 127;
    W1t[idx] = f2b(cv(W1[i*FF + c]));
  } else if (idx < 65536) {                    // W2t[j][c] = W2[c][j]
    int t = idx - 32768; int jj = t >> 8, c = t & 255;
    W2t[t] = f2b(cv(W2[c*HD + jj]));
  } else if (idx < 67584) { int t = idx - 65536; encWf[t] = cv(encW[t]); }
  else if (idx < 67712)   { int t = idx - 67584; encBf[t] = cv(encB[t]); }
  else if (idx < 67968)   { int t = idx - 67712; fb1f[t] = cv(fb1[t]); }
  else if (idx < 68096)   { int t = idx - 67968; fb2f[t] = cv(fb2[t]); }
  else if (idx < 68224)   { int t = idx - 68096; l1gf[t] = cv(l1g[t]); }
  else if (idx < 68352)   { int t = idx - 68224; l1bf[t] = cv(l1b[t]); }
  else if (idx < 68480)   { int t = idx - 68352; l2gf[t] = cv(l2g[t]); }
  else                    { int t = idx - 68480; l2bf[t] = cv(l2b[t]); }
}

// ---------------- fused transformer (4 nodes/block, 2 nodes/thread) ---------
DEV void ln_pair(float v0, float v1, int tid, float* red,
                 float& mu0, float& rs0, float& mu1, float& rs1)
{
  float s0 = v0, q0 = v0*v0, s1 = v1, q1 = v1*v1;
  #pragma unroll
  for (int off = 32; off > 0; off >>= 1) {
    s0 += __shfl_xor(s0, off); q0 += __shfl_xor(q0, off);
    s1 += __shfl_xor(s1, off); q1 += __shfl_xor(q1, off);
  }
  int half = tid >> 7, wih = (tid >> 6) & 1, lane = tid & 63;
  __syncthreads();
  if (lane == 0) {
    float* p = red + half*8 + wih*4;
    p[0] = s0; p[1] = q0; p[2] = s1; p[3] = q1;
  }
  __syncthreads();
  const float* pa = red + half*8;
  float ts0 = pa[0]+pa[4], tq0 = pa[1]+pa[5];
  float ts1 = pa[2]+pa[6], tq1 = pa[3]+pa[7];
  mu0 = ts0*(1.f/128.f); float va0 = tq0*(1.f/128.f) - mu0*mu0; rs0 = rsqrtf(va0 + 1e-5f);
  mu1 = ts1*(1.f/128.f); float va1 = tq1*(1.f/128.f) - mu1*mu1; rs1 = rsqrtf(va1 + 1e-5f);
}

template<typename TI>
__global__ __launch_bounds__(256) void k_xform(
    const int* __restrict__ flag, int want,
    const void* xh_, const void* xc_,
    const unsigned short* __restrict__ Mt, const unsigned short* __restrict__ Pt,
    const unsigned short* __restrict__ W1t, const unsigned short* __restrict__ W2t,
    const float* __restrict__ encWf, const float* __restrict__ encBf,
    const float* __restrict__ fb1f, const float* __restrict__ fb2f,
    const float* __restrict__ l1gf, const float* __restrict__ l1bf,
    const float* __restrict__ l2gf, const float* __restrict__ l2bf,
    float* __restrict__ hlast)
{
  if (*flag != want) return;
  const TI* xh = (const TI*)xh_;
  const TI* xc = (const TI*)xc_;

  __shared__ unsigned short hsB[4][TT][HD];   // h as bf16
  __shared__ float us[4][512];                // u, then w
  __shared__ float scratch[4][256];           // x, then h_last fp32, then f1
  __shared__ float h1s[4][HD];
  __shared__ float lgaw[4][NH][TT];           // logits, then alpha
  __shared__ float red[16];

  const int tid = threadIdx.x;
  const int half = tid >> 7;
  const int j = tid & 127;
  const int m0 = blockIdx.x * 4;

  // --- load x (4 nodes x 12 t x 16 f) ---
  #pragma unroll
  for (int k = 0; k < 3; ++k) {
    int idx = tid + k*256;
    int nl = idx / 192, rem = idx - nl*192;
    int t = rem >> 4, f = rem & 15;
    int m = m0 + nl, b = m / NN, n = m - b*NN;
    float v = (f < 8) ? cv(xh[(((size_t)b*TT + t)*NN + n)*8 + f])
                      : cv(xc[(((size_t)b*TT + t)*NN + n)*8 + (f - 8)]);
    scratch[nl][rem] = v;
  }
  __syncthreads();

  // --- encoder: h[t] = x[t] @ encW + encB ---
  float ew[FD];
  #pragma unroll
  for (int f = 0; f < FD; ++f) ew[f] = encWf[f*HD + j];
  float eb = encBf[j];
  float h11[2];
  #pragma unroll
  for (int r = 0; r < 2; ++r) {
    int nl = half*2 + r;
    #pragma unroll
    for (int t = 0; t < TT; ++t) {
      const fvec4* xp = (const fvec4*)&scratch[nl][t*16];
      fvec4 x0 = xp[0], x1 = xp[1], x2 = xp[2], x3 = xp[3];
      float a = eb;
      a += x0[0]*ew[0]  + x0[1]*ew[1]  + x0[2]*ew[2]  + x0[3]*ew[3];
      a += x1[0]*ew[4]  + x1[1]*ew[5]  + x1[2]*ew[6]  + x1[3]*ew[7];
      a += x2[0]*ew[8]  + x2[1]*ew[9]  + x2[2]*ew[10] + x2[3]*ew[11];
      a += x3[0]*ew[12] + x3[1]*ew[13] + x3[2]*ew[14] + x3[3]*ew[15];
      hsB[nl][t][j] = f2b(a);
      if (t == TT-1) h11[r] = a;
    }
  }
  __syncthreads();                 // x fully consumed

  // stash h_last fp32 in scratch (no cvts in u-loop)
  scratch[half*2+0][j] = h11[0];
  scratch[half*2+1][j] = h11[1];
  __syncthreads();

  // --- u = h_last @ M (4 heads x 128) ---
  float ua[4][2];
  #pragma unroll
  for (int qi = 0; qi < 4; ++qi) { ua[qi][0] = 0.f; ua[qi][1] = 0.f; }
  for (int i8 = 0; i8 < 16; ++i8) {
    float hv[2][8];
    #pragma unroll
    for (int r = 0; r < 2; ++r) {
      const fvec4* hp = (const fvec4*)&scratch[half*2+r][i8*8];
      fvec4 a0 = hp[0], a1 = hp[1];
      hv[r][0]=a0[0]; hv[r][1]=a0[1]; hv[r][2]=a0[2]; hv[r][3]=a0[3];
      hv[r][4]=a1[0]; hv[r][5]=a1[1]; hv[r][6]=a1[2]; hv[r][7]=a1[3];
    }
    #pragma unroll
    for (int qi = 0; qi < 4; ++qi) {
      bvec8 wb = *(const bvec8*)&Mt[(qi*128 + j)*128 + i8*8];
      #pragma unroll
      for (int e = 0; e < 8; ++e) {
        float wf = b2f(wb[e]);
        ua[qi][0] += wf * hv[0][e];
        ua[qi][1] += wf * hv[1][e];
      }
    }
  }
  #pragma unroll
  for (int qi = 0; qi < 4; ++qi) {
    us[half*2+0][qi*128 + j] = ua[qi][0];
    us[half*2+1][qi*128 + j] = ua[qi][1];
  }
  __syncthreads();

  // --- logits: 2 nodes x 4 heads x 12 t per half (vectorized b128 reads) ---
  if (j < 96) {
    int r = j / 48, p = j - r*48, hd = p / 12, t = p - hd*12;
    int nl = half*2 + r;
    float a = 0.f;
    for (int i8 = 0; i8 < 16; ++i8) {
      bvec8 hb = *(const bvec8*)&hsB[nl][t][i8*8];
      const fvec4* up = (const fvec4*)&us[nl][hd*128 + i8*8];
      fvec4 u0 = up[0], u1 = up[1];
      a += b2f(hb[0])*u0[0] + b2f(hb[1])*u0[1] + b2f(hb[2])*u0[2] + b2f(hb[3])*u0[3]
         + b2f(hb[4])*u1[0] + b2f(hb[5])*u1[1] + b2f(hb[6])*u1[2] + b2f(hb[7])*u1[3];
    }
    lgaw[nl][hd][t] = a * 0.17677669529663687f;
  }
  __syncthreads();

  // --- softmax over t ---
  if (j < 8) {
    int r = j >> 2, hd = j & 3, nl = half*2 + r;
    float mx = -1e30f;
    #pragma unroll
    for (int t = 0; t < TT; ++t) mx = fmaxf(mx, lgaw[nl][hd][t]);
    float ex[TT], sm = 0.f;
    #pragma unroll
    for (int t = 0; t < TT; ++t) { ex[t] = expf(lgaw[nl][hd][t] - mx); sm += ex[t]; }
    float inv = 1.f / sm;
    #pragma unroll
    for (int t = 0; t < TT; ++t) lgaw[nl][hd][t] = ex[t] * inv;
  }
  __syncthreads();

  // --- w_h = sum_t alpha_ht * h_t (overwrites us) ---
  float wa[4][2];
  #pragma unroll
  for (int hd = 0; hd < 4; ++hd) { wa[hd][0] = 0.f; wa[hd][1] = 0.f; }
  #pragma unroll
  for (int r = 0; r < 2; ++r) {
    int nl = half*2 + r;
    #pragma unroll
    for (int t = 0; t < TT; ++t) {
      float hv = b2f(hsB[nl][t][j]);
      #pragma unroll
      for (int hd = 0; hd < 4; ++hd) wa[hd][r] += lgaw[nl][hd][t] * hv;
    }
  }
  __syncthreads();
  #pragma unroll
  for (int hd = 0; hd < 4; ++hd) {
    us[half*2+0][hd*128 + j] = wa[hd][0];
    us[half*2+1][hd*128 + j] = wa[hd][1];
  }
  __syncthreads();

  // --- attn-out @ Wo folded: out[j] = sum_q w[q] * Pt[j][q] ---
  float oa[2] = {0.f, 0.f};
  for (int q8 = 0; q8 < 64; ++q8) {
    bvec8 pb = *(const bvec8*)&Pt[j*512 + q8*8];
    float pf[8];
    #pragma unroll
    for (int e = 0; e < 8; ++e) pf[e] = b2f(pb[e]);
    #pragma unroll
    for (int r = 0; r < 2; ++r) {
      const fvec4* wp = (const fvec4*)&us[half*2+r][q8*8];
      fvec4 w0 = wp[0], w1 = wp[1];
      oa[r] += pf[0]*w0[0] + pf[1]*w0[1] + pf[2]*w0[2] + pf[3]*w0[3]
             + pf[4]*w1[0] + pf[5]*w1[1] + pf[6]*w1[2] + pf[7]*w1[3];
    }
  }

  // --- LN1 ---
  float mu0, rs0, mu1, rs1;
  float r1a = h11[0] + oa[0], r1b = h11[1] + oa[1];
  ln_pair(r1a, r1b, tid, red, mu0, rs0, mu1, rs1);
  float g1 = l1gf[j], b1 = l1bf[j];
  float h1a = (r1a - mu0)*rs0*g1 + b1;
  float h1b = (r1b - mu1)*rs1*g1 + b1;
  h1s[half*2+0][j] = h1a;
  h1s[half*2+1][j] = h1b;
  __syncthreads();

  // --- FFN layer 1 (channels j and j+128) ---
  float fa[2][2] = {{0.f,0.f},{0.f,0.f}};
  for (int i8 = 0; i8 < 16; ++i8) {
    float hv[2][8];
    #pragma unroll
    for (int r = 0; r < 2; ++r) {
      const fvec4* hp = (const fvec4*)&h1s[half*2+r][i8*8];
      fvec4 a0 = hp[0], a1 = hp[1];
      hv[r][0]=a0[0]; hv[r][1]=a0[1]; hv[r][2]=a0[2]; hv[r][3]=a0[3];
      hv[r][4]=a1[0]; hv[r][5]=a1[1]; hv[r][6]=a1[2]; hv[r][7]=a1[3];
    }
    bvec8 w0b = *(const bvec8*)&W1t[j*128 + i8*8];
    bvec8 w1b = *(const bvec8*)&W1t[(j+128)*128 + i8*8];
    #pragma unroll
    for (int e = 0; e < 8; ++e) {
      float w0f = b2f(w0b[e]), w1f = b2f(w1b[e]);
      fa[0][0] += w0f*hv[0][e]; fa[0][1] += w0f*hv[1][e];
      fa[1][0] += w1f*hv[0][e]; fa[1][1] += w1f*hv[1][e];
    }
  }
  float bv1 = fb1f[j], bv2 = fb1f[j+128];
  scratch[half*2+0][j]     = fmaxf(fa[0][0] + bv1, 0.f);
  scratch[half*2+1][j]     = fmaxf(fa[0][1] + bv1, 0.f);
  scratch[half*2+0][j+128] = fmaxf(fa[1][0] + bv2, 0.f);
  scratch[half*2+1][j+128] = fmaxf(fa[1][1] + bv2, 0.f);
  __syncthreads();

  // --- FFN layer 2 ---
  float f2a[2] = {0.f, 0.f};
  for (int c8 = 0; c8 < 32; ++c8) {
    bvec8 wb = *(const bvec8*)&W2t[j*256 + c8*8];
    float wf[8];
    #pragma unroll
    for (int e = 0; e < 8; ++e) wf[e] = b2f(wb[e]);
    #pragma unroll
    for (int r = 0; r < 2; ++r) {
      const fvec4* fp = (const fvec4*)&scratch[half*2+r][c8*8];
      fvec4 f0 = fp[0], f1 = fp[1];
      f2a[r] += wf[0]*f0[0] + wf[1]*f0[1] + wf[2]*f0[2] + wf[3]*f0[3]
              + wf[4]*f1[0] + wf[5]*f1[1] + wf[6]*f1[2] + wf[7]*f1[3];
    }
  }
  float fb2v = fb2f[j];
  float r2a = h1a + fb2v + f2a[0];
  float r2b = h1b + fb2v + f2a[1];
  ln_pair(r2a, r2b, tid, red, mu0, rs0, mu1, rs1);
  float g2 = l2gf[j], b2v = l2bf[j];
  hlast[(size_t)(m0 + half*2 + 0)*HD + j] = (r2a - mu0)*rs0*g2 + b2v;
  hlast[(size_t)(m0 + half*2 + 1)*HD + j] = (r2b - mu1)*rs1*g2 + b2v;
}

// ---------------- GAT1 ------------------------------------------------------
template<typename TI>
__global__ __launch_bounds__(128) void k_gat1_pre(
    const int* __restrict__ flag, int want,
    const float* __restrict__ hlast, const void* gW_, const void* asr_, const void* adr_,
    float* __restrict__ xl, float* __restrict__ s1, float* __restrict__ d1,
    float* __restrict__ acc, float* __restrict__ den)
{
  if (*flag != want) return;
  const TI* gW  = (const TI*)gW_;
  const TI* asr = (const TI*)asr_;
  const TI* adr = (const TI*)adr_;
  __shared__ float hrow[HD];
  int j = threadIdx.x, m = blockIdx.x;
  hrow[j] = hlast[(size_t)m*HD + j];
  __syncthreads();
  float a = 0.f;
  for (int i = 0; i < HD; ++i) a += hrow[i] * cv(gW[i*HD + j]);
  xl[(size_t)m*HD + j] = a;
  acc[(size_t)m*HD + j] = 0.f;
  float pa = a * cv(asr[j]);
  float pb = a * cv(adr[j]);
  #pragma unroll
  for (int off = 16; off > 0; off >>= 1) { pa += __shfl_xor(pa, off); pb += __shfl_xor(pb, off); }
  if ((j & 31) == 0) {
    int h = j >> 5;
    s1[m*NH + h] = pa;
    d1[m*NH + h] = pb;
    den[m*NH + h] = 0.f;
  }
}

__global__ __launch_bounds__(256) void k_gat1_edge(
    const int* __restrict__ e0, const int* __restrict__ e1,
    const float* __restrict__ s1, const float* __restrict__ d1,
    const float* __restrict__ xl, float* __restrict__ acc, float* __restrict__ den)
{
  int g = blockIdx.x * 8 + (threadIdx.x >> 5);
  int lane = threadIdx.x & 31;
  int h = g & 3, e = g >> 2;
  int b = e / EE, i = e - b * EE;
  int src = e0[i] + b * NN;
  int dst = e1[i] + b * NN;
  float eev = expf(lrelu(s1[src*NH + h] + d1[dst*NH + h]));
  if (lane == 0) atomicAdd(&den[dst*NH + h], eev);
  atomicAdd(&acc[(size_t)dst*HD + h*DH + lane],
            eev * xl[(size_t)src*HD + h*DH + lane]);
}

template<typename TI>
__global__ __launch_bounds__(128) void k_gat1_fin(
    const int* __restrict__ flag, int want,
    const float* __restrict__ xl, const float* __restrict__ s1, const float* __restrict__ d1,
    const float* __restrict__ acc, const float* __restrict__ den,
    const void* gb_, float* __restrict__ g1o)
{
  if (*flag != want) return;
  const TI* gb = (const TI*)gb_;
  int j = threadIdx.x, m = blockIdx.x, h = j >> 5;
  float es = expf(lrelu(s1[m*NH + h] + d1[m*NH + h]));
  float num = acc[(size_t)m*HD + j] + es * xl[(size_t)m*HD + j];
  float dn = den[m*NH + h] + es + 1e-16f;
  float v = num / dn + cv(gb[j]);
  g1o[(size_t)m*HD + j] = v > 0.f ? v : expm1f(v);
}

// ---------------- GAT2 ------------------------------------------------------
template<typename TI>
__global__ __launch_bounds__(64) void k_gat2_pre(
    const int* __restrict__ flag, int want,
    const float* __restrict__ g1o, const void* gW_, const void* asr_, const void* adr_,
    float* __restrict__ xl2, float* __restrict__ s2, float* __restrict__ d2,
    float* __restrict__ acc2, float* __restrict__ den2)
{
  if (*flag != want) return;
  const TI* gW  = (const TI*)gW_;
  const TI* asr = (const TI*)asr_;
  const TI* adr = (const TI*)adr_;
  __shared__ float grow[HD];
  int j = threadIdx.x, m = blockIdx.x;
  grow[j]      = g1o[(size_t)m*HD + j];
  grow[j + 64] = g1o[(size_t)m*HD + j + 64];
  __syncthreads();
  float a = 0.f;
  for (int i = 0; i < HD; ++i) a += grow[i] * cv(gW[i*GO + j]);
  xl2[(size_t)m*GO + j] = a;
  acc2[(size_t)m*GO + j] = 0.f;
  float pa = a * cv(asr[j]);
  float pb = a * cv(adr[j]);
  #pragma unroll
  for (int off = 32; off > 0; off >>= 1) { pa += __shfl_xor(pa, off); pb += __shfl_xor(pb, off); }
  if (j == 0) { s2[m] = pa; d2[m] = pb; den2[m] = 0.f; }
}

__global__ __launch_bounds__(256) void k_gat2_edge(
    const int* __restrict__ e0, const int* __restrict__ e1,
    const float* __restrict__ s2, const float* __restrict__ d2,
    const float* __restrict__ xl2, float* __restrict__ acc2, float* __restrict__ den2)
{
  int e = blockIdx.x * 4 + (threadIdx.x >> 6);
  int lane = threadIdx.x & 63;
  int b = e / EE, i = e - b * EE;
  int src = e0[i] + b * NN;
  int dst = e1[i] + b * NN;
  float eev = expf(lrelu(s2[src] + d2[dst]));
  if (lane == 0) atomicAdd(&den2[dst], eev);
  atomicAdd(&acc2[(size_t)dst*GO + lane], eev * xl2[(size_t)src*GO + lane]);
}

template<typename TI, typename TO>
__global__ __launch_bounds__(64) void k_gat2_fin(
    const int* __restrict__ flag, int want,
    const float* __restrict__ xl2, const float* __restrict__ s2, const float* __restrict__ d2,
    const float* __restrict__ acc2, const float* __restrict__ den2,
    const void* gb_, const void* oW_, const void* ob_, void* y_)
{
  if (*flag != want) return;
  const TI* gb = (const TI*)gb_;
  const TI* oW = (const TI*)oW_;
  const TI* ob = (const TI*)ob_;
  TO* y = (TO*)y_;
  __shared__ float g2s[GO];
  int j = threadIdx.x, m = blockIdx.x;
  float es = expf(lrelu(s2[m] + d2[m]));
  float num = acc2[(size_t)m*GO + j] + es * xl2[(size_t)m*GO + j];
  float dn = den2[m] + es + 1e-16f;
  g2s[j] = num / dn + cv(gb[j]);
  __syncthreads();
  if (j < HR) {
    float a = cv(ob[j]);
    #pragma unroll
    for (int o2 = 0; o2 < GO; ++o2) a += g2s[o2] * cv(oW[o2*HR + j]);
    int b = m / NN, n = m - b * NN;
    st(&y[((size_t)b*HR + j)*NN + n], a);
  }
}

// ---------------- launch ----------------------------------------------------
extern "C" void kernel_launch(void* const* d_in, const int* in_sizes, int n_in,
                              void* d_out, int out_size, void* d_ws, size_t ws_size,
                              hipStream_t stream)
{
  const int* ei = (const int*)d_in[2];
  const int* e0 = ei;
  const int* e1 = ei + EE;

  float* ws    = (float*)d_ws;
  float* hlast = ws;                  // 40000*128
  float* xl1   = ws + 5120000;        // 40000*128
  float* acc1  = ws + 10240000;       // 40000*128
  float* s1    = ws + 15360000;       // 40000*4
  float* d1    = ws + 15520000;       // 40000*4
  float* den1  = ws + 15680000;       // 40000*4
  int*   flag  = (int*)(ws + 15840000);

  // Weight-prep buffers OVERLAP acc1: Mt/Pt/... live [prep -> k_xform end],
  // acc1 lives [gat1_pre -> end]. Disjoint lifetimes; keeps ws high-water
  // at the proven round-1 footprint.
  unsigned short* Mt  = (unsigned short*)acc1;             // 512*128 bf16
  unsigned short* Pt  = Mt + 65536;                        // 128*512 bf16
  unsigned short* W1t = Mt + 131072;                       // 256*128 bf16
  unsigned short* W2t = Mt + 163840;                       // 128*256 bf16
  float* encWf = (float*)(Mt + 196608);                    // 16*128
  float* encBf = encWf + 2048;
  float* fb1f  = encBf + 128;
  float* fb2f  = fb1f + 256;
  float* l1gf  = fb2f + 128;
  float* l1bf  = l1gf + 128;
  float* l2gf  = l1bf + 128;
  float* l2bf  = l2gf + 128;

  // phase-2 aliases (lifetimes disjoint)
  float* g1o  = hlast;
  float* xl2  = xl1;
  float* acc2 = acc1;
  float* s2 = s1; float* d2 = d1; float* den2 = den1;

  k_detect<<<1, 1, 0, stream>>>(d_in[0], flag);

  k_prep_mp<float><<<512, 256, 0, stream>>>(flag, 0,
      d_in[5], d_in[6], d_in[7], d_in[8], Mt, Pt);
  k_prep_mp<__hip_bfloat16><<<512, 256, 0, stream>>>(flag, 1,
      d_in[5], d_in[6], d_in[7], d_in[8], Mt, Pt);
  k_prep_w<float><<<268, 256, 0, stream>>>(flag, 0,
      d_in[3], d_in[4], d_in[11], d_in[12], d_in[13], d_in[14],
      d_in[9], d_in[10], d_in[15], d_in[16],
      W1t, W2t, encWf, encBf, fb1f, fb2f, l1gf, l1bf, l2gf, l2bf);
  k_prep_w<__hip_bfloat16><<<268, 256, 0, stream>>>(flag, 1,
      d_in[3], d_in[4], d_in[11], d_in[12], d_in[13], d_in[14],
      d_in[9], d_in[10], d_in[15], d_in[16],
      W1t, W2t, encWf, encBf, fb1f, fb2f, l1gf, l1bf, l2gf, l2bf);

  k_xform<float><<<MM/4, 256, 0, stream>>>(flag, 0,
      d_in[0], d_in[1], Mt, Pt, W1t, W2t,
      encWf, encBf, fb1f, fb2f, l1gf, l1bf, l2gf, l2bf, hlast);
  k_xform<__hip_bfloat16><<<MM/4, 256, 0, stream>>>(flag, 1,
      d_in[0], d_in[1], Mt, Pt, W1t, W2t,
      encWf, encBf, fb1f, fb2f, l1gf, l1bf, l2gf, l2bf, hlast);

  k_gat1_pre<float><<<MM, 128, 0, stream>>>(flag, 0, hlast,
      d_in[17], d_in[18], d_in[19], xl1, s1, d1, acc1, den1);
  k_gat1_pre<__hip_bfloat16><<<MM, 128, 0, stream>>>(flag, 1, hlast,
      d_in[17], d_in[18], d_in[19], xl1, s1, d1, acc1, den1);

  k_gat1_edge<<<(BB*EE*NH)/8, 256, 0, stream>>>(e0, e1, s1, d1, xl1, acc1, den1);

  k_gat1_fin<float><<<MM, 128, 0, stream>>>(flag, 0, xl1, s1, d1, acc1, den1, d_in[20], g1o);
  k_gat1_fin<__hip_bfloat16><<<MM, 128, 0, stream>>>(flag, 1, xl1, s1, d1, acc1, den1, d_in[20], g1o);

  k_gat2_pre<float><<<MM, 64, 0, stream>>>(flag, 0, g1o,
      d_in[21], d_in[22], d_in[23], xl2, s2, d2, acc2, den2);
  k_gat2_pre<__hip_bfloat16><<<MM, 64, 0, stream>>>(flag, 1, g1o,
      d_in[21], d_in[22], d_in[23], xl2, s2, d2, acc2, den2);

  k_gat2_edge<<<(BB*EE)/4, 256, 0, stream>>>(e0, e1, s2, d2, xl2, acc2, den2);

  k_gat2_fin<float, float><<<MM, 64, 0, stream>>>(flag, 0,
      xl2, s2, d2, acc2, den2, d_in[24], d_in[25], d_in[26], d_out);
  k_gat2_fin<__hip_bfloat16, __hip_bfloat16><<<MM, 64, 0, stream>>>(flag, 1,
      xl2, s2, d2, acc2, den2, d_in[24], d_in[25], d_in[26], d_out);
}

// Round 4
// 1210.828 us; speedup vs baseline: 1.5325x; 1.5325x over previous
//
#include <hip/hip_runtime.h>
#include <hip/hip_bf16.h>

#define DEV static __device__ __forceinline__

constexpr int BB = 4;        // batches
constexpr int TT = 12;       // timesteps
constexpr int NN = 10000;    // nodes per batch
constexpr int FD = 16;       // input features (8+8)
constexpr int HD = 128;      // hidden
constexpr int NH = 4;        // attn heads
constexpr int DH = 32;       // head dim
constexpr int FF = 256;      // ffn hidden
constexpr int GO = 64;       // gat2 out
constexpr int HR = 24;       // horizon
constexpr int EE = 160000;   // edges per batch
constexpr int MM = BB * NN;  // total nodes

typedef unsigned short bvec8 __attribute__((ext_vector_type(8)));
typedef float fvec4 __attribute__((ext_vector_type(4)));

DEV float cv(float x) { return x; }
DEV float cv(__hip_bfloat16 x) { return __bfloat162float(x); }
DEV void st(float* p, float v) { *p = v; }
DEV void st(__hip_bfloat16* p, float v) { *p = __float2bfloat16(v); }
DEV float lrelu(float x) { return x >= 0.f ? x : 0.2f * x; }

DEV float b2f(unsigned short u) {
  union { unsigned int i; float f; } x; x.i = ((unsigned int)u) << 16; return x.f;
}
DEV unsigned short f2b(float f) {
  union { float f; unsigned int i; } x; x.f = f;
  unsigned int r = x.i + 0x7FFFu + ((x.i >> 16) & 1u);
  return (unsigned short)(r >> 16);
}
// unpack a uint holding two bf16 (lo = element 0, hi = element 1)
DEV void up2(unsigned int u, float& lo, float& hi) {
  union { unsigned int i; float f; } a, b;
  a.i = u << 16; b.i = u & 0xFFFF0000u;
  lo = a.f; hi = b.f;
}

// ---------------- dtype detection (profile-verified: fp32 -> flag=0) --------
__global__ void k_detect(const void* x, int* flag)
{
  const __hip_bfloat16* p = (const __hip_bfloat16*)x;
  int sane = 0;
  for (int i = 0; i < 256; ++i) {
    float v = __bfloat162float(p[i]);
    if (fabsf(v) <= 1024.f) sane++;
  }
  *flag = (sane >= 250) ? 1 : 0;
}

// ---------------- prep: fold + re-layout ALL transformer weights ------------
// Coalesced-GEMV layouts (lane = output column n):
//   Mu [i][512]          : Mu[i*512 + h*128+c] = sum_d Wq[i][h*32+d]*Wk[c][h*32+d]
//   Pw [q/4][128][4]     : Pw[(q>>2)*512 + j*4 + (q&3)] = sum_d Wv[i][h*32+d]*Wo[h*32+d][j], q=h*128+i
//   W1n [i][256]         : direct bf16 cast of W1 (already [k][n])
//   W2p [c/4][128][4]    : W2p[(c>>2)*512 + j*4 + (c&3)] = W2[c][j]
template<typename TI>
__global__ __launch_bounds__(256) void k_prep(
    const int* __restrict__ flag, int want,
    const void* Wq_, const void* Wk_, const void* Wv_, const void* Wo_,
    const void* encW_, const void* encB_, const void* W1_, const void* fb1_,
    const void* W2_, const void* fb2_,
    const void* l1g_, const void* l1b_, const void* l2g_, const void* l2b_,
    unsigned short* __restrict__ Mu, unsigned short* __restrict__ Pw,
    unsigned short* __restrict__ W1n, unsigned short* __restrict__ W2p,
    float* __restrict__ encWf, float* __restrict__ encBf,
    float* __restrict__ fb1f, float* __restrict__ fb2f,
    float* __restrict__ l1gf, float* __restrict__ l1bf,
    float* __restrict__ l2gf, float* __restrict__ l2bf)
{
  if (*flag != want) return;
  const TI* Wq = (const TI*)Wq_;   const TI* Wk = (const TI*)Wk_;
  const TI* Wv = (const TI*)Wv_;   const TI* Wo = (const TI*)Wo_;
  const TI* encW = (const TI*)encW_; const TI* encB = (const TI*)encB_;
  const TI* W1 = (const TI*)W1_;   const TI* fb1 = (const TI*)fb1_;
  const TI* W2 = (const TI*)W2_;   const TI* fb2 = (const TI*)fb2_;
  const TI* l1g = (const TI*)l1g_; const TI* l1b = (const TI*)l1b_;
  const TI* l2g = (const TI*)l2g_; const TI* l2b = (const TI*)l2b_;
  int idx = blockIdx.x * 256 + threadIdx.x;      // 780*256 = 199680 exactly
  if (idx < 65536) {
    int i = idx >> 9, q = idx & 511, h = q >> 7, c = q & 127;
    float a = 0.f;
    #pragma unroll 8
    for (int d = 0; d < DH; ++d)
      a += cv(Wq[i*HD + h*DH + d]) * cv(Wk[c*HD + h*DH + d]);
    Mu[idx] = f2b(a);
  } else if (idx < 131072) {
    int g = idx - 65536;
    int q4 = g >> 9, j = (g >> 2) & 127, qr = g & 3;
    int q = q4*4 + qr, h = q >> 7, i = q & 127;
    float a = 0.f;
    #pragma unroll 8
    for (int d = 0; d < DH; ++d)
      a += cv(Wv[i*HD + h*DH + d]) * cv(Wo[(h*DH + d)*HD + j]);
    Pw[g] = f2b(a);
  } else if (idx < 163840) {
    int g = idx - 131072;                         // [i][c] direct
    W1n[g] = f2b(cv(W1[g]));
  } else if (idx < 196608) {
    int g = idx - 163840;
    int c4 = g >> 9, j = (g >> 2) & 127, cr = g & 3;
    int c = c4*4 + cr;
    W2p[g] = f2b(cv(W2[c*HD + j]));
  } else if (idx < 198656) { int t = idx - 196608; encWf[t] = cv(encW[t]); }
  else if (idx < 198784)   { int t = idx - 198656; encBf[t] = cv(encB[t]); }
  else if (idx < 199040)   { int t = idx - 198784; fb1f[t] = cv(fb1[t]); }
  else if (idx < 199168)   { int t = idx - 199040; fb2f[t] = cv(fb2[t]); }
  else if (idx < 199296)   { int t = idx - 199168; l1gf[t] = cv(l1g[t]); }
  else if (idx < 199424)   { int t = idx - 199296; l1bf[t] = cv(l1b[t]); }
  else if (idx < 199552)   { int t = idx - 199424; l2gf[t] = cv(l2g[t]); }
  else                     { int t = idx - 199552; l2bf[t] = cv(l2b[t]); }
}

// ---------------- fused transformer (4 nodes/block, 2 nodes/thread) ---------
DEV void ln_pair(float v0, float v1, int tid, float* red,
                 float& mu0, float& rs0, float& mu1, float& rs1)
{
  float s0 = v0, q0 = v0*v0, s1 = v1, q1 = v1*v1;
  #pragma unroll
  for (int off = 32; off > 0; off >>= 1) {
    s0 += __shfl_xor(s0, off); q0 += __shfl_xor(q0, off);
    s1 += __shfl_xor(s1, off); q1 += __shfl_xor(q1, off);
  }
  int half = tid >> 7, wih = (tid >> 6) & 1, lane = tid & 63;
  __syncthreads();
  if (lane == 0) {
    float* p = red + half*8 + wih*4;
    p[0] = s0; p[1] = q0; p[2] = s1; p[3] = q1;
  }
  __syncthreads();
  const float* pa = red + half*8;
  float ts0 = pa[0]+pa[4], tq0 = pa[1]+pa[5];
  float ts1 = pa[2]+pa[6], tq1 = pa[3]+pa[7];
  mu0 = ts0*(1.f/128.f); float va0 = tq0*(1.f/128.f) - mu0*mu0; rs0 = rsqrtf(va0 + 1e-5f);
  mu1 = ts1*(1.f/128.f); float va1 = tq1*(1.f/128.f) - mu1*mu1; rs1 = rsqrtf(va1 + 1e-5f);
}

template<typename TI>
__global__ __launch_bounds__(256) void k_xform(
    const int* __restrict__ flag, int want,
    const void* xh_, const void* xc_,
    const unsigned short* __restrict__ Mu, const unsigned short* __restrict__ Pw,
    const unsigned short* __restrict__ W1n, const unsigned short* __restrict__ W2p,
    const float* __restrict__ encWf, const float* __restrict__ encBf,
    const float* __restrict__ fb1f, const float* __restrict__ fb2f,
    const float* __restrict__ l1gf, const float* __restrict__ l1bf,
    const float* __restrict__ l2gf, const float* __restrict__ l2bf,
    float* __restrict__ hlast)
{
  if (*flag != want) return;
  const TI* xh = (const TI*)xh_;
  const TI* xc = (const TI*)xc_;

  __shared__ unsigned short hsB[4][TT][136];  // h bf16, rows padded (+8) for banks
  __shared__ float us[4][NH][136];            // u then w, per-head padded rows
  __shared__ float scratch[4][256];           // x -> h_last stash -> f1
  __shared__ float h1s[4][HD];
  __shared__ float lgaw[4][NH][TT];           // logits then alpha
  __shared__ float red[16];

  const int tid = threadIdx.x;
  const int half = tid >> 7;
  const int j = tid & 127;
  const int m0 = blockIdx.x * 4;

  // --- load x (4 nodes x 12 t x 16 f) ---
  #pragma unroll
  for (int k = 0; k < 3; ++k) {
    int idx = tid + k*256;
    int nl = idx / 192, rem = idx - nl*192;
    int t = rem >> 4, f = rem & 15;
    int m = m0 + nl, b = m / NN, n = m - b*NN;
    float v = (f < 8) ? cv(xh[(((size_t)b*TT + t)*NN + n)*8 + f])
                      : cv(xc[(((size_t)b*TT + t)*NN + n)*8 + (f - 8)]);
    scratch[nl][rem] = v;
  }
  __syncthreads();

  // --- encoder: h[t] = x[t] @ encW + encB (encW lane-coalesced) ---
  float ew[FD];
  #pragma unroll
  for (int f = 0; f < FD; ++f) ew[f] = encWf[f*HD + j];
  float eb = encBf[j];
  float h11[2];
  #pragma unroll
  for (int r = 0; r < 2; ++r) {
    int nl = half*2 + r;
    #pragma unroll
    for (int t = 0; t < TT; ++t) {
      const fvec4* xp = (const fvec4*)&scratch[nl][t*16];
      fvec4 x0 = xp[0], x1 = xp[1], x2 = xp[2], x3 = xp[3];
      float a = eb;
      a += x0[0]*ew[0]  + x0[1]*ew[1]  + x0[2]*ew[2]  + x0[3]*ew[3];
      a += x1[0]*ew[4]  + x1[1]*ew[5]  + x1[2]*ew[6]  + x1[3]*ew[7];
      a += x2[0]*ew[8]  + x2[1]*ew[9]  + x2[2]*ew[10] + x2[3]*ew[11];
      a += x3[0]*ew[12] + x3[1]*ew[13] + x3[2]*ew[14] + x3[3]*ew[15];
      hsB[nl][t][j] = f2b(a);
      if (t == TT-1) h11[r] = a;
    }
  }
  __syncthreads();                 // x fully consumed

  // stash h_last fp32 in scratch cols 0..127
  scratch[half*2+0][j] = h11[0];
  scratch[half*2+1][j] = h11[1];
  __syncthreads();

  // --- u = h_last @ Mu  (thread owns n = 4j..4j+3; coalesced dwordx2) ---
  float ua[2][4] = {{0.f,0.f,0.f,0.f},{0.f,0.f,0.f,0.f}};
  const uint2* Mu2 = (const uint2*)Mu;         // row = 128 uint2
  for (int i4 = 0; i4 < 32; ++i4) {
    fvec4 ha = *(const fvec4*)&scratch[half*2+0][i4*4];
    fvec4 hb = *(const fvec4*)&scratch[half*2+1][i4*4];
    #pragma unroll
    for (int e = 0; e < 4; ++e) {
      uint2 w = Mu2[(i4*4+e)*128 + j];
      float w0,w1,w2,w3; up2(w.x,w0,w1); up2(w.y,w2,w3);
      float hva = ha[e], hvb = hb[e];
      ua[0][0] += w0*hva; ua[0][1] += w1*hva; ua[0][2] += w2*hva; ua[0][3] += w3*hva;
      ua[1][0] += w0*hvb; ua[1][1] += w1*hvb; ua[1][2] += w2*hvb; ua[1][3] += w3*hvb;
    }
  }
  {
    int hd = j >> 5, col = (j & 31) * 4;       // n=4j -> head, column
    fvec4 v0 = {ua[0][0], ua[0][1], ua[0][2], ua[0][3]};
    fvec4 v1 = {ua[1][0], ua[1][1], ua[1][2], ua[1][3]};
    *(fvec4*)&us[half*2+0][hd][col] = v0;
    *(fvec4*)&us[half*2+1][hd][col] = v1;
  }
  __syncthreads();

  // --- logits: 2 nodes x 4 heads x 12 t per half ---
  if (j < 96) {
    int r = j / 48, p = j - r*48, hd = p / 12, t = p - hd*12;
    int nl = half*2 + r;
    float a = 0.f;
    for (int i8 = 0; i8 < 16; ++i8) {
      bvec8 hb8 = *(const bvec8*)&hsB[nl][t][i8*8];
      const fvec4* up = (const fvec4*)&us[nl][hd][i8*8];
      fvec4 u0 = up[0], u1 = up[1];
      a += b2f(hb8[0])*u0[0] + b2f(hb8[1])*u0[1] + b2f(hb8[2])*u0[2] + b2f(hb8[3])*u0[3]
         + b2f(hb8[4])*u1[0] + b2f(hb8[5])*u1[1] + b2f(hb8[6])*u1[2] + b2f(hb8[7])*u1[3];
    }
    lgaw[nl][hd][t] = a * 0.17677669529663687f;
  }
  __syncthreads();

  // --- softmax over t ---
  if (j < 8) {
    int r = j >> 2, hd = j & 3, nl = half*2 + r;
    float mx = -1e30f;
    #pragma unroll
    for (int t = 0; t < TT; ++t) mx = fmaxf(mx, lgaw[nl][hd][t]);
    float ex[TT], sm = 0.f;
    #pragma unroll
    for (int t = 0; t < TT; ++t) { ex[t] = expf(lgaw[nl][hd][t] - mx); sm += ex[t]; }
    float inv = 1.f / sm;
    #pragma unroll
    for (int t = 0; t < TT; ++t) lgaw[nl][hd][t] = ex[t] * inv;
  }
  __syncthreads();

  // --- w_h = sum_t alpha_ht * h_t (overwrites us after sync) ---
  float wa[NH][2];
  #pragma unroll
  for (int hd = 0; hd < NH; ++hd) { wa[hd][0] = 0.f; wa[hd][1] = 0.f; }
  #pragma unroll
  for (int r = 0; r < 2; ++r) {
    int nl = half*2 + r;
    #pragma unroll
    for (int t = 0; t < TT; ++t) {
      float hv = b2f(hsB[nl][t][j]);
      #pragma unroll
      for (int hd = 0; hd < NH; ++hd) wa[hd][r] += lgaw[nl][hd][t] * hv;
    }
  }
  __syncthreads();   // all logits-phase reads of us complete
  #pragma unroll
  for (int hd = 0; hd < NH; ++hd) {
    us[half*2+0][hd][j] = wa[hd][0];
    us[half*2+1][hd][j] = wa[hd][1];
  }
  __syncthreads();

  // --- attn-out @ Wo folded: oa[j] = sum_q w[q]*P[q][j] (k-packed-4) ---
  float oa[2] = {0.f, 0.f};
  const uint2* Pw2 = (const uint2*)Pw;
  for (int q4 = 0; q4 < 128; ++q4) {
    fvec4 wqa = *(const fvec4*)&us[half*2+0][q4>>5][(q4&31)*4];
    fvec4 wqb = *(const fvec4*)&us[half*2+1][q4>>5][(q4&31)*4];
    uint2 pw = Pw2[q4*128 + j];
    float p0,p1,p2,p3; up2(pw.x,p0,p1); up2(pw.y,p2,p3);
    oa[0] += p0*wqa[0] + p1*wqa[1] + p2*wqa[2] + p3*wqa[3];
    oa[1] += p0*wqb[0] + p1*wqb[1] + p2*wqb[2] + p3*wqb[3];
  }

  // --- LN1 ---
  float mu0, rs0, mu1, rs1;
  float r1a = h11[0] + oa[0], r1b = h11[1] + oa[1];
  ln_pair(r1a, r1b, tid, red, mu0, rs0, mu1, rs1);
  float g1 = l1gf[j], b1 = l1bf[j];
  float h1a = (r1a - mu0)*rs0*g1 + b1;
  float h1b = (r1b - mu1)*rs1*g1 + b1;
  h1s[half*2+0][j] = h1a;
  h1s[half*2+1][j] = h1b;
  __syncthreads();

  // --- FFN layer 1: thread owns c = 2j, 2j+1 (coalesced dword) ---
  float fa[2][2] = {{0.f,0.f},{0.f,0.f}};     // [cpair][r]
  const unsigned int* W1u = (const unsigned int*)W1n;  // row = 128 uints
  for (int i4 = 0; i4 < 32; ++i4) {
    fvec4 ha = *(const fvec4*)&h1s[half*2+0][i4*4];
    fvec4 hb = *(const fvec4*)&h1s[half*2+1][i4*4];
    #pragma unroll
    for (int e = 0; e < 4; ++e) {
      unsigned int w = W1u[(i4*4+e)*128 + j];
      float w0,w1; up2(w,w0,w1);
      float hva = ha[e], hvb = hb[e];
      fa[0][0] += w0*hva; fa[0][1] += w0*hvb;
      fa[1][0] += w1*hva; fa[1][1] += w1*hvb;
    }
  }
  float bva = fb1f[2*j], bvb = fb1f[2*j+1];
  scratch[half*2+0][2*j]   = fmaxf(fa[0][0] + bva, 0.f);
  scratch[half*2+1][2*j]   = fmaxf(fa[0][1] + bva, 0.f);
  scratch[half*2+0][2*j+1] = fmaxf(fa[1][0] + bvb, 0.f);
  scratch[half*2+1][2*j+1] = fmaxf(fa[1][1] + bvb, 0.f);
  __syncthreads();

  // --- FFN layer 2: k-packed-4, thread owns n = j ---
  float f2a[2] = {0.f, 0.f};
  const uint2* W2u2 = (const uint2*)W2p;
  for (int c4 = 0; c4 < 64; ++c4) {
    fvec4 fva = *(const fvec4*)&scratch[half*2+0][c4*4];
    fvec4 fvb = *(const fvec4*)&scratch[half*2+1][c4*4];
    uint2 w = W2u2[c4*128 + j];
    float w0,w1,w2,w3; up2(w.x,w0,w1); up2(w.y,w2,w3);
    f2a[0] += w0*fva[0] + w1*fva[1] + w2*fva[2] + w3*fva[3];
    f2a[1] += w0*fvb[0] + w1*fvb[1] + w2*fvb[2] + w3*fvb[3];
  }
  float fb2v = fb2f[j];
  float r2a = h1a + fb2v + f2a[0];
  float r2b = h1b + fb2v + f2a[1];
  ln_pair(r2a, r2b, tid, red, mu0, rs0, mu1, rs1);
  float g2 = l2gf[j], b2v = l2bf[j];
  hlast[(size_t)(m0 + half*2 + 0)*HD + j] = (r2a - mu0)*rs0*g2 + b2v;
  hlast[(size_t)(m0 + half*2 + 1)*HD + j] = (r2b - mu1)*rs1*g2 + b2v;
}

// ---------------- GAT1 ------------------------------------------------------
template<typename TI>
__global__ __launch_bounds__(128) void k_gat1_pre(
    const int* __restrict__ flag, int want,
    const float* __restrict__ hlast, const void* gW_, const void* asr_, const void* adr_,
    float* __restrict__ xl, float* __restrict__ s1, float* __restrict__ d1,
    float* __restrict__ acc, float* __restrict__ den)
{
  if (*flag != want) return;
  const TI* gW  = (const TI*)gW_;
  const TI* asr = (const TI*)asr_;
  const TI* adr = (const TI*)adr_;
  __shared__ float hrow[HD];
  int j = threadIdx.x, m = blockIdx.x;
  hrow[j] = hlast[(size_t)m*HD + j];
  __syncthreads();
  float a = 0.f;
  for (int i = 0; i < HD; ++i) a += hrow[i] * cv(gW[i*HD + j]);
  xl[(size_t)m*HD + j] = a;
  acc[(size_t)m*HD + j] = 0.f;
  float pa = a * cv(asr[j]);
  float pb = a * cv(adr[j]);
  #pragma unroll
  for (int off = 16; off > 0; off >>= 1) { pa += __shfl_xor(pa, off); pb += __shfl_xor(pb, off); }
  if ((j & 31) == 0) {
    int h = j >> 5;
    s1[m*NH + h] = pa;
    d1[m*NH + h] = pb;
    den[m*NH + h] = 0.f;
  }
}

__global__ __launch_bounds__(256) void k_gat1_edge(
    const int* __restrict__ e0, const int* __restrict__ e1,
    const float* __restrict__ s1, const float* __restrict__ d1,
    const float* __restrict__ xl, float* __restrict__ acc, float* __restrict__ den)
{
  int g = blockIdx.x * 8 + (threadIdx.x >> 5);
  int lane = threadIdx.x & 31;
  int h = g & 3, e = g >> 2;
  int b = e / EE, i = e - b * EE;
  int src = e0[i] + b * NN;
  int dst = e1[i] + b * NN;
  float eev = expf(lrelu(s1[src*NH + h] + d1[dst*NH + h]));
  if (lane == 0) atomicAdd(&den[dst*NH + h], eev);
  atomicAdd(&acc[(size_t)dst*HD + h*DH + lane],
            eev * xl[(size_t)src*HD + h*DH + lane]);
}

template<typename TI>
__global__ __launch_bounds__(128) void k_gat1_fin(
    const int* __restrict__ flag, int want,
    const float* __restrict__ xl, const float* __restrict__ s1, const float* __restrict__ d1,
    const float* __restrict__ acc, const float* __restrict__ den,
    const void* gb_, float* __restrict__ g1o)
{
  if (*flag != want) return;
  const TI* gb = (const TI*)gb_;
  int j = threadIdx.x, m = blockIdx.x, h = j >> 5;
  float es = expf(lrelu(s1[m*NH + h] + d1[m*NH + h]));
  float num = acc[(size_t)m*HD + j] + es * xl[(size_t)m*HD + j];
  float dn = den[m*NH + h] + es + 1e-16f;
  float v = num / dn + cv(gb[j]);
  g1o[(size_t)m*HD + j] = v > 0.f ? v : expm1f(v);
}

// ---------------- GAT2 ------------------------------------------------------
template<typename TI>
__global__ __launch_bounds__(64) void k_gat2_pre(
    const int* __restrict__ flag, int want,
    const float* __restrict__ g1o, const void* gW_, const void* asr_, const void* adr_,
    float* __restrict__ xl2, float* __restrict__ s2, float* __restrict__ d2,
    float* __restrict__ acc2, float* __restrict__ den2)
{
  if (*flag != want) return;
  const TI* gW  = (const TI*)gW_;
  const TI* asr = (const TI*)asr_;
  const TI* adr = (const TI*)adr_;
  __shared__ float grow[HD];
  int j = threadIdx.x, m = blockIdx.x;
  grow[j]      = g1o[(size_t)m*HD + j];
  grow[j + 64] = g1o[(size_t)m*HD + j + 64];
  __syncthreads();
  float a = 0.f;
  for (int i = 0; i < HD; ++i) a += grow[i] * cv(gW[i*GO + j]);
  xl2[(size_t)m*GO + j] = a;
  acc2[(size_t)m*GO + j] = 0.f;
  float pa = a * cv(asr[j]);
  float pb = a * cv(adr[j]);
  #pragma unroll
  for (int off = 32; off > 0; off >>= 1) { pa += __shfl_xor(pa, off); pb += __shfl_xor(pb, off); }
  if (j == 0) { s2[m] = pa; d2[m] = pb; den2[m] = 0.f; }
}

__global__ __launch_bounds__(256) void k_gat2_edge(
    const int* __restrict__ e0, const int* __restrict__ e1,
    const float* __restrict__ s2, const float* __restrict__ d2,
    const float* __restrict__ xl2, float* __restrict__ acc2, float* __restrict__ den2)
{
  int e = blockIdx.x * 4 + (threadIdx.x >> 6);
  int lane = threadIdx.x & 63;
  int b = e / EE, i = e - b * EE;
  int src = e0[i] + b * NN;
  int dst = e1[i] + b * NN;
  float eev = expf(lrelu(s2[src] + d2[dst]));
  if (lane == 0) atomicAdd(&den2[dst], eev);
  atomicAdd(&acc2[(size_t)dst*GO + lane], eev * xl2[(size_t)src*GO + lane]);
}

template<typename TI, typename TO>
__global__ __launch_bounds__(64) void k_gat2_fin(
    const int* __restrict__ flag, int want,
    const float* __restrict__ xl2, const float* __restrict__ s2, const float* __restrict__ d2,
    const float* __restrict__ acc2, const float* __restrict__ den2,
    const void* gb_, const void* oW_, const void* ob_, void* y_)
{
  if (*flag != want) return;
  const TI* gb = (const TI*)gb_;
  const TI* oW = (const TI*)oW_;
  const TI* ob = (const TI*)ob_;
  TO* y = (TO*)y_;
  __shared__ float g2s[GO];
  int j = threadIdx.x, m = blockIdx.x;
  float es = expf(lrelu(s2[m] + d2[m]));
  float num = acc2[(size_t)m*GO + j] + es * xl2[(size_t)m*GO + j];
  float dn = den2[m] + es + 1e-16f;
  g2s[j] = num / dn + cv(gb[j]);
  __syncthreads();
  if (j < HR) {
    float a = cv(ob[j]);
    #pragma unroll
    for (int o2 = 0; o2 < GO; ++o2) a += g2s[o2] * cv(oW[o2*HR + j]);
    int b = m / NN, n = m - b * NN;
    st(&y[((size_t)b*HR + j)*NN + n], a);
  }
}

// ---------------- launch ----------------------------------------------------
extern "C" void kernel_launch(void* const* d_in, const int* in_sizes, int n_in,
                              void* d_out, int out_size, void* d_ws, size_t ws_size,
                              hipStream_t stream)
{
  const int* ei = (const int*)d_in[2];
  const int* e0 = ei;
  const int* e1 = ei + EE;

  float* ws    = (float*)d_ws;
  float* hlast = ws;                  // 40000*128
  float* xl1   = ws + 5120000;        // 40000*128
  float* acc1  = ws + 10240000;       // 40000*128
  float* s1    = ws + 15360000;       // 40000*4
  float* d1    = ws + 15520000;       // 40000*4
  float* den1  = ws + 15680000;       // 40000*4
  int*   flag  = (int*)(ws + 15840000);

  // Weight buffers OVERLAP acc1 (disjoint lifetimes: prep->xform vs gat1+)
  unsigned short* Mu  = (unsigned short*)acc1;             // 128*512 bf16
  unsigned short* Pw  = Mu + 65536;                        // 128q4*128*4 bf16
  unsigned short* W1n = Mu + 131072;                       // 128*256 bf16
  unsigned short* W2p = Mu + 163840;                       // 64c4*128*4 bf16
  float* encWf = (float*)(Mu + 196608);                    // 16*128
  float* encBf = encWf + 2048;
  float* fb1f  = encBf + 128;
  float* fb2f  = fb1f + 256;
  float* l1gf  = fb2f + 128;
  float* l1bf  = l1gf + 128;
  float* l2gf  = l1bf + 128;
  float* l2bf  = l2gf + 128;

  // phase-2 aliases (lifetimes disjoint)
  float* g1o  = hlast;
  float* xl2  = xl1;
  float* acc2 = acc1;
  float* s2 = s1; float* d2 = d1; float* den2 = den1;

  k_detect<<<1, 1, 0, stream>>>(d_in[0], flag);

  k_prep<float><<<780, 256, 0, stream>>>(flag, 0,
      d_in[5], d_in[6], d_in[7], d_in[8],
      d_in[3], d_in[4], d_in[11], d_in[12], d_in[13], d_in[14],
      d_in[9], d_in[10], d_in[15], d_in[16],
      Mu, Pw, W1n, W2p, encWf, encBf, fb1f, fb2f, l1gf, l1bf, l2gf, l2bf);
  k_prep<__hip_bfloat16><<<780, 256, 0, stream>>>(flag, 1,
      d_in[5], d_in[6], d_in[7], d_in[8],
      d_in[3], d_in[4], d_in[11], d_in[12], d_in[13], d_in[14],
      d_in[9], d_in[10], d_in[15], d_in[16],
      Mu, Pw, W1n, W2p, encWf, encBf, fb1f, fb2f, l1gf, l1bf, l2gf, l2bf);

  k_xform<float><<<MM/4, 256, 0, stream>>>(flag, 0,
      d_in[0], d_in[1], Mu, Pw, W1n, W2p,
      encWf, encBf, fb1f, fb2f, l1gf, l1bf, l2gf, l2bf, hlast);
  k_xform<__hip_bfloat16><<<MM/4, 256, 0, stream>>>(flag, 1,
      d_in[0], d_in[1], Mu, Pw, W1n, W2p,
      encWf, encBf, fb1f, fb2f, l1gf, l1bf, l2gf, l2bf, hlast);

  k_gat1_pre<float><<<MM, 128, 0, stream>>>(flag, 0, hlast,
      d_in[17], d_in[18], d_in[19], xl1, s1, d1, acc1, den1);
  k_gat1_pre<__hip_bfloat16><<<MM, 128, 0, stream>>>(flag, 1, hlast,
      d_in[17], d_in[18], d_in[19], xl1, s1, d1, acc1, den1);

  k_gat1_edge<<<(BB*EE*NH)/8, 256, 0, stream>>>(e0, e1, s1, d1, xl1, acc1, den1);

  k_gat1_fin<float><<<MM, 128, 0, stream>>>(flag, 0, xl1, s1, d1, acc1, den1, d_in[20], g1o);
  k_gat1_fin<__hip_bfloat16><<<MM, 128, 0, stream>>>(flag, 1, xl1, s1, d1, acc1, den1, d_in[20], g1o);

  k_gat2_pre<float><<<MM, 64, 0, stream>>>(flag, 0, g1o,
      d_in[21], d_in[22], d_in[23], xl2, s2, d2, acc2, den2);
  k_gat2_pre<__hip_bfloat16><<<MM, 64, 0, stream>>>(flag, 1, g1o,
      d_in[21], d_in[22], d_in[23], xl2, s2, d2, acc2, den2);

  k_gat2_edge<<<(BB*EE)/4, 256, 0, stream>>>(e0, e1, s2, d2, xl2, acc2, den2);

  k_gat2_fin<float, float><<<MM, 64, 0, stream>>>(flag, 0,
      xl2, s2, d2, acc2, den2, d_in[24], d_in[25], d_in[26], d_out);
  k_gat2_fin<__hip_bfloat16, __hip_bfloat16><<<MM, 64, 0, stream>>>(flag, 1,
      xl2, s2, d2, acc2, den2, d_in[24], d_in[25], d_in[26], d_out);
}

// Round 5
// 806.770 us; speedup vs baseline: 2.3000x; 1.5008x over previous
//
#include <hip/hip_runtime.h>
#include <hip/hip_bf16.h>

#define DEV static __device__ __forceinline__

constexpr int BB = 4;        // batches
constexpr int TT = 12;       // timesteps
constexpr int NN = 10000;    // nodes per batch
constexpr int FD = 16;       // input features (8+8)
constexpr int HD = 128;      // hidden
constexpr int NH = 4;        // attn heads
constexpr int DH = 32;       // head dim
constexpr int FF = 256;      // ffn hidden
constexpr int GO = 64;       // gat2 out
constexpr int HR = 24;       // horizon
constexpr int EE = 160000;   // edges per batch
constexpr int MM = BB * NN;  // total nodes

typedef unsigned short bvec8 __attribute__((ext_vector_type(8)));
typedef float fvec4 __attribute__((ext_vector_type(4)));

DEV float cv(float x) { return x; }
DEV float cv(__hip_bfloat16 x) { return __bfloat162float(x); }
DEV void st(float* p, float v) { *p = v; }
DEV void st(__hip_bfloat16* p, float v) { *p = __float2bfloat16(v); }
DEV float lrelu(float x) { return x >= 0.f ? x : 0.2f * x; }

DEV float b2f(unsigned short u) {
  union { unsigned int i; float f; } x; x.i = ((unsigned int)u) << 16; return x.f;
}
DEV unsigned short f2b(float f) {
  union { float f; unsigned int i; } x; x.f = f;
  unsigned int r = x.i + 0x7FFFu + ((x.i >> 16) & 1u);
  return (unsigned short)(r >> 16);
}
DEV void up2(unsigned int u, float& lo, float& hi) {
  union { unsigned int i; float f; } a, b;
  a.i = u << 16; b.i = u & 0xFFFF0000u;
  lo = a.f; hi = b.f;
}

// ---------------- dtype detection (profile-verified: fp32 -> flag=0) --------
__global__ void k_detect(const void* x, int* flag)
{
  const __hip_bfloat16* p = (const __hip_bfloat16*)x;
  int sane = 0;
  for (int i = 0; i < 256; ++i) {
    float v = __bfloat162float(p[i]);
    if (fabsf(v) <= 1024.f) sane++;
  }
  *flag = (sane >= 250) ? 1 : 0;
}

// ---------------- prep: fold + re-layout ALL transformer weights ------------
template<typename TI>
__global__ __launch_bounds__(256) void k_prep(
    const int* __restrict__ flag, int want,
    const void* Wq_, const void* Wk_, const void* Wv_, const void* Wo_,
    const void* encW_, const void* encB_, const void* W1_, const void* fb1_,
    const void* W2_, const void* fb2_,
    const void* l1g_, const void* l1b_, const void* l2g_, const void* l2b_,
    unsigned short* __restrict__ Mu, unsigned short* __restrict__ Pw,
    unsigned short* __restrict__ W1n, unsigned short* __restrict__ W2p,
    float* __restrict__ encWf, float* __restrict__ encBf,
    float* __restrict__ fb1f, float* __restrict__ fb2f,
    float* __restrict__ l1gf, float* __restrict__ l1bf,
    float* __restrict__ l2gf, float* __restrict__ l2bf)
{
  if (*flag != want) return;
  const TI* Wq = (const TI*)Wq_;   const TI* Wk = (const TI*)Wk_;
  const TI* Wv = (const TI*)Wv_;   const TI* Wo = (const TI*)Wo_;
  const TI* encW = (const TI*)encW_; const TI* encB = (const TI*)encB_;
  const TI* W1 = (const TI*)W1_;   const TI* fb1 = (const TI*)fb1_;
  const TI* W2 = (const TI*)W2_;   const TI* fb2 = (const TI*)fb2_;
  const TI* l1g = (const TI*)l1g_; const TI* l1b = (const TI*)l1b_;
  const TI* l2g = (const TI*)l2g_; const TI* l2b = (const TI*)l2b_;
  int idx = blockIdx.x * 256 + threadIdx.x;      // 780*256 = 199680 exactly
  if (idx < 65536) {
    int i = idx >> 9, q = idx & 511, h = q >> 7, c = q & 127;
    float a = 0.f;
    #pragma unroll 8
    for (int d = 0; d < DH; ++d)
      a += cv(Wq[i*HD + h*DH + d]) * cv(Wk[c*HD + h*DH + d]);
    Mu[idx] = f2b(a);
  } else if (idx < 131072) {
    int g = idx - 65536;
    int q4 = g >> 9, j = (g >> 2) & 127, qr = g & 3;
    int q = q4*4 + qr, h = q >> 7, i = q & 127;
    float a = 0.f;
    #pragma unroll 8
    for (int d = 0; d < DH; ++d)
      a += cv(Wv[i*HD + h*DH + d]) * cv(Wo[(h*DH + d)*HD + j]);
    Pw[g] = f2b(a);
  } else if (idx < 163840) {
    int g = idx - 131072;                         // [i][c] direct
    W1n[g] = f2b(cv(W1[g]));
  } else if (idx < 196608) {
    int g = idx - 163840;
    int c4 = g >> 9, j = (g >> 2) & 127, cr = g & 3;
    int c = c4*4 + cr;
    W2p[g] = f2b(cv(W2[c*HD + j]));
  } else if (idx < 198656) { int t = idx - 196608; encWf[t] = cv(encW[t]); }
  else if (idx < 198784)   { int t = idx - 198656; encBf[t] = cv(encB[t]); }
  else if (idx < 199040)   { int t = idx - 198784; fb1f[t] = cv(fb1[t]); }
  else if (idx < 199168)   { int t = idx - 199040; fb2f[t] = cv(fb2[t]); }
  else if (idx < 199296)   { int t = idx - 199168; l1gf[t] = cv(l1g[t]); }
  else if (idx < 199424)   { int t = idx - 199296; l1bf[t] = cv(l1b[t]); }
  else if (idx < 199552)   { int t = idx - 199424; l2gf[t] = cv(l2g[t]); }
  else                     { int t = idx - 199552; l2bf[t] = cv(l2b[t]); }
}

// ---------------- fused transformer (4 nodes/block, 2 nodes/thread) ---------
DEV void ln_pair(float v0, float v1, int tid, float* red,
                 float& mu0, float& rs0, float& mu1, float& rs1)
{
  float s0 = v0, q0 = v0*v0, s1 = v1, q1 = v1*v1;
  #pragma unroll
  for (int off = 32; off > 0; off >>= 1) {
    s0 += __shfl_xor(s0, off); q0 += __shfl_xor(q0, off);
    s1 += __shfl_xor(s1, off); q1 += __shfl_xor(q1, off);
  }
  int half = tid >> 7, wih = (tid >> 6) & 1, lane = tid & 63;
  __syncthreads();
  if (lane == 0) {
    float* p = red + half*8 + wih*4;
    p[0] = s0; p[1] = q0; p[2] = s1; p[3] = q1;
  }
  __syncthreads();
  const float* pa = red + half*8;
  float ts0 = pa[0]+pa[4], tq0 = pa[1]+pa[5];
  float ts1 = pa[2]+pa[6], tq1 = pa[3]+pa[7];
  mu0 = ts0*(1.f/128.f); float va0 = tq0*(1.f/128.f) - mu0*mu0; rs0 = rsqrtf(va0 + 1e-5f);
  mu1 = ts1*(1.f/128.f); float va1 = tq1*(1.f/128.f) - mu1*mu1; rs1 = rsqrtf(va1 + 1e-5f);
}

template<typename TI>
__global__ __launch_bounds__(256) void k_xform(
    const int* __restrict__ flag, int want,
    const void* xh_, const void* xc_,
    const unsigned short* __restrict__ Mu, const unsigned short* __restrict__ Pw,
    const unsigned short* __restrict__ W1n, const unsigned short* __restrict__ W2p,
    const float* __restrict__ encWf, const float* __restrict__ encBf,
    const float* __restrict__ fb1f, const float* __restrict__ fb2f,
    const float* __restrict__ l1gf, const float* __restrict__ l1bf,
    const float* __restrict__ l2gf, const float* __restrict__ l2bf,
    float* __restrict__ hlast)
{
  if (*flag != want) return;
  const TI* xh = (const TI*)xh_;
  const TI* xc = (const TI*)xc_;

  __shared__ unsigned short hsB[4][TT][136];  // h bf16, rows padded for banks
  __shared__ float us[4][NH][136];            // u then w
  __shared__ float scratch[4][256];           // x -> h_last stash -> f1
  __shared__ float h1s[4][HD];
  __shared__ float lgaw[4][NH][TT];           // logits then alpha
  __shared__ float red[16];

  const int tid = threadIdx.x;
  const int half = tid >> 7;
  const int j = tid & 127;
  const int m0 = blockIdx.x * 4;

  // --- load x (4 nodes x 12 t x 16 f) ---
  #pragma unroll
  for (int k = 0; k < 3; ++k) {
    int idx = tid + k*256;
    int nl = idx / 192, rem = idx - nl*192;
    int t = rem >> 4, f = rem & 15;
    int m = m0 + nl, b = m / NN, n = m - b*NN;
    float v = (f < 8) ? cv(xh[(((size_t)b*TT + t)*NN + n)*8 + f])
                      : cv(xc[(((size_t)b*TT + t)*NN + n)*8 + (f - 8)]);
    scratch[nl][rem] = v;
  }
  __syncthreads();

  // --- encoder ---
  float ew[FD];
  #pragma unroll
  for (int f = 0; f < FD; ++f) ew[f] = encWf[f*HD + j];
  float eb = encBf[j];
  float h11[2];
  #pragma unroll
  for (int r = 0; r < 2; ++r) {
    int nl = half*2 + r;
    #pragma unroll
    for (int t = 0; t < TT; ++t) {
      const fvec4* xp = (const fvec4*)&scratch[nl][t*16];
      fvec4 x0 = xp[0], x1 = xp[1], x2 = xp[2], x3 = xp[3];
      float a = eb;
      a += x0[0]*ew[0]  + x0[1]*ew[1]  + x0[2]*ew[2]  + x0[3]*ew[3];
      a += x1[0]*ew[4]  + x1[1]*ew[5]  + x1[2]*ew[6]  + x1[3]*ew[7];
      a += x2[0]*ew[8]  + x2[1]*ew[9]  + x2[2]*ew[10] + x2[3]*ew[11];
      a += x3[0]*ew[12] + x3[1]*ew[13] + x3[2]*ew[14] + x3[3]*ew[15];
      hsB[nl][t][j] = f2b(a);
      if (t == TT-1) h11[r] = a;
    }
  }
  __syncthreads();

  scratch[half*2+0][j] = h11[0];
  scratch[half*2+1][j] = h11[1];
  __syncthreads();

  // --- u = h_last @ Mu ---
  float ua[2][4] = {{0.f,0.f,0.f,0.f},{0.f,0.f,0.f,0.f}};
  const uint2* Mu2 = (const uint2*)Mu;
  for (int i4 = 0; i4 < 32; ++i4) {
    fvec4 ha = *(const fvec4*)&scratch[half*2+0][i4*4];
    fvec4 hb = *(const fvec4*)&scratch[half*2+1][i4*4];
    #pragma unroll
    for (int e = 0; e < 4; ++e) {
      uint2 w = Mu2[(i4*4+e)*128 + j];
      float w0,w1,w2,w3; up2(w.x,w0,w1); up2(w.y,w2,w3);
      float hva = ha[e], hvb = hb[e];
      ua[0][0] += w0*hva; ua[0][1] += w1*hva; ua[0][2] += w2*hva; ua[0][3] += w3*hva;
      ua[1][0] += w0*hvb; ua[1][1] += w1*hvb; ua[1][2] += w2*hvb; ua[1][3] += w3*hvb;
    }
  }
  {
    int hd = j >> 5, col = (j & 31) * 4;
    fvec4 v0 = {ua[0][0], ua[0][1], ua[0][2], ua[0][3]};
    fvec4 v1 = {ua[1][0], ua[1][1], ua[1][2], ua[1][3]};
    *(fvec4*)&us[half*2+0][hd][col] = v0;
    *(fvec4*)&us[half*2+1][hd][col] = v1;
  }
  __syncthreads();

  // --- logits ---
  if (j < 96) {
    int r = j / 48, p = j - r*48, hd = p / 12, t = p - hd*12;
    int nl = half*2 + r;
    float a = 0.f;
    for (int i8 = 0; i8 < 16; ++i8) {
      bvec8 hb8 = *(const bvec8*)&hsB[nl][t][i8*8];
      const fvec4* up = (const fvec4*)&us[nl][hd][i8*8];
      fvec4 u0 = up[0], u1 = up[1];
      a += b2f(hb8[0])*u0[0] + b2f(hb8[1])*u0[1] + b2f(hb8[2])*u0[2] + b2f(hb8[3])*u0[3]
         + b2f(hb8[4])*u1[0] + b2f(hb8[5])*u1[1] + b2f(hb8[6])*u1[2] + b2f(hb8[7])*u1[3];
    }
    lgaw[nl][hd][t] = a * 0.17677669529663687f;
  }
  __syncthreads();

  // --- softmax over t ---
  if (j < 8) {
    int r = j >> 2, hd = j & 3, nl = half*2 + r;
    float mx = -1e30f;
    #pragma unroll
    for (int t = 0; t < TT; ++t) mx = fmaxf(mx, lgaw[nl][hd][t]);
    float ex[TT], sm = 0.f;
    #pragma unroll
    for (int t = 0; t < TT; ++t) { ex[t] = expf(lgaw[nl][hd][t] - mx); sm += ex[t]; }
    float inv = 1.f / sm;
    #pragma unroll
    for (int t = 0; t < TT; ++t) lgaw[nl][hd][t] = ex[t] * inv;
  }
  __syncthreads();

  // --- w_h = sum_t alpha_ht * h_t ---
  float wa[NH][2];
  #pragma unroll
  for (int hd = 0; hd < NH; ++hd) { wa[hd][0] = 0.f; wa[hd][1] = 0.f; }
  #pragma unroll
  for (int r = 0; r < 2; ++r) {
    int nl = half*2 + r;
    #pragma unroll
    for (int t = 0; t < TT; ++t) {
      float hv = b2f(hsB[nl][t][j]);
      #pragma unroll
      for (int hd = 0; hd < NH; ++hd) wa[hd][r] += lgaw[nl][hd][t] * hv;
    }
  }
  __syncthreads();
  #pragma unroll
  for (int hd = 0; hd < NH; ++hd) {
    us[half*2+0][hd][j] = wa[hd][0];
    us[half*2+1][hd][j] = wa[hd][1];
  }
  __syncthreads();

  // --- attn-out @ Wo folded ---
  float oa[2] = {0.f, 0.f};
  const uint2* Pw2 = (const uint2*)Pw;
  for (int q4 = 0; q4 < 128; ++q4) {
    fvec4 wqa = *(const fvec4*)&us[half*2+0][q4>>5][(q4&31)*4];
    fvec4 wqb = *(const fvec4*)&us[half*2+1][q4>>5][(q4&31)*4];
    uint2 pw = Pw2[q4*128 + j];
    float p0,p1,p2,p3; up2(pw.x,p0,p1); up2(pw.y,p2,p3);
    oa[0] += p0*wqa[0] + p1*wqa[1] + p2*wqa[2] + p3*wqa[3];
    oa[1] += p0*wqb[0] + p1*wqb[1] + p2*wqb[2] + p3*wqb[3];
  }

  // --- LN1 ---
  float mu0, rs0, mu1, rs1;
  float r1a = h11[0] + oa[0], r1b = h11[1] + oa[1];
  ln_pair(r1a, r1b, tid, red, mu0, rs0, mu1, rs1);
  float g1 = l1gf[j], b1 = l1bf[j];
  float h1a = (r1a - mu0)*rs0*g1 + b1;
  float h1b = (r1b - mu1)*rs1*g1 + b1;
  h1s[half*2+0][j] = h1a;
  h1s[half*2+1][j] = h1b;
  __syncthreads();

  // --- FFN layer 1 ---
  float fa[2][2] = {{0.f,0.f},{0.f,0.f}};
  const unsigned int* W1u = (const unsigned int*)W1n;
  for (int i4 = 0; i4 < 32; ++i4) {
    fvec4 ha = *(const fvec4*)&h1s[half*2+0][i4*4];
    fvec4 hb = *(const fvec4*)&h1s[half*2+1][i4*4];
    #pragma unroll
    for (int e = 0; e < 4; ++e) {
      unsigned int w = W1u[(i4*4+e)*128 + j];
      float w0,w1; up2(w,w0,w1);
      float hva = ha[e], hvb = hb[e];
      fa[0][0] += w0*hva; fa[0][1] += w0*hvb;
      fa[1][0] += w1*hva; fa[1][1] += w1*hvb;
    }
  }
  float bva = fb1f[2*j], bvb = fb1f[2*j+1];
  scratch[half*2+0][2*j]   = fmaxf(fa[0][0] + bva, 0.f);
  scratch[half*2+1][2*j]   = fmaxf(fa[0][1] + bva, 0.f);
  scratch[half*2+0][2*j+1] = fmaxf(fa[1][0] + bvb, 0.f);
  scratch[half*2+1][2*j+1] = fmaxf(fa[1][1] + bvb, 0.f);
  __syncthreads();

  // --- FFN layer 2 ---
  float f2a[2] = {0.f, 0.f};
  const uint2* W2u2 = (const uint2*)W2p;
  for (int c4 = 0; c4 < 64; ++c4) {
    fvec4 fva = *(const fvec4*)&scratch[half*2+0][c4*4];
    fvec4 fvb = *(const fvec4*)&scratch[half*2+1][c4*4];
    uint2 w = W2u2[c4*128 + j];
    float w0,w1,w2,w3; up2(w.x,w0,w1); up2(w.y,w2,w3);
    f2a[0] += w0*fva[0] + w1*fva[1] + w2*fva[2] + w3*fva[3];
    f2a[1] += w0*fvb[0] + w1*fvb[1] + w2*fvb[2] + w3*fvb[3];
  }
  float fb2v = fb2f[j];
  float r2a = h1a + fb2v + f2a[0];
  float r2b = h1b + fb2v + f2a[1];
  ln_pair(r2a, r2b, tid, red, mu0, rs0, mu1, rs1);
  float g2 = l2gf[j], b2v = l2bf[j];
  hlast[(size_t)(m0 + half*2 + 0)*HD + j] = (r2a - mu0)*rs0*g2 + b2v;
  hlast[(size_t)(m0 + half*2 + 1)*HD + j] = (r2b - mu1)*rs1*g2 + b2v;
}

// ---------------- CSR build (batch-shared, dtype-independent) ---------------
__global__ __launch_bounds__(256) void k_zero(int* __restrict__ cnt)
{
  int i = blockIdx.x * 256 + threadIdx.x;
  if (i < NN) cnt[i] = 0;
}

__global__ __launch_bounds__(256) void k_hist(const int* __restrict__ e1,
                                              int* __restrict__ cnt)
{
  int i = blockIdx.x * 256 + threadIdx.x;
  if (i < EE) atomicAdd(&cnt[e1[i]], 1);
}

__global__ __launch_bounds__(1024) void k_scan(const int* __restrict__ cnt,
                                               int* __restrict__ row_ptr,
                                               int* __restrict__ cur)
{
  __shared__ int sm[1024];
  int tid = threadIdx.x;
  int base = tid * 10;
  int loc[10];
  int s = 0;
  #pragma unroll
  for (int k = 0; k < 10; ++k) {
    int idx = base + k;
    int v = (idx < NN) ? cnt[idx] : 0;
    loc[k] = s;
    s += v;
  }
  sm[tid] = s;
  __syncthreads();
  for (int off = 1; off < 1024; off <<= 1) {
    int t = (tid >= off) ? sm[tid - off] : 0;
    __syncthreads();
    sm[tid] += t;
    __syncthreads();
  }
  int segbase = sm[tid] - s;      // exclusive base of this thread's segment
  #pragma unroll
  for (int k = 0; k < 10; ++k) {
    int idx = base + k;
    if (idx < NN) { int o = segbase + loc[k]; row_ptr[idx] = o; cur[idx] = o; }
  }
  if (tid == 1023) row_ptr[NN] = sm[1023];
}

__global__ __launch_bounds__(256) void k_scatter(const int* __restrict__ e0,
                                                 const int* __restrict__ e1,
                                                 int* __restrict__ cur,
                                                 int* __restrict__ ssrc)
{
  int i = blockIdx.x * 256 + threadIdx.x;
  if (i >= EE) return;
  int pos = atomicAdd(&cur[e1[i]], 1);
  ssrc[pos] = e0[i];
}

// ---------------- GAT1 ------------------------------------------------------
template<typename TI>
__global__ __launch_bounds__(128) void k_gat1_pre(
    const int* __restrict__ flag, int want,
    const float* __restrict__ hlast, const void* gW_, const void* asr_, const void* adr_,
    float* __restrict__ xl, float* __restrict__ s1, float* __restrict__ d1)
{
  if (*flag != want) return;
  const TI* gW  = (const TI*)gW_;
  const TI* asr = (const TI*)asr_;
  const TI* adr = (const TI*)adr_;
  __shared__ float hrow[HD];
  int j = threadIdx.x, m = blockIdx.x;
  hrow[j] = hlast[(size_t)m*HD + j];
  __syncthreads();
  float a = 0.f;
  for (int i = 0; i < HD; ++i) a += hrow[i] * cv(gW[i*HD + j]);
  xl[(size_t)m*HD + j] = a;
  float pa = a * cv(asr[j]);
  float pb = a * cv(adr[j]);
  #pragma unroll
  for (int off = 16; off > 0; off >>= 1) { pa += __shfl_xor(pa, off); pb += __shfl_xor(pb, off); }
  if ((j & 31) == 0) {
    int h = j >> 5;
    s1[m*NH + h] = pa;
    d1[m*NH + h] = pb;
  }
}

// CSR gather + softmax-normalize + self-loop + bias + ELU, fully fused.
template<typename TI>
__global__ __launch_bounds__(128) void k_gat1_gather(
    const int* __restrict__ flag, int want,
    const int* __restrict__ row_ptr, const int* __restrict__ ssrc,
    const float* __restrict__ xl, const float* __restrict__ s1, const float* __restrict__ d1,
    const void* gb_, float* __restrict__ g1o)
{
  if (*flag != want) return;
  const TI* gb = (const TI*)gb_;
  int j = threadIdx.x, m = blockIdx.x, h = j >> 5;
  int b = m / NN, n = m - b * NN, boff = b * NN;
  float dh = d1[m*NH + h];
  int r0 = row_ptr[n], r1 = row_ptr[n+1];
  float acc = 0.f, dsum = 0.f;
  for (int e = r0; e < r1; ++e) {
    int src = ssrc[e] + boff;
    float ev = expf(lrelu(s1[src*NH + h] + dh));
    acc  += ev * xl[(size_t)src*HD + j];
    dsum += ev;
  }
  float es = expf(lrelu(s1[m*NH + h] + dh));     // self loop
  acc  += es * xl[(size_t)m*HD + j];
  dsum += es;
  float v = acc / (dsum + 1e-16f) + cv(gb[j]);
  g1o[(size_t)m*HD + j] = v > 0.f ? v : expm1f(v);   // ELU
}

// ---------------- GAT2 ------------------------------------------------------
template<typename TI>
__global__ __launch_bounds__(64) void k_gat2_pre(
    const int* __restrict__ flag, int want,
    const float* __restrict__ g1o, const void* gW_, const void* asr_, const void* adr_,
    float* __restrict__ xl2, float* __restrict__ s2, float* __restrict__ d2)
{
  if (*flag != want) return;
  const TI* gW  = (const TI*)gW_;
  const TI* asr = (const TI*)asr_;
  const TI* adr = (const TI*)adr_;
  __shared__ float grow[HD];
  int j = threadIdx.x, m = blockIdx.x;
  grow[j]      = g1o[(size_t)m*HD + j];
  grow[j + 64] = g1o[(size_t)m*HD + j + 64];
  __syncthreads();
  float a = 0.f;
  for (int i = 0; i < HD; ++i) a += grow[i] * cv(gW[i*GO + j]);
  xl2[(size_t)m*GO + j] = a;
  float pa = a * cv(asr[j]);
  float pb = a * cv(adr[j]);
  #pragma unroll
  for (int off = 32; off > 0; off >>= 1) { pa += __shfl_xor(pa, off); pb += __shfl_xor(pb, off); }
  if (j == 0) { s2[m] = pa; d2[m] = pb; }
}

// CSR gather + normalize + self-loop + bias + output projection, fused.
template<typename TI, typename TO>
__global__ __launch_bounds__(64) void k_gat2_gather(
    const int* __restrict__ flag, int want,
    const int* __restrict__ row_ptr, const int* __restrict__ ssrc,
    const float* __restrict__ xl2, const float* __restrict__ s2, const float* __restrict__ d2,
    const void* gb_, const void* oW_, const void* ob_, void* y_)
{
  if (*flag != want) return;
  const TI* gb = (const TI*)gb_;
  const TI* oW = (const TI*)oW_;
  const TI* ob = (const TI*)ob_;
  TO* y = (TO*)y_;
  __shared__ float g2s[GO];
  int j = threadIdx.x, m = blockIdx.x;
  int b = m / NN, n = m - b * NN, boff = b * NN;
  float d2m = d2[m];
  int r0 = row_ptr[n], r1 = row_ptr[n+1];
  float acc = 0.f, dsum = 0.f;
  for (int e = r0; e < r1; ++e) {
    int src = ssrc[e] + boff;
    float ev = expf(lrelu(s2[src] + d2m));
    acc  += ev * xl2[(size_t)src*GO + j];
    dsum += ev;
  }
  float es = expf(lrelu(s2[m] + d2m));
  acc  += es * xl2[(size_t)m*GO + j];
  dsum += es;
  g2s[j] = acc / (dsum + 1e-16f) + cv(gb[j]);
  __syncthreads();
  if (j < HR) {
    float a = cv(ob[j]);
    #pragma unroll
    for (int o2 = 0; o2 < GO; ++o2) a += g2s[o2] * cv(oW[o2*HR + j]);
    st(&y[((size_t)b*HR + j)*NN + n], a);
  }
}

// ---------------- launch ----------------------------------------------------
extern "C" void kernel_launch(void* const* d_in, const int* in_sizes, int n_in,
                              void* d_out, int out_size, void* d_ws, size_t ws_size,
                              hipStream_t stream)
{
  const int* ei = (const int*)d_in[2];
  const int* e0 = ei;
  const int* e1 = ei + EE;

  float* ws    = (float*)d_ws;
  float* hlast = ws;                  // 40000*128
  float* xl1   = ws + 5120000;        // 40000*128
  float* ovl   = ws + 10240000;       // overlap region (weights, then CSR)
  float* s1    = ws + 15360000;       // 40000*4
  float* d1    = ws + 15520000;       // 40000*4
  int*   flag  = (int*)(ws + 15680000);

  // Weight buffers live [prep, xform] in the overlap region.
  unsigned short* Mu  = (unsigned short*)ovl;              // 128*512 bf16
  unsigned short* Pw  = Mu + 65536;
  unsigned short* W1n = Mu + 131072;
  unsigned short* W2p = Mu + 163840;
  float* encWf = (float*)(Mu + 196608);
  float* encBf = encWf + 2048;
  float* fb1f  = encBf + 128;
  float* fb2f  = fb1f + 256;
  float* l1gf  = fb2f + 128;
  float* l1bf  = l1gf + 128;
  float* l2gf  = l1bf + 128;
  float* l2bf  = l2gf + 128;

  // CSR arrays live [hist, end] in the SAME overlap region (stream-serial,
  // weights are dead after k_xform).
  int* cnt     = (int*)ovl;           // 10000
  int* row_ptr = cnt + 16384;         // 10001
  int* cur     = cnt + 32768;         // 10000
  int* ssrc    = cnt + 49152;         // 160000

  // phase-2 aliases (lifetimes disjoint)
  float* g1o  = hlast;
  float* xl2  = xl1;
  float* s2 = s1; float* d2 = d1;

  k_detect<<<1, 1, 0, stream>>>(d_in[0], flag);

  k_prep<float><<<780, 256, 0, stream>>>(flag, 0,
      d_in[5], d_in[6], d_in[7], d_in[8],
      d_in[3], d_in[4], d_in[11], d_in[12], d_in[13], d_in[14],
      d_in[9], d_in[10], d_in[15], d_in[16],
      Mu, Pw, W1n, W2p, encWf, encBf, fb1f, fb2f, l1gf, l1bf, l2gf, l2bf);
  k_prep<__hip_bfloat16><<<780, 256, 0, stream>>>(flag, 1,
      d_in[5], d_in[6], d_in[7], d_in[8],
      d_in[3], d_in[4], d_in[11], d_in[12], d_in[13], d_in[14],
      d_in[9], d_in[10], d_in[15], d_in[16],
      Mu, Pw, W1n, W2p, encWf, encBf, fb1f, fb2f, l1gf, l1bf, l2gf, l2bf);

  k_xform<float><<<MM/4, 256, 0, stream>>>(flag, 0,
      d_in[0], d_in[1], Mu, Pw, W1n, W2p,
      encWf, encBf, fb1f, fb2f, l1gf, l1bf, l2gf, l2bf, hlast);
  k_xform<__hip_bfloat16><<<MM/4, 256, 0, stream>>>(flag, 1,
      d_in[0], d_in[1], Mu, Pw, W1n, W2p,
      encWf, encBf, fb1f, fb2f, l1gf, l1bf, l2gf, l2bf, hlast);

  // CSR build (after xform: overlap region is free now)
  k_zero<<<(NN + 255)/256, 256, 0, stream>>>(cnt);
  k_hist<<<(EE + 255)/256, 256, 0, stream>>>(e1, cnt);
  k_scan<<<1, 1024, 0, stream>>>(cnt, row_ptr, cur);
  k_scatter<<<(EE + 255)/256, 256, 0, stream>>>(e0, e1, cur, ssrc);

  k_gat1_pre<float><<<MM, 128, 0, stream>>>(flag, 0, hlast,
      d_in[17], d_in[18], d_in[19], xl1, s1, d1);
  k_gat1_pre<__hip_bfloat16><<<MM, 128, 0, stream>>>(flag, 1, hlast,
      d_in[17], d_in[18], d_in[19], xl1, s1, d1);

  k_gat1_gather<float><<<MM, 128, 0, stream>>>(flag, 0,
      row_ptr, ssrc, xl1, s1, d1, d_in[20], g1o);
  k_gat1_gather<__hip_bfloat16><<<MM, 128, 0, stream>>>(flag, 1,
      row_ptr, ssrc, xl1, s1, d1, d_in[20], g1o);

  k_gat2_pre<float><<<MM, 64, 0, stream>>>(flag, 0, g1o,
      d_in[21], d_in[22], d_in[23], xl2, s2, d2);
  k_gat2_pre<__hip_bfloat16><<<MM, 64, 0, stream>>>(flag, 1, g1o,
      d_in[21], d_in[22], d_in[23], xl2, s2, d2);

  k_gat2_gather<float, float><<<MM, 64, 0, stream>>>(flag, 0,
      row_ptr, ssrc, xl2, s2, d2, d_in[24], d_in[25], d_in[26], d_out);
  k_gat2_gather<__hip_bfloat16, __hip_bfloat16><<<MM, 64, 0, stream>>>(flag, 1,
      row_ptr, ssrc, xl2, s2, d2, d_in[24], d_in[25], d_in[26], d_out);
}

// Round 6
// 575.951 us; speedup vs baseline: 3.2217x; 1.4008x over previous
//
#include <hip/hip_runtime.h>
#include <hip/hip_bf16.h>

#define DEV static __device__ __forceinline__

constexpr int BB = 4;        // batches
constexpr int TT = 12;       // timesteps
constexpr int NN = 10000;    // nodes per batch
constexpr int FD = 16;       // input features (8+8)
constexpr int HD = 128;      // hidden
constexpr int NH = 4;        // attn heads
constexpr int DH = 32;       // head dim
constexpr int FF = 256;      // ffn hidden
constexpr int GO = 64;       // gat2 out
constexpr int HR = 24;       // horizon
constexpr int EE = 160000;   // edges per batch
constexpr int MM = BB * NN;  // total nodes

typedef unsigned short bvec8 __attribute__((ext_vector_type(8)));
typedef float fvec4 __attribute__((ext_vector_type(4)));
typedef short bs8 __attribute__((ext_vector_type(8)));      // MFMA bf16 frag (4 VGPR)

DEV float cv(float x) { return x; }
DEV float cv(__hip_bfloat16 x) { return __bfloat162float(x); }
DEV void st(float* p, float v) { *p = v; }
DEV void st(__hip_bfloat16* p, float v) { *p = __float2bfloat16(v); }
DEV float lrelu(float x) { return x >= 0.f ? x : 0.2f * x; }

DEV float b2f(unsigned short u) {
  union { unsigned int i; float f; } x; x.i = ((unsigned int)u) << 16; return x.f;
}
DEV unsigned short f2b(float f) {
  union { float f; unsigned int i; } x; x.f = f;
  unsigned int r = x.i + 0x7FFFu + ((x.i >> 16) & 1u);
  return (unsigned short)(r >> 16);
}
DEV void up2(unsigned int u, float& lo, float& hi) {
  union { unsigned int i; float f; } a, b;
  a.i = u << 16; b.i = u & 0xFFFF0000u;
  lo = a.f; hi = b.f;
}

DEV fvec4 mfma16(bs8 a, bs8 b, fvec4 c) {
  return __builtin_amdgcn_mfma_f32_16x16x32_bf16(a, b, c, 0, 0, 0);
}

// ---------------- dtype detection (profile-verified: fp32 -> flag=0) --------
__global__ void k_detect(const void* x, int* flag)
{
  const __hip_bfloat16* p = (const __hip_bfloat16*)x;
  int sane = 0;
  for (int i = 0; i < 256; ++i) {
    float v = __bfloat162float(p[i]);
    if (fabsf(v) <= 1024.f) sane++;
  }
  *flag = (sane >= 250) ? 1 : 0;
}

// ---------------- prep: fold + re-layout ALL transformer weights ------------
// MuF/PwF are stored in MFMA B-fragment order:
//   frag idx = ((nt*nK + kk)*64 + lane)*8 + e ; B[k][n]: k = kk*32+(lane>>4)*8+e,
//   n = nt*16 + (lane&15).  u-GEMM: K=128 (nK=4), N=512. Pw-GEMM: K=512 (nK=16), N=128.
template<typename TI>
__global__ __launch_bounds__(256) void k_prep(
    const int* __restrict__ flag, int want,
    const void* Wq_, const void* Wk_, const void* Wv_, const void* Wo_,
    const void* encW_, const void* encB_, const void* W1_, const void* fb1_,
    const void* W2_, const void* fb2_,
    const void* l1g_, const void* l1b_, const void* l2g_, const void* l2b_,
    unsigned short* __restrict__ Mu, unsigned short* __restrict__ Pw,
    unsigned short* __restrict__ W1n, unsigned short* __restrict__ W2p,
    float* __restrict__ encWf, float* __restrict__ encBf,
    float* __restrict__ fb1f, float* __restrict__ fb2f,
    float* __restrict__ l1gf, float* __restrict__ l1bf,
    float* __restrict__ l2gf, float* __restrict__ l2bf)
{
  if (*flag != want) return;
  const TI* Wq = (const TI*)Wq_;   const TI* Wk = (const TI*)Wk_;
  const TI* Wv = (const TI*)Wv_;   const TI* Wo = (const TI*)Wo_;
  const TI* encW = (const TI*)encW_; const TI* encB = (const TI*)encB_;
  const TI* W1 = (const TI*)W1_;   const TI* fb1 = (const TI*)fb1_;
  const TI* W2 = (const TI*)W2_;   const TI* fb2 = (const TI*)fb2_;
  const TI* l1g = (const TI*)l1g_; const TI* l1b = (const TI*)l1b_;
  const TI* l2g = (const TI*)l2g_; const TI* l2b = (const TI*)l2b_;
  int idx = blockIdx.x * 256 + threadIdx.x;      // 780*256 = 199680 exactly
  if (idx < 65536) {
    // MuF fragment: B[i][q] = sum_d Wq[i][h*32+d]*Wk[c][h*32+d], q=(h,c)
    int e = idx & 7, lane = (idx >> 3) & 63, kk = (idx >> 9) & 3, nt = idx >> 11;
    int i = kk*32 + (lane >> 4)*8 + e;
    int q = nt*16 + (lane & 15);
    int h = q >> 7, c = q & 127;
    float a = 0.f;
    #pragma unroll 8
    for (int d = 0; d < DH; ++d)
      a += cv(Wq[i*HD + h*DH + d]) * cv(Wk[c*HD + h*DH + d]);
    Mu[idx] = f2b(a);
  } else if (idx < 131072) {
    // PwF fragment: B[q][j] = sum_d Wv[i][h*32+d]*Wo[h*32+d][j], q=(h,i)
    int g2 = idx - 65536;
    int e = g2 & 7, lane = (g2 >> 3) & 63, kk = (g2 >> 9) & 15, nt = g2 >> 13;
    int q = kk*32 + (lane >> 4)*8 + e;
    int j = nt*16 + (lane & 15);
    int h = q >> 7, i = q & 127;
    float a = 0.f;
    #pragma unroll 8
    for (int d = 0; d < DH; ++d)
      a += cv(Wv[i*HD + h*DH + d]) * cv(Wo[(h*DH + d)*HD + j]);
    Pw[g2] = f2b(a);
  } else if (idx < 163840) {
    int g = idx - 131072;                         // W1n[i][c] direct
    W1n[g] = f2b(cv(W1[g]));
  } else if (idx < 196608) {
    int g = idx - 163840;                         // W2p k-packed-4
    int c4 = g >> 9, j = (g >> 2) & 127, cr = g & 3;
    int c = c4*4 + cr;
    W2p[g] = f2b(cv(W2[c*HD + j]));
  } else if (idx < 198656) { int t = idx - 196608; encWf[t] = cv(encW[t]); }
  else if (idx < 198784)   { int t = idx - 198656; encBf[t] = cv(encB[t]); }
  else if (idx < 199040)   { int t = idx - 198784; fb1f[t] = cv(fb1[t]); }
  else if (idx < 199168)   { int t = idx - 199040; fb2f[t] = cv(fb2[t]); }
  else if (idx < 199296)   { int t = idx - 199168; l1gf[t] = cv(l1g[t]); }
  else if (idx < 199424)   { int t = idx - 199296; l1bf[t] = cv(l1b[t]); }
  else if (idx < 199552)   { int t = idx - 199424; l2gf[t] = cv(l2g[t]); }
  else                     { int t = idx - 199552; l2bf[t] = cv(l2b[t]); }
}

// ---------------- fused transformer (8 nodes/block, MFMA for u & Pw) --------
template<typename TI>
__global__ __launch_bounds__(256) void k_xform(
    const int* __restrict__ flag, int want,
    const void* xh_, const void* xc_,
    const unsigned short* __restrict__ MuF, const unsigned short* __restrict__ PwF,
    const unsigned short* __restrict__ W1n, const unsigned short* __restrict__ W2p,
    const float* __restrict__ encWf, const float* __restrict__ encBf,
    const float* __restrict__ fb1f, const float* __restrict__ fb2f,
    const float* __restrict__ l1gf, const float* __restrict__ l1bf,
    const float* __restrict__ l2gf, const float* __restrict__ l2bf,
    float* __restrict__ hlast)
{
  if (*flag != want) return;
  const TI* xh = (const TI*)xh_;
  const TI* xc = (const TI*)xc_;

  __shared__ unsigned short hsB[8][TT][136];   // h bf16 (26112 B)
  __shared__ float hlastF[8][128];             // residual fp32 (4096 B)
  __shared__ unsigned short hlastB[16][136];   // u-GEMM A frags (4352 B; rows 8-15 junk->discarded)
  __shared__ float lgaw[8][NH][TT];            // logits then alpha (1536 B)
  __shared__ __align__(16) char regB[17408];   // unioned transient region

  float* xs  = (float*)regB;                   // [8][192]  (phase 0-1)
  float* usF = (float*)regB;                   // [8][4][132] fp32 u (phase 2-3)
  unsigned short* wB = (unsigned short*)regB;  // [16][520] bf16 w (phase 5-6)
  float* r1F = (float*)regB;                   // [8][132]  (phase 6-7, reused 9-10)
  float* h1s = (float*)(regB + 4224);          // [8][132]  (phase 7-9)
  float* f1s = (float*)(regB + 8448);          // [8][260]  (phase 8-9)

  const int tid  = threadIdx.x;
  const int j    = tid & 127;
  const int g    = tid >> 7;
  const int w    = tid >> 6;
  const int lane = tid & 63;
  const int m0   = blockIdx.x * 8;

  // --- phase 0: load x (8 nodes x 12 t x 16 f) ---
  #pragma unroll
  for (int k = 0; k < 6; ++k) {
    int idx = tid + k*256;
    int nl = idx / 192, rem = idx - nl*192;
    int t = rem >> 4, f = rem & 15;
    int m = m0 + nl, b = m / NN, n = m - b*NN;
    float v = (f < 8) ? cv(xh[(((size_t)b*TT + t)*NN + n)*8 + f])
                      : cv(xc[(((size_t)b*TT + t)*NN + n)*8 + (f - 8)]);
    xs[nl*192 + rem] = v;
  }
  __syncthreads();

  // --- phase 1: encoder (fp32 VALU; preserves residual accuracy) ---
  {
    float ew[FD];
    #pragma unroll
    for (int f = 0; f < FD; ++f) ew[f] = encWf[f*HD + j];
    float eb = encBf[j];
    #pragma unroll
    for (int r = 0; r < 4; ++r) {
      int nl = g*4 + r;
      #pragma unroll
      for (int t = 0; t < TT; ++t) {
        const fvec4* xp = (const fvec4*)&xs[nl*192 + t*16];
        fvec4 x0 = xp[0], x1 = xp[1], x2 = xp[2], x3 = xp[3];
        float a = eb;
        a += x0[0]*ew[0]  + x0[1]*ew[1]  + x0[2]*ew[2]  + x0[3]*ew[3];
        a += x1[0]*ew[4]  + x1[1]*ew[5]  + x1[2]*ew[6]  + x1[3]*ew[7];
        a += x2[0]*ew[8]  + x2[1]*ew[9]  + x2[2]*ew[10] + x2[3]*ew[11];
        a += x3[0]*ew[12] + x3[1]*ew[13] + x3[2]*ew[14] + x3[3]*ew[15];
        hsB[nl][t][j] = f2b(a);
        if (t == TT-1) { hlastF[nl][j] = a; hlastB[nl][j] = f2b(a); }
      }
    }
  }
  __syncthreads();

  // --- phase 2: u = h_last @ Mu via MFMA (D: 8 nodes x 512, fp32) ---
  {
    int arow = lane & 15, akg = lane >> 4;
    bs8 af[4];
    #pragma unroll
    for (int kk = 0; kk < 4; ++kk)
      af[kk] = *(const bs8*)&hlastB[arow][kk*32 + akg*8];
    const bs8* bp = (const bs8*)MuF;
    fvec4 acc[8];
    #pragma unroll
    for (int n8 = 0; n8 < 8; ++n8) {
      int nt = w*8 + n8;
      const bs8* bq = bp + nt*256 + lane;      // frag idx (nt*4+kk)*64+lane
      fvec4 a4 = {0.f, 0.f, 0.f, 0.f};
      #pragma unroll
      for (int kk = 0; kk < 4; ++kk)
        a4 = mfma16(af[kk], bq[kk*64], a4);
      acc[n8] = a4;
    }
    if (lane < 32) {                            // valid D rows 0..7 only
      int drow = (lane >> 4)*4, dc = lane & 15;
      #pragma unroll
      for (int n8 = 0; n8 < 8; ++n8) {
        int col = (w*8 + n8)*16 + dc, hd = col >> 7, c = col & 127;
        #pragma unroll
        for (int reg = 0; reg < 4; ++reg)
          usF[((drow + reg)*4 + hd)*132 + c] = acc[n8][reg];
      }
    }
  }
  __syncthreads();

  // --- phase 3: logits (8n x 4h x 12t = 384 dots of K=128) ---
  #pragma unroll
  for (int pass = 0; pass < 2; ++pass) {
    int item = pass*256 + tid;
    if (item < 384) {
      int nl = item / 48, p = item - nl*48, hd = p / 12, t = p - hd*12;
      const float* up = &usF[(nl*4 + hd)*132];
      float a = 0.f;
      for (int i8 = 0; i8 < 16; ++i8) {
        bvec8 hb8 = *(const bvec8*)&hsB[nl][t][i8*8];
        const fvec4* uq = (const fvec4*)&up[i8*8];
        fvec4 u0 = uq[0], u1 = uq[1];
        a += b2f(hb8[0])*u0[0] + b2f(hb8[1])*u0[1] + b2f(hb8[2])*u0[2] + b2f(hb8[3])*u0[3]
           + b2f(hb8[4])*u1[0] + b2f(hb8[5])*u1[1] + b2f(hb8[6])*u1[2] + b2f(hb8[7])*u1[3];
      }
      lgaw[nl][hd][t] = a * 0.17677669529663687f;
    }
  }
  __syncthreads();

  // --- phase 4: softmax over t ---
  if (tid < 32) {
    int nl = tid >> 2, hd = tid & 3;
    float mx = -1e30f;
    #pragma unroll
    for (int t = 0; t < TT; ++t) mx = fmaxf(mx, lgaw[nl][hd][t]);
    float ex[TT], sm = 0.f;
    #pragma unroll
    for (int t = 0; t < TT; ++t) { ex[t] = expf(lgaw[nl][hd][t] - mx); sm += ex[t]; }
    float inv = 1.f / sm;
    #pragma unroll
    for (int t = 0; t < TT; ++t) lgaw[nl][hd][t] = ex[t] * inv;
  }
  __syncthreads();

  // --- phase 5: w_h = sum_t alpha*h_t -> wB bf16 (Pw-GEMM A operand) ---
  {
    #pragma unroll
    for (int r = 0; r < 4; ++r) {
      int nl = g*4 + r;
      float wacc[NH] = {0.f, 0.f, 0.f, 0.f};
      #pragma unroll
      for (int t = 0; t < TT; ++t) {
        float hv = b2f(hsB[nl][t][j]);
        #pragma unroll
        for (int hd = 0; hd < NH; ++hd) wacc[hd] += lgaw[nl][hd][t] * hv;
      }
      #pragma unroll
      for (int hd = 0; hd < NH; ++hd) wB[nl*520 + hd*128 + j] = f2b(wacc[hd]);
    }
  }
  __syncthreads();

  // --- phase 6: oa = w @ Pw via MFMA; r1 = h11 + oa -> r1F ---
  {
    int arow = lane & 15, akg = lane >> 4;
    fvec4 pacc0 = {0.f,0.f,0.f,0.f}, pacc1 = {0.f,0.f,0.f,0.f};
    const bs8* bp = (const bs8*)PwF;
    const bs8* bq0 = bp + (w*2 + 0)*1024 + lane;  // frag idx (nt*16+kk)*64+lane
    const bs8* bq1 = bp + (w*2 + 1)*1024 + lane;
    #pragma unroll
    for (int kk = 0; kk < 16; ++kk) {
      bs8 af = *(const bs8*)&wB[arow*520 + kk*32 + akg*8];
      pacc0 = mfma16(af, bq0[kk*64], pacc0);
      pacc1 = mfma16(af, bq1[kk*64], pacc1);
    }
    __syncthreads();                             // wB dead before r1F overlay write
    if (lane < 32) {
      int drow = (lane >> 4)*4, dc = lane & 15;
      #pragma unroll
      for (int reg = 0; reg < 4; ++reg) {
        int nd = drow + reg;
        int c0 = (w*2 + 0)*16 + dc;
        int c1 = (w*2 + 1)*16 + dc;
        r1F[nd*132 + c0] = hlastF[nd][c0] + pacc0[reg];
        r1F[nd*132 + c1] = hlastF[nd][c1] + pacc1[reg];
      }
    }
  }
  __syncthreads();

  // --- phase 7: LN1 (node = tid>>5, 4 cols/thread, shfl over 32 lanes) ---
  {
    int nd = tid >> 5, l32 = tid & 31;
    float v[4], s = 0.f, q = 0.f;
    #pragma unroll
    for (int k = 0; k < 4; ++k) {
      v[k] = r1F[nd*132 + l32 + k*32];
      s += v[k]; q += v[k]*v[k];
    }
    #pragma unroll
    for (int off = 16; off > 0; off >>= 1) { s += __shfl_xor(s, off); q += __shfl_xor(q, off); }
    float mu = s*(1.f/128.f), var = q*(1.f/128.f) - mu*mu, rs = rsqrtf(var + 1e-5f);
    #pragma unroll
    for (int k = 0; k < 4; ++k) {
      int c = l32 + k*32;
      h1s[nd*132 + c] = (v[k] - mu)*rs*l1gf[c] + l1bf[c];
    }
  }
  __syncthreads();

  // --- phase 8: FFN1 (fp32 VALU, coalesced bf16 weights) ---
  {
    float fa0[4] = {0.f,0.f,0.f,0.f}, fa1[4] = {0.f,0.f,0.f,0.f};
    const unsigned int* W1u = (const unsigned int*)W1n;
    for (int i4 = 0; i4 < 32; ++i4) {
      fvec4 hv[4];
      #pragma unroll
      for (int r = 0; r < 4; ++r) hv[r] = *(const fvec4*)&h1s[(g*4 + r)*132 + i4*4];
      #pragma unroll
      for (int e = 0; e < 4; ++e) {
        unsigned int wv = W1u[(i4*4 + e)*128 + j];
        float w0, w1; up2(wv, w0, w1);
        #pragma unroll
        for (int r = 0; r < 4; ++r) { fa0[r] += w0*hv[r][e]; fa1[r] += w1*hv[r][e]; }
      }
    }
    float b0 = fb1f[2*j], b1 = fb1f[2*j + 1];
    #pragma unroll
    for (int r = 0; r < 4; ++r) {
      f1s[(g*4 + r)*260 + 2*j]     = fmaxf(fa0[r] + b0, 0.f);
      f1s[(g*4 + r)*260 + 2*j + 1] = fmaxf(fa1[r] + b1, 0.f);
    }
  }
  __syncthreads();

  // --- phase 9: FFN2 + residual -> r1F (r2) ---
  {
    float f2[4] = {0.f,0.f,0.f,0.f};
    const uint2* W2u2 = (const uint2*)W2p;
    for (int c4 = 0; c4 < 64; ++c4) {
      fvec4 fv[4];
      #pragma unroll
      for (int r = 0; r < 4; ++r) fv[r] = *(const fvec4*)&f1s[(g*4 + r)*260 + c4*4];
      uint2 wv = W2u2[c4*128 + j];
      float w0,w1,w2,w3; up2(wv.x, w0, w1); up2(wv.y, w2, w3);
      #pragma unroll
      for (int r = 0; r < 4; ++r)
        f2[r] += w0*fv[r][0] + w1*fv[r][1] + w2*fv[r][2] + w3*fv[r][3];
    }
    float fb2v = fb2f[j];
    #pragma unroll
    for (int r = 0; r < 4; ++r) {
      int nl = g*4 + r;
      r1F[nl*132 + j] = h1s[nl*132 + j] + fb2v + f2[r];
    }
  }
  __syncthreads();

  // --- phase 10: LN2 -> hlast (global) ---
  {
    int nd = tid >> 5, l32 = tid & 31;
    float v[4], s = 0.f, q = 0.f;
    #pragma unroll
    for (int k = 0; k < 4; ++k) {
      v[k] = r1F[nd*132 + l32 + k*32];
      s += v[k]; q += v[k]*v[k];
    }
    #pragma unroll
    for (int off = 16; off > 0; off >>= 1) { s += __shfl_xor(s, off); q += __shfl_xor(q, off); }
    float mu = s*(1.f/128.f), var = q*(1.f/128.f) - mu*mu, rs = rsqrtf(var + 1e-5f);
    #pragma unroll
    for (int k = 0; k < 4; ++k) {
      int c = l32 + k*32;
      hlast[(size_t)(m0 + nd)*HD + c] = (v[k] - mu)*rs*l2gf[c] + l2bf[c];
    }
  }
}

// ---------------- CSR build (batch-shared, dtype-independent) ---------------
__global__ __launch_bounds__(256) void k_zero(int* __restrict__ cnt)
{
  int i = blockIdx.x * 256 + threadIdx.x;
  if (i < NN) cnt[i] = 0;
}

__global__ __launch_bounds__(256) void k_hist(const int* __restrict__ e1,
                                              int* __restrict__ cnt)
{
  int i = blockIdx.x * 256 + threadIdx.x;
  if (i < EE) atomicAdd(&cnt[e1[i]], 1);
}

__global__ __launch_bounds__(1024) void k_scan(const int* __restrict__ cnt,
                                               int* __restrict__ row_ptr,
                                               int* __restrict__ cur)
{
  __shared__ int sm[1024];
  int tid = threadIdx.x;
  int base = tid * 10;
  int loc[10];
  int s = 0;
  #pragma unroll
  for (int k = 0; k < 10; ++k) {
    int idx = base + k;
    int v = (idx < NN) ? cnt[idx] : 0;
    loc[k] = s;
    s += v;
  }
  sm[tid] = s;
  __syncthreads();
  for (int off = 1; off < 1024; off <<= 1) {
    int t = (tid >= off) ? sm[tid - off] : 0;
    __syncthreads();
    sm[tid] += t;
    __syncthreads();
  }
  int segbase = sm[tid] - s;
  #pragma unroll
  for (int k = 0; k < 10; ++k) {
    int idx = base + k;
    if (idx < NN) { int o = segbase + loc[k]; row_ptr[idx] = o; cur[idx] = o; }
  }
  if (tid == 1023) row_ptr[NN] = sm[1023];
}

__global__ __launch_bounds__(256) void k_scatter(const int* __restrict__ e0,
                                                 const int* __restrict__ e1,
                                                 int* __restrict__ cur,
                                                 int* __restrict__ ssrc)
{
  int i = blockIdx.x * 256 + threadIdx.x;
  if (i >= EE) return;
  int pos = atomicAdd(&cur[e1[i]], 1);
  ssrc[pos] = e0[i];
}

// ---------------- GAT1 ------------------------------------------------------
template<typename TI>
__global__ __launch_bounds__(128) void k_gat1_pre(
    const int* __restrict__ flag, int want,
    const float* __restrict__ hlast, const void* gW_, const void* asr_, const void* adr_,
    float* __restrict__ xl, float* __restrict__ s1, float* __restrict__ d1)
{
  if (*flag != want) return;
  const TI* gW  = (const TI*)gW_;
  const TI* asr = (const TI*)asr_;
  const TI* adr = (const TI*)adr_;
  __shared__ float hrow[HD];
  int j = threadIdx.x, m = blockIdx.x;
  hrow[j] = hlast[(size_t)m*HD + j];
  __syncthreads();
  float a = 0.f;
  for (int i = 0; i < HD; ++i) a += hrow[i] * cv(gW[i*HD + j]);
  xl[(size_t)m*HD + j] = a;
  float pa = a * cv(asr[j]);
  float pb = a * cv(adr[j]);
  #pragma unroll
  for (int off = 16; off > 0; off >>= 1) { pa += __shfl_xor(pa, off); pb += __shfl_xor(pb, off); }
  if ((j & 31) == 0) {
    int h = j >> 5;
    s1[m*NH + h] = pa;
    d1[m*NH + h] = pb;
  }
}

template<typename TI>
__global__ __launch_bounds__(128) void k_gat1_gather(
    const int* __restrict__ flag, int want,
    const int* __restrict__ row_ptr, const int* __restrict__ ssrc,
    const float* __restrict__ xl, const float* __restrict__ s1, const float* __restrict__ d1,
    const void* gb_, float* __restrict__ g1o)
{
  if (*flag != want) return;
  const TI* gb = (const TI*)gb_;
  int j = threadIdx.x, m = blockIdx.x, h = j >> 5;
  int b = m / NN, n = m - b * NN, boff = b * NN;
  float dh = d1[m*NH + h];
  int r0 = row_ptr[n], r1 = row_ptr[n+1];
  float acc = 0.f, dsum = 0.f;
  for (int e = r0; e < r1; ++e) {
    int src = ssrc[e] + boff;
    float ev = expf(lrelu(s1[src*NH + h] + dh));
    acc  += ev * xl[(size_t)src*HD + j];
    dsum += ev;
  }
  float es = expf(lrelu(s1[m*NH + h] + dh));
  acc  += es * xl[(size_t)m*HD + j];
  dsum += es;
  float v = acc / (dsum + 1e-16f) + cv(gb[j]);
  g1o[(size_t)m*HD + j] = v > 0.f ? v : expm1f(v);
}

// ---------------- GAT2 ------------------------------------------------------
template<typename TI>
__global__ __launch_bounds__(64) void k_gat2_pre(
    const int* __restrict__ flag, int want,
    const float* __restrict__ g1o, const void* gW_, const void* asr_, const void* adr_,
    float* __restrict__ xl2, float* __restrict__ s2, float* __restrict__ d2)
{
  if (*flag != want) return;
  const TI* gW  = (const TI*)gW_;
  const TI* asr = (const TI*)asr_;
  const TI* adr = (const TI*)adr_;
  __shared__ float grow[HD];
  int j = threadIdx.x, m = blockIdx.x;
  grow[j]      = g1o[(size_t)m*HD + j];
  grow[j + 64] = g1o[(size_t)m*HD + j + 64];
  __syncthreads();
  float a = 0.f;
  for (int i = 0; i < HD; ++i) a += grow[i] * cv(gW[i*GO + j]);
  xl2[(size_t)m*GO + j] = a;
  float pa = a * cv(asr[j]);
  float pb = a * cv(adr[j]);
  #pragma unroll
  for (int off = 32; off > 0; off >>= 1) { pa += __shfl_xor(pa, off); pb += __shfl_xor(pb, off); }
  if (j == 0) { s2[m] = pa; d2[m] = pb; }
}

template<typename TI, typename TO>
__global__ __launch_bounds__(64) void k_gat2_gather(
    const int* __restrict__ flag, int want,
    const int* __restrict__ row_ptr, const int* __restrict__ ssrc,
    const float* __restrict__ xl2, const float* __restrict__ s2, const float* __restrict__ d2,
    const void* gb_, const void* oW_, const void* ob_, void* y_)
{
  if (*flag != want) return;
  const TI* gb = (const TI*)gb_;
  const TI* oW = (const TI*)oW_;
  const TI* ob = (const TI*)ob_;
  TO* y = (TO*)y_;
  __shared__ float g2s[GO];
  int j = threadIdx.x, m = blockIdx.x;
  int b = m / NN, n = m - b * NN, boff = b * NN;
  float d2m = d2[m];
  int r0 = row_ptr[n], r1 = row_ptr[n+1];
  float acc = 0.f, dsum = 0.f;
  for (int e = r0; e < r1; ++e) {
    int src = ssrc[e] + boff;
    float ev = expf(lrelu(s2[src] + d2m));
    acc  += ev * xl2[(size_t)src*GO + j];
    dsum += ev;
  }
  float es = expf(lrelu(s2[m] + d2m));
  acc  += es * xl2[(size_t)m*GO + j];
  dsum += es;
  g2s[j] = acc / (dsum + 1e-16f) + cv(gb[j]);
  __syncthreads();
  if (j < HR) {
    float a = cv(ob[j]);
    #pragma unroll
    for (int o2 = 0; o2 < GO; ++o2) a += g2s[o2] * cv(oW[o2*HR + j]);
    st(&y[((size_t)b*HR + j)*NN + n], a);
  }
}

// ---------------- launch ----------------------------------------------------
extern "C" void kernel_launch(void* const* d_in, const int* in_sizes, int n_in,
                              void* d_out, int out_size, void* d_ws, size_t ws_size,
                              hipStream_t stream)
{
  const int* ei = (const int*)d_in[2];
  const int* e0 = ei;
  const int* e1 = ei + EE;

  float* ws    = (float*)d_ws;
  float* hlast = ws;                  // 40000*128
  float* xl1   = ws + 5120000;        // 40000*128
  float* ovl   = ws + 10240000;       // overlap region (weights, then CSR)
  float* s1    = ws + 15360000;       // 40000*4
  float* d1    = ws + 15520000;       // 40000*4
  int*   flag  = (int*)(ws + 15680000);

  // Weight buffers live [prep, xform] in the overlap region.
  unsigned short* Mu  = (unsigned short*)ovl;              // 65536 bf16 (frag order)
  unsigned short* Pw  = Mu + 65536;                        // 65536 bf16 (frag order)
  unsigned short* W1n = Mu + 131072;
  unsigned short* W2p = Mu + 163840;
  float* encWf = (float*)(Mu + 196608);
  float* encBf = encWf + 2048;
  float* fb1f  = encBf + 128;
  float* fb2f  = fb1f + 256;
  float* l1gf  = fb2f + 128;
  float* l1bf  = l1gf + 128;
  float* l2gf  = l1bf + 128;
  float* l2bf  = l2gf + 128;

  // CSR arrays live [hist, end] in the SAME overlap region (stream-serial).
  int* cnt     = (int*)ovl;           // 10000
  int* row_ptr = cnt + 16384;         // 10001
  int* cur     = cnt + 32768;         // 10000
  int* ssrc    = cnt + 49152;         // 160000

  // phase-2 aliases (lifetimes disjoint)
  float* g1o  = hlast;
  float* xl2  = xl1;
  float* s2 = s1; float* d2 = d1;

  k_detect<<<1, 1, 0, stream>>>(d_in[0], flag);

  k_prep<float><<<780, 256, 0, stream>>>(flag, 0,
      d_in[5], d_in[6], d_in[7], d_in[8],
      d_in[3], d_in[4], d_in[11], d_in[12], d_in[13], d_in[14],
      d_in[9], d_in[10], d_in[15], d_in[16],
      Mu, Pw, W1n, W2p, encWf, encBf, fb1f, fb2f, l1gf, l1bf, l2gf, l2bf);
  k_prep<__hip_bfloat16><<<780, 256, 0, stream>>>(flag, 1,
      d_in[5], d_in[6], d_in[7], d_in[8],
      d_in[3], d_in[4], d_in[11], d_in[12], d_in[13], d_in[14],
      d_in[9], d_in[10], d_in[15], d_in[16],
      Mu, Pw, W1n, W2p, encWf, encBf, fb1f, fb2f, l1gf, l1bf, l2gf, l2bf);

  k_xform<float><<<MM/8, 256, 0, stream>>>(flag, 0,
      d_in[0], d_in[1], Mu, Pw, W1n, W2p,
      encWf, encBf, fb1f, fb2f, l1gf, l1bf, l2gf, l2bf, hlast);
  k_xform<__hip_bfloat16><<<MM/8, 256, 0, stream>>>(flag, 1,
      d_in[0], d_in[1], Mu, Pw, W1n, W2p,
      encWf, encBf, fb1f, fb2f, l1gf, l1bf, l2gf, l2bf, hlast);

  // CSR build (after xform: overlap region is free now)
  k_zero<<<(NN + 255)/256, 256, 0, stream>>>(cnt);
  k_hist<<<(EE + 255)/256, 256, 0, stream>>>(e1, cnt);
  k_scan<<<1, 1024, 0, stream>>>(cnt, row_ptr, cur);
  k_scatter<<<(EE + 255)/256, 256, 0, stream>>>(e0, e1, cur, ssrc);

  k_gat1_pre<float><<<MM, 128, 0, stream>>>(flag, 0, hlast,
      d_in[17], d_in[18], d_in[19], xl1, s1, d1);
  k_gat1_pre<__hip_bfloat16><<<MM, 128, 0, stream>>>(flag, 1, hlast,
      d_in[17], d_in[18], d_in[19], xl1, s1, d1);

  k_gat1_gather<float><<<MM, 128, 0, stream>>>(flag, 0,
      row_ptr, ssrc, xl1, s1, d1, d_in[20], g1o);
  k_gat1_gather<__hip_bfloat16><<<MM, 128, 0, stream>>>(flag, 1,
      row_ptr, ssrc, xl1, s1, d1, d_in[20], g1o);

  k_gat2_pre<float><<<MM, 64, 0, stream>>>(flag, 0, g1o,
      d_in[21], d_in[22], d_in[23], xl2, s2, d2);
  k_gat2_pre<__hip_bfloat16><<<MM, 64, 0, stream>>>(flag, 1, g1o,
      d_in[21], d_in[22], d_in[23], xl2, s2, d2);

  k_gat2_gather<float, float><<<MM, 64, 0, stream>>>(flag, 0,
      row_ptr, ssrc, xl2, s2, d2, d_in[24], d_in[25], d_in[26], d_out);
  k_gat2_gather<__hip_bfloat16, __hip_bfloat16><<<MM, 64, 0, stream>>>(flag, 1,
      row_ptr, ssrc, xl2, s2, d2, d_in[24], d_in[25], d_in[26], d_out);
}

// Round 7
// 463.299 us; speedup vs baseline: 4.0051x; 1.2432x over previous
//
#include <hip/hip_runtime.h>
#include <hip/hip_bf16.h>

#define DEV static __device__ __forceinline__

constexpr int BB = 4;        // batches
constexpr int TT = 12;       // timesteps
constexpr int NN = 10000;    // nodes per batch
constexpr int FD = 16;       // input features (8+8)
constexpr int HD = 128;      // hidden
constexpr int NH = 4;        // attn heads
constexpr int DH = 32;       // head dim
constexpr int FF = 256;      // ffn hidden
constexpr int GO = 64;       // gat2 out
constexpr int HR = 24;       // horizon
constexpr int EE = 160000;   // edges per batch
constexpr int MM = BB * NN;  // total nodes

typedef unsigned short bvec8 __attribute__((ext_vector_type(8)));
typedef float fvec4 __attribute__((ext_vector_type(4)));
typedef short bs8 __attribute__((ext_vector_type(8)));      // MFMA bf16 frag (4 VGPR)

DEV float cv(float x) { return x; }
DEV float cv(__hip_bfloat16 x) { return __bfloat162float(x); }
DEV void st(float* p, float v) { *p = v; }
DEV void st(__hip_bfloat16* p, float v) { *p = __float2bfloat16(v); }
DEV float lrelu(float x) { return x >= 0.f ? x : 0.2f * x; }

DEV float b2f(unsigned short u) {
  union { unsigned int i; float f; } x; x.i = ((unsigned int)u) << 16; return x.f;
}
DEV unsigned short f2b(float f) {
  union { float f; unsigned int i; } x; x.f = f;
  unsigned int r = x.i + 0x7FFFu + ((x.i >> 16) & 1u);
  return (unsigned short)(r >> 16);
}
DEV void up2(unsigned int u, float& lo, float& hi) {
  union { unsigned int i; float f; } a, b;
  a.i = u << 16; b.i = u & 0xFFFF0000u;
  lo = a.f; hi = b.f;
}

DEV fvec4 mfma16(bs8 a, bs8 b, fvec4 c) {
  return __builtin_amdgcn_mfma_f32_16x16x32_bf16(a, b, c, 0, 0, 0);
}

// ---------------- dtype detection (profile-verified: fp32 -> flag=0) --------
__global__ void k_detect(const void* x, int* flag)
{
  const __hip_bfloat16* p = (const __hip_bfloat16*)x;
  int sane = 0;
  for (int i = 0; i < 256; ++i) {
    float v = __bfloat162float(p[i]);
    if (fabsf(v) <= 1024.f) sane++;
  }
  *flag = (sane >= 250) ? 1 : 0;
}

// ---------------- prep: fold + re-layout ALL transformer weights ------------
// All matmul weights emitted in MFMA B-fragment order:
//   frag idx = ((nt*nK + kk)*64 + lane), element e: B[k][n] with
//   k = kk*32 + (lane>>4)*8 + e, n = nt*16 + (lane&15).
//   MuF: K=128,N=512 (u-GEMM); PwF: K=512,N=128; W1F: K=128,N=256;
//   W2F: K=256,N=128; encWF: K=32 (rows 16-31 zero), N=128.
template<typename TI>
__global__ __launch_bounds__(256) void k_prep(
    const int* __restrict__ flag, int want,
    const void* Wq_, const void* Wk_, const void* Wv_, const void* Wo_,
    const void* encW_, const void* encB_, const void* W1_, const void* fb1_,
    const void* W2_, const void* fb2_,
    const void* l1g_, const void* l1b_, const void* l2g_, const void* l2b_,
    unsigned short* __restrict__ Mu, unsigned short* __restrict__ Pw,
    unsigned short* __restrict__ W1F, unsigned short* __restrict__ W2F,
    unsigned short* __restrict__ encWF, float* __restrict__ encBf,
    float* __restrict__ fb1f, float* __restrict__ fb2f,
    float* __restrict__ l1gf, float* __restrict__ l1bf,
    float* __restrict__ l2gf, float* __restrict__ l2bf)
{
  if (*flag != want) return;
  const TI* Wq = (const TI*)Wq_;   const TI* Wk = (const TI*)Wk_;
  const TI* Wv = (const TI*)Wv_;   const TI* Wo = (const TI*)Wo_;
  const TI* encW = (const TI*)encW_; const TI* encB = (const TI*)encB_;
  const TI* W1 = (const TI*)W1_;   const TI* fb1 = (const TI*)fb1_;
  const TI* W2 = (const TI*)W2_;   const TI* fb2 = (const TI*)fb2_;
  const TI* l1g = (const TI*)l1g_; const TI* l1b = (const TI*)l1b_;
  const TI* l2g = (const TI*)l2g_; const TI* l2b = (const TI*)l2b_;
  int idx = blockIdx.x * 256 + threadIdx.x;      // 788*256 = 201728 exactly
  if (idx < 65536) {
    // MuF: B[i][q] = sum_d Wq[i][h*32+d]*Wk[c][h*32+d], q=(h,c). nK=4.
    int e = idx & 7, lane = (idx >> 3) & 63, kk = (idx >> 9) & 3, nt = idx >> 11;
    int i = kk*32 + (lane >> 4)*8 + e;
    int q = nt*16 + (lane & 15);
    int h = q >> 7, c = q & 127;
    float a = 0.f;
    #pragma unroll 8
    for (int d = 0; d < DH; ++d)
      a += cv(Wq[i*HD + h*DH + d]) * cv(Wk[c*HD + h*DH + d]);
    Mu[idx] = f2b(a);
  } else if (idx < 131072) {
    // PwF: B[q][j] = sum_d Wv[i][h*32+d]*Wo[h*32+d][j], q=(h,i). nK=16.
    int g2 = idx - 65536;
    int e = g2 & 7, lane = (g2 >> 3) & 63, kk = (g2 >> 9) & 15, nt = g2 >> 13;
    int q = kk*32 + (lane >> 4)*8 + e;
    int j = nt*16 + (lane & 15);
    int h = q >> 7, i = q & 127;
    float a = 0.f;
    #pragma unroll 8
    for (int d = 0; d < DH; ++d)
      a += cv(Wv[i*HD + h*DH + d]) * cv(Wo[(h*DH + d)*HD + j]);
    Pw[g2] = f2b(a);
  } else if (idx < 163840) {
    // W1F: B = W1 [128][256]. nK=4, nt 0..15.
    int g = idx - 131072;
    int e = g & 7, lane = (g >> 3) & 63, kk = (g >> 9) & 3, nt = g >> 11;
    int k = kk*32 + (lane >> 4)*8 + e;
    int n = nt*16 + (lane & 15);
    W1F[g] = f2b(cv(W1[k*FF + n]));
  } else if (idx < 196608) {
    // W2F: B = W2 [256][128]. nK=8, nt 0..7.
    int g = idx - 163840;
    int e = g & 7, lane = (g >> 3) & 63, kk = (g >> 9) & 7, nt = g >> 12;
    int k = kk*32 + (lane >> 4)*8 + e;
    int n = nt*16 + (lane & 15);
    W2F[g] = f2b(cv(W2[k*HD + n]));
  } else if (idx < 200704) {
    // encWF: B = encW [16][128] zero-padded to K=32. nK=1, nt 0..7.
    int g = idx - 196608;
    int e = g & 7, lane = (g >> 3) & 63, nt = g >> 9;
    int k = (lane >> 4)*8 + e;
    int n = nt*16 + (lane & 15);
    encWF[g] = (k < FD) ? f2b(cv(encW[k*HD + n])) : (unsigned short)0;
  } else if (idx < 200832) { int t = idx - 200704; encBf[t] = cv(encB[t]); }
  else if (idx < 201088)   { int t = idx - 200832; fb1f[t] = cv(fb1[t]); }
  else if (idx < 201216)   { int t = idx - 201088; fb2f[t] = cv(fb2[t]); }
  else if (idx < 201344)   { int t = idx - 201216; l1gf[t] = cv(l1g[t]); }
  else if (idx < 201472)   { int t = idx - 201344; l1bf[t] = cv(l1b[t]); }
  else if (idx < 201600)   { int t = idx - 201472; l2gf[t] = cv(l2g[t]); }
  else                     { int t = idx - 201600; l2bf[t] = cv(l2b[t]); }
}

// ---------------- fused transformer (8 nodes/block, MFMA everywhere) --------
template<typename TI>
__global__ __launch_bounds__(256) void k_xform(
    const int* __restrict__ flag, int want,
    const void* xh_, const void* xc_,
    const unsigned short* __restrict__ MuF, const unsigned short* __restrict__ PwF,
    const unsigned short* __restrict__ W1F, const unsigned short* __restrict__ W2F,
    const unsigned short* __restrict__ encWF, const float* __restrict__ encBf,
    const float* __restrict__ fb1f, const float* __restrict__ fb2f,
    const float* __restrict__ l1gf, const float* __restrict__ l1bf,
    const float* __restrict__ l2gf, const float* __restrict__ l2bf,
    float* __restrict__ hlast)
{
  if (*flag != want) return;
  const TI* xh = (const TI*)xh_;
  const TI* xc = (const TI*)xc_;

  // big: hsB (ph1-5), then {r1F,h1s,h1B,f1B,r2F} (ph6-10) -- disjoint lifetimes
  __shared__ __align__(16) char big[26112];
  __shared__ float hlastF[8][128];
  __shared__ unsigned short hlastB[16*136];    // rows 8-15 junk -> D discarded
  __shared__ float lgaw[8][NH][TT];
  __shared__ __align__(16) char regB[16896];   // xB -> usF -> wB

  unsigned short* hsB = (unsigned short*)big;          // [(nl*12+t)][136]
  float* r1F = (float*)big;                            // [8][132] ph6-7
  float* h1s = (float*)(big + 4224);                   // [8][132] ph7-9
  unsigned short* h1B = (unsigned short*)(big + 8448); // [16][136] ph7-8
  unsigned short* f1B = (unsigned short*)(big + 12800);// [16][264] ph8-9
  float* r2F = (float*)(big + 8448);                   // [8][132] ph9-10 (over h1B)

  unsigned short* xB = (unsigned short*)regB;          // [96][40] ph0-1
  float* usF = (float*)regB;                           // [8][4][132] ph2-3
  unsigned short* wB = (unsigned short*)regB;          // [16][520] ph5-6

  const int tid  = threadIdx.x;
  const int w    = tid >> 6;
  const int lane = tid & 63;
  const int m0   = blockIdx.x * 8;
  const int arow = lane & 15, akg = lane >> 4;

  // --- phase 0: load x -> xB bf16, rows = t*8+nl, K zero-padded 16..31 ---
  #pragma unroll
  for (int k = 0; k < 6; ++k) {
    int idx = tid + k*256;
    int f = idx & 15, rest = idx >> 4;      // rest 0..95
    int nl = rest & 7, t = rest >> 3;
    int m = m0 + nl, b = m / NN, n = m - b*NN;
    float v = (f < 8) ? cv(xh[(((size_t)b*TT + t)*NN + n)*8 + f])
                      : cv(xc[(((size_t)b*TT + t)*NN + n)*8 + (f - 8)]);
    xB[(t*8 + nl)*40 + f] = f2b(v);
  }
  #pragma unroll
  for (int k = 0; k < 6; ++k) {
    int idx = tid + k*256;
    xB[(idx >> 4)*40 + 16 + (idx & 15)] = 0;
  }
  __syncthreads();

  // --- phase 1: encoder via MFMA (96x128 = 6 mt x 8 nt tiles) ---
  {
    const bs8* ef = (const bs8*)encWF;
    bs8 b0 = ef[(2*w + 0)*64 + lane];
    bs8 b1 = ef[(2*w + 1)*64 + lane];
    int drow = akg*4, dc = arow;
    int j0 = (2*w + 0)*16 + dc, j1 = (2*w + 1)*16 + dc;
    float eb0 = encBf[j0], eb1 = encBf[j1];
    fvec4 z4 = {0.f, 0.f, 0.f, 0.f};
    #pragma unroll
    for (int mt = 0; mt < 6; ++mt) {
      bs8 af = *(const bs8*)&xB[(mt*16 + arow)*40 + akg*8];
      fvec4 d0 = mfma16(af, b0, z4);
      fvec4 d1 = mfma16(af, b1, z4);
      #pragma unroll
      for (int reg = 0; reg < 4; ++reg) {
        int gr = mt*16 + drow + reg;
        int t = gr >> 3, nl = gr & 7;
        float v0 = d0[reg] + eb0, v1 = d1[reg] + eb1;
        hsB[(nl*12 + t)*136 + j0] = f2b(v0);
        hsB[(nl*12 + t)*136 + j1] = f2b(v1);
        if (t == TT-1) {
          hlastF[nl][j0] = v0; hlastB[nl*136 + j0] = f2b(v0);
          hlastF[nl][j1] = v1; hlastB[nl*136 + j1] = f2b(v1);
        }
      }
    }
  }
  __syncthreads();                // xB dead

  // --- phase 2: u = h_last @ Mu via MFMA -> usF fp32 ---
  {
    bs8 af[4];
    #pragma unroll
    for (int kk = 0; kk < 4; ++kk)
      af[kk] = *(const bs8*)&hlastB[arow*136 + kk*32 + akg*8];
    const bs8* bp = (const bs8*)MuF;
    fvec4 acc[8];
    #pragma unroll
    for (int n8 = 0; n8 < 8; ++n8) {
      int nt = w*8 + n8;
      const bs8* bq = bp + nt*256 + lane;
      fvec4 a4 = {0.f, 0.f, 0.f, 0.f};
      #pragma unroll
      for (int kk = 0; kk < 4; ++kk)
        a4 = mfma16(af[kk], bq[kk*64], a4);
      acc[n8] = a4;
    }
    if (lane < 32) {                            // valid D rows 0..7 only
      int drow = akg*4, dc = arow;
      #pragma unroll
      for (int n8 = 0; n8 < 8; ++n8) {
        int col = (w*8 + n8)*16 + dc, hd = col >> 7, c = col & 127;
        #pragma unroll
        for (int reg = 0; reg < 4; ++reg)
          usF[((drow + reg)*4 + hd)*132 + c] = acc[n8][reg];
      }
    }
  }
  __syncthreads();

  // --- phase 3: logits (8n x 4h x 12t = 384 dots of K=128) ---
  #pragma unroll
  for (int pass = 0; pass < 2; ++pass) {
    int item = pass*256 + tid;
    if (item < 384) {
      int nl = item / 48, p = item - nl*48, hd = p / 12, t = p - hd*12;
      const float* up = &usF[(nl*4 + hd)*132];
      float a = 0.f;
      for (int i8 = 0; i8 < 16; ++i8) {
        bvec8 hb8 = *(const bvec8*)&hsB[(nl*12 + t)*136 + i8*8];
        const fvec4* uq = (const fvec4*)&up[i8*8];
        fvec4 u0 = uq[0], u1 = uq[1];
        a += b2f(hb8[0])*u0[0] + b2f(hb8[1])*u0[1] + b2f(hb8[2])*u0[2] + b2f(hb8[3])*u0[3]
           + b2f(hb8[4])*u1[0] + b2f(hb8[5])*u1[1] + b2f(hb8[6])*u1[2] + b2f(hb8[7])*u1[3];
      }
      lgaw[nl][hd][t] = a * 0.17677669529663687f;
    }
  }
  __syncthreads();

  // --- phase 4: softmax over t ---
  if (tid < 32) {
    int nl = tid >> 2, hd = tid & 3;
    float mx = -1e30f;
    #pragma unroll
    for (int t = 0; t < TT; ++t) mx = fmaxf(mx, lgaw[nl][hd][t]);
    float ex[TT], sm = 0.f;
    #pragma unroll
    for (int t = 0; t < TT; ++t) { ex[t] = expf(lgaw[nl][hd][t] - mx); sm += ex[t]; }
    float inv = 1.f / sm;
    #pragma unroll
    for (int t = 0; t < TT; ++t) lgaw[nl][hd][t] = ex[t] * inv;
  }
  __syncthreads();

  // --- phase 5: w_h = sum_t alpha*h_t -> wB bf16 (over usF) ---
  {
    int g = tid >> 7, j = tid & 127;
    #pragma unroll
    for (int r = 0; r < 4; ++r) {
      int nl = g*4 + r;
      float wacc[NH] = {0.f, 0.f, 0.f, 0.f};
      #pragma unroll
      for (int t = 0; t < TT; ++t) {
        float hv = b2f(hsB[(nl*12 + t)*136 + j]);
        #pragma unroll
        for (int hd = 0; hd < NH; ++hd) wacc[hd] += lgaw[nl][hd][t] * hv;
      }
      #pragma unroll
      for (int hd = 0; hd < NH; ++hd) wB[nl*520 + hd*128 + j] = f2b(wacc[hd]);
    }
  }
  __syncthreads();                // hsB dead after this point

  // --- phase 6: oa = w @ Pw via MFMA; r1 = h_last + oa -> r1F (over hsB) ---
  {
    fvec4 pacc0 = {0.f,0.f,0.f,0.f}, pacc1 = {0.f,0.f,0.f,0.f};
    const bs8* bp = (const bs8*)PwF;
    const bs8* bq0 = bp + (w*2 + 0)*1024 + lane;
    const bs8* bq1 = bp + (w*2 + 1)*1024 + lane;
    #pragma unroll
    for (int kk = 0; kk < 16; ++kk) {
      bs8 af = *(const bs8*)&wB[arow*520 + kk*32 + akg*8];
      pacc0 = mfma16(af, bq0[kk*64], pacc0);
      pacc1 = mfma16(af, bq1[kk*64], pacc1);
    }
    if (lane < 32) {
      int drow = akg*4, dc = arow;
      #pragma unroll
      for (int reg = 0; reg < 4; ++reg) {
        int nd = drow + reg;
        int c0 = (w*2 + 0)*16 + dc;
        int c1 = (w*2 + 1)*16 + dc;
        r1F[nd*132 + c0] = hlastF[nd][c0] + pacc0[reg];
        r1F[nd*132 + c1] = hlastF[nd][c1] + pacc1[reg];
      }
    }
  }
  __syncthreads();

  // --- phase 7: LN1 -> h1s fp32 + h1B bf16 ---
  {
    int nd = tid >> 5, l32 = tid & 31;
    float v[4], s = 0.f, q = 0.f;
    #pragma unroll
    for (int k = 0; k < 4; ++k) {
      v[k] = r1F[nd*132 + l32 + k*32];
      s += v[k]; q += v[k]*v[k];
    }
    #pragma unroll
    for (int off = 16; off > 0; off >>= 1) { s += __shfl_xor(s, off); q += __shfl_xor(q, off); }
    float mu = s*(1.f/128.f), var = q*(1.f/128.f) - mu*mu, rs = rsqrtf(var + 1e-5f);
    #pragma unroll
    for (int k = 0; k < 4; ++k) {
      int c = l32 + k*32;
      float hv = (v[k] - mu)*rs*l1gf[c] + l1bf[c];
      h1s[nd*132 + c] = hv;
      h1B[nd*136 + c] = f2b(hv);
    }
  }
  __syncthreads();

  // --- phase 8: FFN1 via MFMA (K=128, N=256), relu+bias fused -> f1B bf16 ---
  {
    bs8 af[4];
    #pragma unroll
    for (int kk = 0; kk < 4; ++kk)
      af[kk] = *(const bs8*)&h1B[arow*136 + kk*32 + akg*8];
    const bs8* bp = (const bs8*)W1F;
    #pragma unroll
    for (int n4 = 0; n4 < 4; ++n4) {
      int nt = w*4 + n4;
      const bs8* bq = bp + nt*256 + lane;
      fvec4 a4 = {0.f, 0.f, 0.f, 0.f};
      #pragma unroll
      for (int kk = 0; kk < 4; ++kk)
        a4 = mfma16(af[kk], bq[kk*64], a4);
      if (lane < 32) {
        int drow = akg*4, dc = arow;
        int n = nt*16 + dc;
        float bias = fb1f[n];
        #pragma unroll
        for (int reg = 0; reg < 4; ++reg)
          f1B[(drow + reg)*264 + n] = f2b(fmaxf(a4[reg] + bias, 0.f));
      }
    }
  }
  __syncthreads();

  // --- phase 9: FFN2 via MFMA (K=256, N=128) + residual -> r2F (over h1B) ---
  {
    const bs8* bp = (const bs8*)W2F;
    #pragma unroll
    for (int n2 = 0; n2 < 2; ++n2) {
      int nt = w*2 + n2;
      const bs8* bq = bp + nt*512 + lane;
      fvec4 a4 = {0.f, 0.f, 0.f, 0.f};
      #pragma unroll
      for (int kk = 0; kk < 8; ++kk) {
        bs8 af = *(const bs8*)&f1B[arow*264 + kk*32 + akg*8];
        a4 = mfma16(af, bq[kk*64], a4);
      }
      if (lane < 32) {
        int drow = akg*4, dc = arow;
        int c = nt*16 + dc;
        float fb2v = fb2f[c];
        #pragma unroll
        for (int reg = 0; reg < 4; ++reg) {
          int nd = drow + reg;
          r2F[nd*132 + c] = h1s[nd*132 + c] + fb2v + a4[reg];
        }
      }
    }
  }
  __syncthreads();

  // --- phase 10: LN2 -> hlast (global) ---
  {
    int nd = tid >> 5, l32 = tid & 31;
    float v[4], s = 0.f, q = 0.f;
    #pragma unroll
    for (int k = 0; k < 4; ++k) {
      v[k] = r2F[nd*132 + l32 + k*32];
      s += v[k]; q += v[k]*v[k];
    }
    #pragma unroll
    for (int off = 16; off > 0; off >>= 1) { s += __shfl_xor(s, off); q += __shfl_xor(q, off); }
    float mu = s*(1.f/128.f), var = q*(1.f/128.f) - mu*mu, rs = rsqrtf(var + 1e-5f);
    #pragma unroll
    for (int k = 0; k < 4; ++k) {
      int c = l32 + k*32;
      hlast[(size_t)(m0 + nd)*HD + c] = (v[k] - mu)*rs*l2gf[c] + l2bf[c];
    }
  }
}

// ---------------- CSR build (batch-shared, dtype-independent) ---------------
__global__ __launch_bounds__(256) void k_zero(int* __restrict__ cnt)
{
  int i = blockIdx.x * 256 + threadIdx.x;
  if (i < NN) cnt[i] = 0;
}

__global__ __launch_bounds__(256) void k_hist(const int* __restrict__ e1,
                                              int* __restrict__ cnt)
{
  int i = blockIdx.x * 256 + threadIdx.x;
  if (i < EE) atomicAdd(&cnt[e1[i]], 1);
}

__global__ __launch_bounds__(1024) void k_scan(const int* __restrict__ cnt,
                                               int* __restrict__ row_ptr,
                                               int* __restrict__ cur)
{
  __shared__ int sm[1024];
  int tid = threadIdx.x;
  int base = tid * 10;
  int loc[10];
  int s = 0;
  #pragma unroll
  for (int k = 0; k < 10; ++k) {
    int idx = base + k;
    int v = (idx < NN) ? cnt[idx] : 0;
    loc[k] = s;
    s += v;
  }
  sm[tid] = s;
  __syncthreads();
  for (int off = 1; off < 1024; off <<= 1) {
    int t = (tid >= off) ? sm[tid - off] : 0;
    __syncthreads();
    sm[tid] += t;
    __syncthreads();
  }
  int segbase = sm[tid] - s;
  #pragma unroll
  for (int k = 0; k < 10; ++k) {
    int idx = base + k;
    if (idx < NN) { int o = segbase + loc[k]; row_ptr[idx] = o; cur[idx] = o; }
  }
  if (tid == 1023) row_ptr[NN] = sm[1023];
}

__global__ __launch_bounds__(256) void k_scatter(const int* __restrict__ e0,
                                                 const int* __restrict__ e1,
                                                 int* __restrict__ cur,
                                                 int* __restrict__ ssrc)
{
  int i = blockIdx.x * 256 + threadIdx.x;
  if (i >= EE) return;
  int pos = atomicAdd(&cur[e1[i]], 1);
  ssrc[pos] = e0[i];
}

// ---------------- GAT1 ------------------------------------------------------
template<typename TI>
__global__ __launch_bounds__(128) void k_gat1_pre(
    const int* __restrict__ flag, int want,
    const float* __restrict__ hlast, const void* gW_, const void* asr_, const void* adr_,
    float* __restrict__ xl, float* __restrict__ s1, float* __restrict__ d1)
{
  if (*flag != want) return;
  const TI* gW  = (const TI*)gW_;
  const TI* asr = (const TI*)asr_;
  const TI* adr = (const TI*)adr_;
  __shared__ float hrow[HD];
  int j = threadIdx.x, m = blockIdx.x;
  hrow[j] = hlast[(size_t)m*HD + j];
  __syncthreads();
  float a = 0.f;
  for (int i = 0; i < HD; ++i) a += hrow[i] * cv(gW[i*HD + j]);
  xl[(size_t)m*HD + j] = a;
  float pa = a * cv(asr[j]);
  float pb = a * cv(adr[j]);
  #pragma unroll
  for (int off = 16; off > 0; off >>= 1) { pa += __shfl_xor(pa, off); pb += __shfl_xor(pb, off); }
  if ((j & 31) == 0) {
    int h = j >> 5;
    s1[m*NH + h] = pa;
    d1[m*NH + h] = pb;
  }
}

template<typename TI>
__global__ __launch_bounds__(128) void k_gat1_gather(
    const int* __restrict__ flag, int want,
    const int* __restrict__ row_ptr, const int* __restrict__ ssrc,
    const float* __restrict__ xl, const float* __restrict__ s1, const float* __restrict__ d1,
    const void* gb_, float* __restrict__ g1o)
{
  if (*flag != want) return;
  const TI* gb = (const TI*)gb_;
  int j = threadIdx.x, m = blockIdx.x, h = j >> 5;
  int b = m / NN, n = m - b * NN, boff = b * NN;
  float dh = d1[m*NH + h];
  int r0 = row_ptr[n], r1 = row_ptr[n+1];
  float acc = 0.f, dsum = 0.f;
  for (int e = r0; e < r1; ++e) {
    int src = ssrc[e] + boff;
    float ev = expf(lrelu(s1[src*NH + h] + dh));
    acc  += ev * xl[(size_t)src*HD + j];
    dsum += ev;
  }
  float es = expf(lrelu(s1[m*NH + h] + dh));
  acc  += es * xl[(size_t)m*HD + j];
  dsum += es;
  float v = acc / (dsum + 1e-16f) + cv(gb[j]);
  g1o[(size_t)m*HD + j] = v > 0.f ? v : expm1f(v);
}

// ---------------- GAT2 ------------------------------------------------------
template<typename TI>
__global__ __launch_bounds__(64) void k_gat2_pre(
    const int* __restrict__ flag, int want,
    const float* __restrict__ g1o, const void* gW_, const void* asr_, const void* adr_,
    float* __restrict__ xl2, float* __restrict__ s2, float* __restrict__ d2)
{
  if (*flag != want) return;
  const TI* gW  = (const TI*)gW_;
  const TI* asr = (const TI*)asr_;
  const TI* adr = (const TI*)adr_;
  __shared__ float grow[HD];
  int j = threadIdx.x, m = blockIdx.x;
  grow[j]      = g1o[(size_t)m*HD + j];
  grow[j + 64] = g1o[(size_t)m*HD + j + 64];
  __syncthreads();
  float a = 0.f;
  for (int i = 0; i < HD; ++i) a += grow[i] * cv(gW[i*GO + j]);
  xl2[(size_t)m*GO + j] = a;
  float pa = a * cv(asr[j]);
  float pb = a * cv(adr[j]);
  #pragma unroll
  for (int off = 32; off > 0; off >>= 1) { pa += __shfl_xor(pa, off); pb += __shfl_xor(pb, off); }
  if (j == 0) { s2[m] = pa; d2[m] = pb; }
}

template<typename TI, typename TO>
__global__ __launch_bounds__(64) void k_gat2_gather(
    const int* __restrict__ flag, int want,
    const int* __restrict__ row_ptr, const int* __restrict__ ssrc,
    const float* __restrict__ xl2, const float* __restrict__ s2, const float* __restrict__ d2,
    const void* gb_, const void* oW_, const void* ob_, void* y_)
{
  if (*flag != want) return;
  const TI* gb = (const TI*)gb_;
  const TI* oW = (const TI*)oW_;
  const TI* ob = (const TI*)ob_;
  TO* y = (TO*)y_;
  __shared__ float g2s[GO];
  int j = threadIdx.x, m = blockIdx.x;
  int b = m / NN, n = m - b * NN, boff = b * NN;
  float d2m = d2[m];
  int r0 = row_ptr[n], r1 = row_ptr[n+1];
  float acc = 0.f, dsum = 0.f;
  for (int e = r0; e < r1; ++e) {
    int src = ssrc[e] + boff;
    float ev = expf(lrelu(s2[src] + d2m));
    acc  += ev * xl2[(size_t)src*GO + j];
    dsum += ev;
  }
  float es = expf(lrelu(s2[m] + d2m));
  acc  += es * xl2[(size_t)m*GO + j];
  dsum += es;
  g2s[j] = acc / (dsum + 1e-16f) + cv(gb[j]);
  __syncthreads();
  if (j < HR) {
    float a = cv(ob[j]);
    #pragma unroll
    for (int o2 = 0; o2 < GO; ++o2) a += g2s[o2] * cv(oW[o2*HR + j]);
    st(&y[((size_t)b*HR + j)*NN + n], a);
  }
}

// ---------------- launch ----------------------------------------------------
extern "C" void kernel_launch(void* const* d_in, const int* in_sizes, int n_in,
                              void* d_out, int out_size, void* d_ws, size_t ws_size,
                              hipStream_t stream)
{
  const int* ei = (const int*)d_in[2];
  const int* e0 = ei;
  const int* e1 = ei + EE;

  float* ws    = (float*)d_ws;
  float* hlast = ws;                  // 40000*128
  float* xl1   = ws + 5120000;        // 40000*128
  float* ovl   = ws + 10240000;       // overlap region (weights, then CSR)
  float* s1    = ws + 15360000;       // 40000*4
  float* d1    = ws + 15520000;       // 40000*4
  int*   flag  = (int*)(ws + 15680000);

  // Weight buffers live [prep, xform] in the overlap region.
  unsigned short* Mu    = (unsigned short*)ovl;          // 65536 bf16 frags
  unsigned short* Pw    = Mu + 65536;                    // 65536
  unsigned short* W1F   = Mu + 131072;                   // 32768
  unsigned short* W2F   = Mu + 163840;                   // 32768
  unsigned short* encWF = Mu + 196608;                   // 4096
  float* encBf = (float*)(Mu + 200704);
  float* fb1f  = encBf + 128;
  float* fb2f  = fb1f + 256;
  float* l1gf  = fb2f + 128;
  float* l1bf  = l1gf + 128;
  float* l2gf  = l1bf + 128;
  float* l2bf  = l2gf + 128;

  // CSR arrays live [hist, end] in the SAME overlap region (stream-serial).
  int* cnt     = (int*)ovl;           // 10000
  int* row_ptr = cnt + 16384;         // 10001
  int* cur     = cnt + 32768;         // 10000
  int* ssrc    = cnt + 49152;         // 160000

  // phase-2 aliases (lifetimes disjoint)
  float* g1o  = hlast;
  float* xl2  = xl1;
  float* s2 = s1; float* d2 = d1;

  k_detect<<<1, 1, 0, stream>>>(d_in[0], flag);

  k_prep<float><<<788, 256, 0, stream>>>(flag, 0,
      d_in[5], d_in[6], d_in[7], d_in[8],
      d_in[3], d_in[4], d_in[11], d_in[12], d_in[13], d_in[14],
      d_in[9], d_in[10], d_in[15], d_in[16],
      Mu, Pw, W1F, W2F, encWF, encBf, fb1f, fb2f, l1gf, l1bf, l2gf, l2bf);
  k_prep<__hip_bfloat16><<<788, 256, 0, stream>>>(flag, 1,
      d_in[5], d_in[6], d_in[7], d_in[8],
      d_in[3], d_in[4], d_in[11], d_in[12], d_in[13], d_in[14],
      d_in[9], d_in[10], d_in[15], d_in[16],
      Mu, Pw, W1F, W2F, encWF, encBf, fb1f, fb2f, l1gf, l1bf, l2gf, l2bf);

  k_xform<float><<<MM/8, 256, 0, stream>>>(flag, 0,
      d_in[0], d_in[1], Mu, Pw, W1F, W2F,
      encWF, encBf, fb1f, fb2f, l1gf, l1bf, l2gf, l2bf, hlast);
  k_xform<__hip_bfloat16><<<MM/8, 256, 0, stream>>>(flag, 1,
      d_in[0], d_in[1], Mu, Pw, W1F, W2F,
      encWF, encBf, fb1f, fb2f, l1gf, l1bf, l2gf, l2bf, hlast);

  // CSR build (after xform: overlap region is free now)
  k_zero<<<(NN + 255)/256, 256, 0, stream>>>(cnt);
  k_hist<<<(EE + 255)/256, 256, 0, stream>>>(e1, cnt);
  k_scan<<<1, 1024, 0, stream>>>(cnt, row_ptr, cur);
  k_scatter<<<(EE + 255)/256, 256, 0, stream>>>(e0, e1, cur, ssrc);

  k_gat1_pre<float><<<MM, 128, 0, stream>>>(flag, 0, hlast,
      d_in[17], d_in[18], d_in[19], xl1, s1, d1);
  k_gat1_pre<__hip_bfloat16><<<MM, 128, 0, stream>>>(flag, 1, hlast,
      d_in[17], d_in[18], d_in[19], xl1, s1, d1);

  k_gat1_gather<float><<<MM, 128, 0, stream>>>(flag, 0,
      row_ptr, ssrc, xl1, s1, d1, d_in[20], g1o);
  k_gat1_gather<__hip_bfloat16><<<MM, 128, 0, stream>>>(flag, 1,
      row_ptr, ssrc, xl1, s1, d1, d_in[20], g1o);

  k_gat2_pre<float><<<MM, 64, 0, stream>>>(flag, 0, g1o,
      d_in[21], d_in[22], d_in[23], xl2, s2, d2);
  k_gat2_pre<__hip_bfloat16><<<MM, 64, 0, stream>>>(flag, 1, g1o,
      d_in[21], d_in[22], d_in[23], xl2, s2, d2);

  k_gat2_gather<float, float><<<MM, 64, 0, stream>>>(flag, 0,
      row_ptr, ssrc, xl2, s2, d2, d_in[24], d_in[25], d_in[26], d_out);
  k_gat2_gather<__hip_bfloat16, __hip_bfloat16><<<MM, 64, 0, stream>>>(flag, 1,
      row_ptr, ssrc, xl2, s2, d2, d_in[24], d_in[25], d_in[26], d_out);
}

// Round 8
// 416.357 us; speedup vs baseline: 4.4567x; 1.1127x over previous
//
#include <hip/hip_runtime.h>
#include <hip/hip_bf16.h>

#define DEV static __device__ __forceinline__

constexpr int BB = 4;        // batches
constexpr int TT = 12;       // timesteps
constexpr int NN = 10000;    // nodes per batch
constexpr int FD = 16;       // input features (8+8)
constexpr int HD = 128;      // hidden
constexpr int NH = 4;        // attn heads
constexpr int DH = 32;       // head dim
constexpr int FF = 256;      // ffn hidden
constexpr int GO = 64;       // gat2 out
constexpr int HR = 24;       // horizon
constexpr int EE = 160000;   // edges per batch
constexpr int MM = BB * NN;  // total nodes

typedef unsigned short bvec8 __attribute__((ext_vector_type(8)));
typedef float fvec4 __attribute__((ext_vector_type(4)));
typedef short bs8 __attribute__((ext_vector_type(8)));      // MFMA bf16 frag (4 VGPR)

DEV float lrelu(float x) { return x >= 0.f ? x : 0.2f * x; }

DEV float b2f(unsigned short u) {
  union { unsigned int i; float f; } x; x.i = ((unsigned int)u) << 16; return x.f;
}
DEV unsigned short f2b(float f) {
  union { float f; unsigned int i; } x; x.f = f;
  unsigned int r = x.i + 0x7FFFu + ((x.i >> 16) & 1u);
  return (unsigned short)(r >> 16);
}

DEV fvec4 mfma16(bs8 a, bs8 b, fvec4 c) {
  return __builtin_amdgcn_mfma_f32_16x16x32_bf16(a, b, c, 0, 0, 0);
}

// ---------------- prep: fold + re-layout ALL transformer weights (fp32 in) --
// MFMA B-fragment order: frag idx = ((nt*nK + kk)*64 + lane), element e:
//   B[k][n] with k = kk*32 + (lane>>4)*8 + e, n = nt*16 + (lane&15).
// MuF: K=128,N=512; PwF: K=512,N=128; W1F: K=128,N=256; W2F: K=256,N=128;
// encWF: K=32 (rows 16+ zero), N=128; gW1F: K=128,N=128.
__global__ __launch_bounds__(256) void k_prep(
    const float* __restrict__ Wq, const float* __restrict__ Wk,
    const float* __restrict__ Wv, const float* __restrict__ Wo,
    const float* __restrict__ encW, const float* __restrict__ encB,
    const float* __restrict__ W1, const float* __restrict__ fb1,
    const float* __restrict__ W2, const float* __restrict__ fb2,
    const float* __restrict__ l1g, const float* __restrict__ l1b,
    const float* __restrict__ l2g, const float* __restrict__ l2b,
    const float* __restrict__ gW1,
    unsigned short* __restrict__ Mu, unsigned short* __restrict__ Pw,
    unsigned short* __restrict__ W1F, unsigned short* __restrict__ W2F,
    unsigned short* __restrict__ encWF, unsigned short* __restrict__ gW1F,
    float* __restrict__ encBf, float* __restrict__ fb1f, float* __restrict__ fb2f,
    float* __restrict__ l1gf, float* __restrict__ l1bf,
    float* __restrict__ l2gf, float* __restrict__ l2bf)
{
  int idx = blockIdx.x * 256 + threadIdx.x;      // 852*256 = 218112 exactly
  if (idx < 65536) {
    // MuF: B[i][q] = sum_d Wq[i][h*32+d]*Wk[c][h*32+d], q=(h,c). nK=4.
    int e = idx & 7, lane = (idx >> 3) & 63, kk = (idx >> 9) & 3, nt = idx >> 11;
    int i = kk*32 + (lane >> 4)*8 + e;
    int q = nt*16 + (lane & 15);
    int h = q >> 7, c = q & 127;
    float a = 0.f;
    #pragma unroll 8
    for (int d = 0; d < DH; ++d)
      a += Wq[i*HD + h*DH + d] * Wk[c*HD + h*DH + d];
    Mu[idx] = f2b(a);
  } else if (idx < 131072) {
    // PwF: B[q][j] = sum_d Wv[i][h*32+d]*Wo[h*32+d][j], q=(h,i). nK=16.
    int g2 = idx - 65536;
    int e = g2 & 7, lane = (g2 >> 3) & 63, kk = (g2 >> 9) & 15, nt = g2 >> 13;
    int q = kk*32 + (lane >> 4)*8 + e;
    int j = nt*16 + (lane & 15);
    int h = q >> 7, i = q & 127;
    float a = 0.f;
    #pragma unroll 8
    for (int d = 0; d < DH; ++d)
      a += Wv[i*HD + h*DH + d] * Wo[(h*DH + d)*HD + j];
    Pw[g2] = f2b(a);
  } else if (idx < 163840) {
    // W1F: B = W1 [128][256]. nK=4, nt 0..15.
    int g = idx - 131072;
    int e = g & 7, lane = (g >> 3) & 63, kk = (g >> 9) & 3, nt = g >> 11;
    int k = kk*32 + (lane >> 4)*8 + e;
    int n = nt*16 + (lane & 15);
    W1F[g] = f2b(W1[k*FF + n]);
  } else if (idx < 196608) {
    // W2F: B = W2 [256][128]. nK=8, nt 0..7.
    int g = idx - 163840;
    int e = g & 7, lane = (g >> 3) & 63, kk = (g >> 9) & 7, nt = g >> 12;
    int k = kk*32 + (lane >> 4)*8 + e;
    int n = nt*16 + (lane & 15);
    W2F[g] = f2b(W2[k*HD + n]);
  } else if (idx < 200704) {
    // encWF: B = encW [16][128] zero-padded to K=32. nK=1, nt 0..7.
    int g = idx - 196608;
    int e = g & 7, lane = (g >> 3) & 63, nt = g >> 9;
    int k = (lane >> 4)*8 + e;
    int n = nt*16 + (lane & 15);
    encWF[g] = (k < FD) ? f2b(encW[k*HD + n]) : (unsigned short)0;
  } else if (idx < 217088) {
    // gW1F: B = gW1 [128][128]. nK=4, nt 0..7.
    int g = idx - 200704;
    int e = g & 7, lane = (g >> 3) & 63, kk = (g >> 9) & 3, nt = g >> 11;
    int k = kk*32 + (lane >> 4)*8 + e;
    int n = nt*16 + (lane & 15);
    gW1F[g] = f2b(gW1[k*HD + n]);
  } else if (idx < 217216) { int t = idx - 217088; encBf[t] = encB[t]; }
  else if (idx < 217472)   { int t = idx - 217216; fb1f[t] = fb1[t]; }
  else if (idx < 217600)   { int t = idx - 217472; fb2f[t] = fb2[t]; }
  else if (idx < 217728)   { int t = idx - 217600; l1gf[t] = l1g[t]; }
  else if (idx < 217856)   { int t = idx - 217728; l1bf[t] = l1b[t]; }
  else if (idx < 217984)   { int t = idx - 217856; l2gf[t] = l2g[t]; }
  else                     { int t = idx - 217984; l2bf[t] = l2b[t]; }
}

// ---------------- fused transformer + GAT1-pre (8 nodes/block) --------------
__global__ __launch_bounds__(256) void k_xform(
    const float* __restrict__ xh, const float* __restrict__ xc,
    const unsigned short* __restrict__ MuF, const unsigned short* __restrict__ PwF,
    const unsigned short* __restrict__ W1F, const unsigned short* __restrict__ W2F,
    const unsigned short* __restrict__ encWF, const unsigned short* __restrict__ gW1F,
    const float* __restrict__ encBf,
    const float* __restrict__ fb1f, const float* __restrict__ fb2f,
    const float* __restrict__ l1gf, const float* __restrict__ l1bf,
    const float* __restrict__ l2gf, const float* __restrict__ l2bf,
    const float* __restrict__ asrc, const float* __restrict__ adrc,
    float* __restrict__ xl1, float* __restrict__ s1, float* __restrict__ d1)
{
  // big: hsB (ph1-5) then {r1F,h1s,h1B,f1B,r2F} (ph6-10)
  __shared__ __align__(16) char big[25344];
  __shared__ float hlastF[8][128];
  __shared__ unsigned short hlastB[16*132];    // rows 8-15 junk -> D discarded
  __shared__ float lgaw[8][NH][TT];
  __shared__ __align__(16) char regB[16896];   // xB -> usF -> wB -> xlF

  unsigned short* hsB = (unsigned short*)big;          // [(nl*12+t)][132]
  float* r1F = (float*)big;                            // [8][132] ph6-7
  float* h1s = (float*)(big + 4224);                   // [8][132] ph7-9
  unsigned short* h1B = (unsigned short*)(big + 8448); // [16][132] ph7-8
  unsigned short* f1B = (unsigned short*)(big + 12672);// [16][260] ph8-9
  float* r2F = (float*)(big + 8448);                   // [8][132] ph9-10 (over h1B)

  unsigned short* xB = (unsigned short*)regB;          // [96][40] ph0-1
  float* usF = (float*)regB;                           // [8][4][132] ph2-3
  unsigned short* wB = (unsigned short*)regB;          // [16][516] ph5-6
  float* xlF = (float*)regB;                           // [8][128] ph11

  const int tid  = threadIdx.x;
  const int w    = tid >> 6;
  const int lane = tid & 63;
  const int m0   = blockIdx.x * 8;
  const int arow = lane & 15, akg = lane >> 4;

  // --- phase 0: load x -> xB bf16, rows = t*8+nl, K zero-padded 16..31 ---
  #pragma unroll
  for (int k = 0; k < 6; ++k) {
    int idx = tid + k*256;
    int f = idx & 15, rest = idx >> 4;
    int nl = rest & 7, t = rest >> 3;
    int m = m0 + nl, b = m / NN, n = m - b*NN;
    float v = (f < 8) ? xh[(((size_t)b*TT + t)*NN + n)*8 + f]
                      : xc[(((size_t)b*TT + t)*NN + n)*8 + (f - 8)];
    xB[(t*8 + nl)*40 + f] = f2b(v);
  }
  #pragma unroll
  for (int k = 0; k < 6; ++k) {
    int idx = tid + k*256;
    xB[(idx >> 4)*40 + 16 + (idx & 15)] = 0;
  }
  __syncthreads();

  // --- phase 1: encoder via MFMA (96x128 = 6 mt x 8 nt tiles) ---
  {
    const bs8* ef = (const bs8*)encWF;
    bs8 b0 = ef[(2*w + 0)*64 + lane];
    bs8 b1 = ef[(2*w + 1)*64 + lane];
    int drow = akg*4, dc = arow;
    int j0 = (2*w + 0)*16 + dc, j1 = (2*w + 1)*16 + dc;
    float eb0 = encBf[j0], eb1 = encBf[j1];
    fvec4 z4 = {0.f, 0.f, 0.f, 0.f};
    #pragma unroll
    for (int mt = 0; mt < 6; ++mt) {
      bs8 af = *(const bs8*)&xB[(mt*16 + arow)*40 + akg*8];
      fvec4 d0 = mfma16(af, b0, z4);
      fvec4 d1 = mfma16(af, b1, z4);
      #pragma unroll
      for (int reg = 0; reg < 4; ++reg) {
        int gr = mt*16 + drow + reg;
        int t = gr >> 3, nl = gr & 7;
        float v0 = d0[reg] + eb0, v1 = d1[reg] + eb1;
        hsB[(nl*12 + t)*132 + j0] = f2b(v0);
        hsB[(nl*12 + t)*132 + j1] = f2b(v1);
        if (t == TT-1) {
          hlastF[nl][j0] = v0; hlastB[nl*132 + j0] = f2b(v0);
          hlastF[nl][j1] = v1; hlastB[nl*132 + j1] = f2b(v1);
        }
      }
    }
  }
  __syncthreads();                // xB dead

  // --- phase 2: u = h_last @ Mu via MFMA -> usF fp32 ---
  {
    bs8 af[4];
    #pragma unroll
    for (int kk = 0; kk < 4; ++kk)
      af[kk] = *(const bs8*)&hlastB[arow*132 + kk*32 + akg*8];
    const bs8* bp = (const bs8*)MuF;
    fvec4 acc[8];
    #pragma unroll
    for (int n8 = 0; n8 < 8; ++n8) {
      int nt = w*8 + n8;
      const bs8* bq = bp + nt*256 + lane;
      fvec4 a4 = {0.f, 0.f, 0.f, 0.f};
      #pragma unroll
      for (int kk = 0; kk < 4; ++kk)
        a4 = mfma16(af[kk], bq[kk*64], a4);
      acc[n8] = a4;
    }
    if (lane < 32) {
      int drow = akg*4, dc = arow;
      #pragma unroll
      for (int n8 = 0; n8 < 8; ++n8) {
        int col = (w*8 + n8)*16 + dc, hd = col >> 7, c = col & 127;
        #pragma unroll
        for (int reg = 0; reg < 4; ++reg)
          usF[((drow + reg)*4 + hd)*132 + c] = acc[n8][reg];
      }
    }
  }
  __syncthreads();

  // --- phase 3: logits (8n x 4h x 12t = 384 dots of K=128) ---
  #pragma unroll
  for (int pass = 0; pass < 2; ++pass) {
    int item = pass*256 + tid;
    if (item < 384) {
      int nl = item / 48, p = item - nl*48, hd = p / 12, t = p - hd*12;
      const float* up = &usF[(nl*4 + hd)*132];
      float a = 0.f;
      for (int i8 = 0; i8 < 16; ++i8) {
        bvec8 hb8 = *(const bvec8*)&hsB[(nl*12 + t)*132 + i8*8];
        const fvec4* uq = (const fvec4*)&up[i8*8];
        fvec4 u0 = uq[0], u1 = uq[1];
        a += b2f(hb8[0])*u0[0] + b2f(hb8[1])*u0[1] + b2f(hb8[2])*u0[2] + b2f(hb8[3])*u0[3]
           + b2f(hb8[4])*u1[0] + b2f(hb8[5])*u1[1] + b2f(hb8[6])*u1[2] + b2f(hb8[7])*u1[3];
      }
      lgaw[nl][hd][t] = a * 0.17677669529663687f;
    }
  }
  __syncthreads();

  // --- phase 4: softmax over t ---
  if (tid < 32) {
    int nl = tid >> 2, hd = tid & 3;
    float mx = -1e30f;
    #pragma unroll
    for (int t = 0; t < TT; ++t) mx = fmaxf(mx, lgaw[nl][hd][t]);
    float ex[TT], sm = 0.f;
    #pragma unroll
    for (int t = 0; t < TT; ++t) { ex[t] = expf(lgaw[nl][hd][t] - mx); sm += ex[t]; }
    float inv = 1.f / sm;
    #pragma unroll
    for (int t = 0; t < TT; ++t) lgaw[nl][hd][t] = ex[t] * inv;
  }
  __syncthreads();

  // --- phase 5: w_h = sum_t alpha*h_t -> wB bf16 (over usF) ---
  {
    int g = tid >> 7, j = tid & 127;
    #pragma unroll
    for (int r = 0; r < 4; ++r) {
      int nl = g*4 + r;
      float wacc[NH] = {0.f, 0.f, 0.f, 0.f};
      #pragma unroll
      for (int t = 0; t < TT; ++t) {
        float hv = b2f(hsB[(nl*12 + t)*132 + j]);
        #pragma unroll
        for (int hd = 0; hd < NH; ++hd) wacc[hd] += lgaw[nl][hd][t] * hv;
      }
      #pragma unroll
      for (int hd = 0; hd < NH; ++hd) wB[nl*516 + hd*128 + j] = f2b(wacc[hd]);
    }
  }
  __syncthreads();                // hsB dead after this point

  // --- phase 6: oa = w @ Pw via MFMA; r1 = h_last + oa -> r1F (over hsB) ---
  {
    fvec4 pacc0 = {0.f,0.f,0.f,0.f}, pacc1 = {0.f,0.f,0.f,0.f};
    const bs8* bp = (const bs8*)PwF;
    const bs8* bq0 = bp + (w*2 + 0)*1024 + lane;
    const bs8* bq1 = bp + (w*2 + 1)*1024 + lane;
    #pragma unroll
    for (int kk = 0; kk < 16; ++kk) {
      bs8 af = *(const bs8*)&wB[arow*516 + kk*32 + akg*8];
      pacc0 = mfma16(af, bq0[kk*64], pacc0);
      pacc1 = mfma16(af, bq1[kk*64], pacc1);
    }
    if (lane < 32) {
      int drow = akg*4, dc = arow;
      #pragma unroll
      for (int reg = 0; reg < 4; ++reg) {
        int nd = drow + reg;
        int c0 = (w*2 + 0)*16 + dc;
        int c1 = (w*2 + 1)*16 + dc;
        r1F[nd*132 + c0] = hlastF[nd][c0] + pacc0[reg];
        r1F[nd*132 + c1] = hlastF[nd][c1] + pacc1[reg];
      }
    }
  }
  __syncthreads();

  // --- phase 7: LN1 -> h1s fp32 + h1B bf16 ---
  {
    int nd = tid >> 5, l32 = tid & 31;
    float v[4], s = 0.f, q = 0.f;
    #pragma unroll
    for (int k = 0; k < 4; ++k) {
      v[k] = r1F[nd*132 + l32 + k*32];
      s += v[k]; q += v[k]*v[k];
    }
    #pragma unroll
    for (int off = 16; off > 0; off >>= 1) { s += __shfl_xor(s, off); q += __shfl_xor(q, off); }
    float mu = s*(1.f/128.f), var = q*(1.f/128.f) - mu*mu, rs = rsqrtf(var + 1e-5f);
    #pragma unroll
    for (int k = 0; k < 4; ++k) {
      int c = l32 + k*32;
      float hv = (v[k] - mu)*rs*l1gf[c] + l1bf[c];
      h1s[nd*132 + c] = hv;
      h1B[nd*132 + c] = f2b(hv);
    }
  }
  __syncthreads();

  // --- phase 8: FFN1 via MFMA (K=128, N=256), relu+bias fused -> f1B bf16 ---
  {
    bs8 af[4];
    #pragma unroll
    for (int kk = 0; kk < 4; ++kk)
      af[kk] = *(const bs8*)&h1B[arow*132 + kk*32 + akg*8];
    const bs8* bp = (const bs8*)W1F;
    #pragma unroll
    for (int n4 = 0; n4 < 4; ++n4) {
      int nt = w*4 + n4;
      const bs8* bq = bp + nt*256 + lane;
      fvec4 a4 = {0.f, 0.f, 0.f, 0.f};
      #pragma unroll
      for (int kk = 0; kk < 4; ++kk)
        a4 = mfma16(af[kk], bq[kk*64], a4);
      if (lane < 32) {
        int drow = akg*4, dc = arow;
        int n = nt*16 + dc;
        float bias = fb1f[n];
        #pragma unroll
        for (int reg = 0; reg < 4; ++reg)
          f1B[(drow + reg)*260 + n] = f2b(fmaxf(a4[reg] + bias, 0.f));
      }
    }
  }
  __syncthreads();

  // --- phase 9: FFN2 via MFMA (K=256, N=128) + residual -> r2F (over h1B) ---
  {
    const bs8* bp = (const bs8*)W2F;
    #pragma unroll
    for (int n2 = 0; n2 < 2; ++n2) {
      int nt = w*2 + n2;
      const bs8* bq = bp + nt*512 + lane;
      fvec4 a4 = {0.f, 0.f, 0.f, 0.f};
      #pragma unroll
      for (int kk = 0; kk < 8; ++kk) {
        bs8 af = *(const bs8*)&f1B[arow*260 + kk*32 + akg*8];
        a4 = mfma16(af, bq[kk*64], a4);
      }
      if (lane < 32) {
        int drow = akg*4, dc = arow;
        int c = nt*16 + dc;
        float fb2v = fb2f[c];
        #pragma unroll
        for (int reg = 0; reg < 4; ++reg) {
          int nd = drow + reg;
          r2F[nd*132 + c] = h1s[nd*132 + c] + fb2v + a4[reg];
        }
      }
    }
  }
  __syncthreads();

  // --- phase 10: LN2 -> hlastB bf16 (A-frags for GAT1 projection) ---
  {
    int nd = tid >> 5, l32 = tid & 31;
    float v[4], s = 0.f, q = 0.f;
    #pragma unroll
    for (int k = 0; k < 4; ++k) {
      v[k] = r2F[nd*132 + l32 + k*32];
      s += v[k]; q += v[k]*v[k];
    }
    #pragma unroll
    for (int off = 16; off > 0; off >>= 1) { s += __shfl_xor(s, off); q += __shfl_xor(q, off); }
    float mu = s*(1.f/128.f), var = q*(1.f/128.f) - mu*mu, rs = rsqrtf(var + 1e-5f);
    #pragma unroll
    for (int k = 0; k < 4; ++k) {
      int c = l32 + k*32;
      hlastB[nd*132 + c] = f2b((v[k] - mu)*rs*l2gf[c] + l2bf[c]);
    }
  }
  __syncthreads();

  // --- phase 11: xl1 = hlast @ gW1 via MFMA; s1/d1 reduce; globals out ---
  {
    bs8 af[4];
    #pragma unroll
    for (int kk = 0; kk < 4; ++kk)
      af[kk] = *(const bs8*)&hlastB[arow*132 + kk*32 + akg*8];
    const bs8* bp = (const bs8*)gW1F;
    #pragma unroll
    for (int n2 = 0; n2 < 2; ++n2) {
      int nt = w*2 + n2;
      const bs8* bq = bp + nt*256 + lane;
      fvec4 a4 = {0.f, 0.f, 0.f, 0.f};
      #pragma unroll
      for (int kk = 0; kk < 4; ++kk)
        a4 = mfma16(af[kk], bq[kk*64], a4);
      if (lane < 32) {
        int drow = akg*4, dc = arow;
        int c = nt*16 + dc;
        #pragma unroll
        for (int reg = 0; reg < 4; ++reg)
          xlF[(drow + reg)*128 + c] = a4[reg];
      }
    }
  }
  __syncthreads();
  {
    // coalesced xl1 write: 4 consecutive floats per thread
    fvec4 vv = ((const fvec4*)xlF)[tid];
    *(fvec4*)&xl1[(size_t)m0*HD + tid*4] = vv;
    // s1/d1: nd = tid>>5; lane's 4 cols map to heads 0..3 (col = l32 + k*32)
    int nd = tid >> 5, l32 = tid & 31;
    float pa[4], pb[4];
    #pragma unroll
    for (int k = 0; k < 4; ++k) {
      float xv = xlF[nd*128 + l32 + k*32];
      pa[k] = xv * asrc[l32 + k*32];
      pb[k] = xv * adrc[l32 + k*32];
    }
    #pragma unroll
    for (int off = 16; off > 0; off >>= 1) {
      #pragma unroll
      for (int k = 0; k < 4; ++k) {
        pa[k] += __shfl_xor(pa[k], off);
        pb[k] += __shfl_xor(pb[k], off);
      }
    }
    if (l32 == 0) {
      int m = m0 + nd;
      #pragma unroll
      for (int k = 0; k < 4; ++k) {
        s1[m*NH + k] = pa[k];
        d1[m*NH + k] = pb[k];
      }
    }
  }
}

// ---------------- CSR build (batch-shared) ----------------------------------
__global__ __launch_bounds__(256) void k_zero(int* __restrict__ cnt)
{
  int i = blockIdx.x * 256 + threadIdx.x;
  if (i < NN) cnt[i] = 0;
}

__global__ __launch_bounds__(256) void k_hist(const int* __restrict__ e1,
                                              int* __restrict__ cnt)
{
  int i = blockIdx.x * 256 + threadIdx.x;
  if (i < EE) atomicAdd(&cnt[e1[i]], 1);
}

__global__ __launch_bounds__(1024) void k_scan(const int* __restrict__ cnt,
                                               int* __restrict__ row_ptr,
                                               int* __restrict__ cur)
{
  __shared__ int sm[1024];
  int tid = threadIdx.x;
  int base = tid * 10;
  int loc[10];
  int s = 0;
  #pragma unroll
  for (int k = 0; k < 10; ++k) {
    int idx = base + k;
    int v = (idx < NN) ? cnt[idx] : 0;
    loc[k] = s;
    s += v;
  }
  sm[tid] = s;
  __syncthreads();
  for (int off = 1; off < 1024; off <<= 1) {
    int t = (tid >= off) ? sm[tid - off] : 0;
    __syncthreads();
    sm[tid] += t;
    __syncthreads();
  }
  int segbase = sm[tid] - s;
  #pragma unroll
  for (int k = 0; k < 10; ++k) {
    int idx = base + k;
    if (idx < NN) { int o = segbase + loc[k]; row_ptr[idx] = o; cur[idx] = o; }
  }
  if (tid == 1023) row_ptr[NN] = sm[1023];
}

__global__ __launch_bounds__(256) void k_scatter(const int* __restrict__ e0,
                                                 const int* __restrict__ e1,
                                                 int* __restrict__ cur,
                                                 int* __restrict__ ssrc)
{
  int i = blockIdx.x * 256 + threadIdx.x;
  if (i >= EE) return;
  int pos = atomicAdd(&cur[e1[i]], 1);
  ssrc[pos] = e0[i];
}

// ---------------- GAT1 gather + GAT2 pre (fused; 1 node/block) --------------
__global__ __launch_bounds__(128) void k_g1(
    const int* __restrict__ row_ptr, const int* __restrict__ ssrc,
    const float* __restrict__ xl, const float* __restrict__ s1, const float* __restrict__ d1,
    const float* __restrict__ gb1, const float* __restrict__ gW2,
    const float* __restrict__ asr2, const float* __restrict__ adr2,
    float* __restrict__ xl2, float* __restrict__ s2, float* __restrict__ d2)
{
  __shared__ float g1s[HD];
  int j = threadIdx.x, m = blockIdx.x, h = j >> 5;
  int b = m / NN, n = m - b * NN, boff = b * NN;
  float dh = d1[m*NH + h];
  int r0 = row_ptr[n], r1 = row_ptr[n+1];
  float acc = 0.f, dsum = 0.f;
  for (int e = r0; e < r1; ++e) {
    int src = ssrc[e] + boff;
    float ev = expf(lrelu(s1[src*NH + h] + dh));
    acc  += ev * xl[(size_t)src*HD + j];
    dsum += ev;
  }
  float es = expf(lrelu(s1[m*NH + h] + dh));    // self loop
  acc  += es * xl[(size_t)m*HD + j];
  dsum += es;
  float v = acc / (dsum + 1e-16f) + gb1[j];
  g1s[j] = v > 0.f ? v : expm1f(v);             // ELU
  __syncthreads();
  if (j < GO) {
    float a = 0.f;
    for (int i = 0; i < HD; ++i) a += g1s[i] * gW2[i*GO + j];
    xl2[(size_t)m*GO + j] = a;
    float pa = a * asr2[j], pb = a * adr2[j];
    #pragma unroll
    for (int off = 32; off > 0; off >>= 1) { pa += __shfl_xor(pa, off); pb += __shfl_xor(pb, off); }
    if (j == 0) { s2[m] = pa; d2[m] = pb; }
  }
}

// ---------------- GAT2 gather + output projection ---------------------------
__global__ __launch_bounds__(64) void k_g2(
    const int* __restrict__ row_ptr, const int* __restrict__ ssrc,
    const float* __restrict__ xl2, const float* __restrict__ s2, const float* __restrict__ d2,
    const float* __restrict__ gb2, const float* __restrict__ oW, const float* __restrict__ ob,
    float* __restrict__ y)
{
  __shared__ float g2s[GO];
  int j = threadIdx.x, m = blockIdx.x;
  int b = m / NN, n = m - b * NN, boff = b * NN;
  float d2m = d2[m];
  int r0 = row_ptr[n], r1 = row_ptr[n+1];
  float acc = 0.f, dsum = 0.f;
  for (int e = r0; e < r1; ++e) {
    int src = ssrc[e] + boff;
    float ev = expf(lrelu(s2[src] + d2m));
    acc  += ev * xl2[(size_t)src*GO + j];
    dsum += ev;
  }
  float es = expf(lrelu(s2[m] + d2m));
  acc  += es * xl2[(size_t)m*GO + j];
  dsum += es;
  g2s[j] = acc / (dsum + 1e-16f) + gb2[j];
  __syncthreads();
  if (j < HR) {
    float a = ob[j];
    #pragma unroll
    for (int o2 = 0; o2 < GO; ++o2) a += g2s[o2] * oW[o2*HR + j];
    y[((size_t)b*HR + j)*NN + n] = a;
  }
}

// ---------------- launch ----------------------------------------------------
extern "C" void kernel_launch(void* const* d_in, const int* in_sizes, int n_in,
                              void* d_out, int out_size, void* d_ws, size_t ws_size,
                              hipStream_t stream)
{
  const int* ei = (const int*)d_in[2];
  const int* e0 = ei;
  const int* e1 = ei + EE;

  float* ws   = (float*)d_ws;
  float* xl1  = ws;                   // 40000*128
  float* xl2  = ws + 5120000;         // 40000*64
  float* ovl  = ws + 10240000;        // overlap region (weights, then CSR)
  float* s1   = ws + 15360000;        // 40000*4
  float* d1   = ws + 15520000;        // 40000*4
  float* s2   = ws + 15680000;        // 40000
  float* d2   = ws + 15720000;        // 40000

  // Weight buffers live [prep, xform] in the overlap region.
  unsigned short* Mu    = (unsigned short*)ovl;          // 65536 bf16 frags
  unsigned short* Pw    = Mu + 65536;                    // 65536
  unsigned short* W1F   = Mu + 131072;                   // 32768
  unsigned short* W2F   = Mu + 163840;                   // 32768
  unsigned short* encWF = Mu + 196608;                   // 4096
  unsigned short* gW1F  = Mu + 200704;                   // 16384
  float* encBf = (float*)(Mu + 217088);
  float* fb1f  = encBf + 128;
  float* fb2f  = fb1f + 256;
  float* l1gf  = fb2f + 128;
  float* l1bf  = l1gf + 128;
  float* l2gf  = l1bf + 128;
  float* l2bf  = l2gf + 128;

  // CSR arrays live [hist, end] in the SAME overlap region (stream-serial).
  int* cnt     = (int*)ovl;           // 10000
  int* row_ptr = cnt + 16384;         // 10001
  int* cur     = cnt + 32768;         // 10000
  int* ssrc    = cnt + 49152;         // 160000

  k_prep<<<852, 256, 0, stream>>>(
      (const float*)d_in[5], (const float*)d_in[6], (const float*)d_in[7], (const float*)d_in[8],
      (const float*)d_in[3], (const float*)d_in[4], (const float*)d_in[11], (const float*)d_in[12],
      (const float*)d_in[13], (const float*)d_in[14], (const float*)d_in[9], (const float*)d_in[10],
      (const float*)d_in[15], (const float*)d_in[16], (const float*)d_in[17],
      Mu, Pw, W1F, W2F, encWF, gW1F,
      encBf, fb1f, fb2f, l1gf, l1bf, l2gf, l2bf);

  k_xform<<<MM/8, 256, 0, stream>>>(
      (const float*)d_in[0], (const float*)d_in[1],
      Mu, Pw, W1F, W2F, encWF, gW1F,
      encBf, fb1f, fb2f, l1gf, l1bf, l2gf, l2bf,
      (const float*)d_in[18], (const float*)d_in[19],
      xl1, s1, d1);

  // CSR build (after xform: overlap region is free now)
  k_zero<<<(NN + 255)/256, 256, 0, stream>>>(cnt);
  k_hist<<<(EE + 255)/256, 256, 0, stream>>>(e1, cnt);
  k_scan<<<1, 1024, 0, stream>>>(cnt, row_ptr, cur);
  k_scatter<<<(EE + 255)/256, 256, 0, stream>>>(e0, e1, cur, ssrc);

  k_g1<<<MM, 128, 0, stream>>>(row_ptr, ssrc, xl1, s1, d1,
      (const float*)d_in[20], (const float*)d_in[21],
      (const float*)d_in[22], (const float*)d_in[23],
      xl2, s2, d2);

  k_g2<<<MM, 64, 0, stream>>>(row_ptr, ssrc, xl2, s2, d2,
      (const float*)d_in[24], (const float*)d_in[25], (const float*)d_in[26],
      (float*)d_out);
}

// Round 9
// 336.981 us; speedup vs baseline: 5.5064x; 1.2356x over previous
//
#include <hip/hip_runtime.h>
#include <hip/hip_bf16.h>

#define DEV static __device__ __forceinline__

constexpr int BB = 4;        // batches
constexpr int TT = 12;       // timesteps
constexpr int NN = 10000;    // nodes per batch
constexpr int FD = 16;       // input features (8+8)
constexpr int HD = 128;      // hidden
constexpr int NH = 4;        // attn heads
constexpr int DH = 32;       // head dim
constexpr int FF = 256;      // ffn hidden
constexpr int GO = 64;       // gat2 out
constexpr int HR = 24;       // horizon
constexpr int EE = 160000;   // edges per batch
constexpr int MM = BB * NN;  // total nodes

typedef unsigned short bvec8 __attribute__((ext_vector_type(8)));
typedef float fvec4 __attribute__((ext_vector_type(4)));
typedef short bs8 __attribute__((ext_vector_type(8)));      // MFMA bf16 frag (4 VGPR)

DEV float lrelu(float x) { return x >= 0.f ? x : 0.2f * x; }

DEV float b2f(unsigned short u) {
  union { unsigned int i; float f; } x; x.i = ((unsigned int)u) << 16; return x.f;
}
DEV unsigned short f2b(float f) {
  union { float f; unsigned int i; } x; x.f = f;
  unsigned int r = x.i + 0x7FFFu + ((x.i >> 16) & 1u);
  return (unsigned short)(r >> 16);
}

DEV fvec4 mfma16(bs8 a, bs8 b, fvec4 c) {
  return __builtin_amdgcn_mfma_f32_16x16x32_bf16(a, b, c, 0, 0, 0);
}

// ---------------- prep: fold + re-layout ALL transformer weights (fp32 in) --
// MFMA B-fragment order: frag idx = ((nt*nK + kk)*64 + lane), element e:
//   B[k][n] with k = kk*32 + (lane>>4)*8 + e, n = nt*16 + (lane&15).
__global__ __launch_bounds__(256) void k_prep(
    const float* __restrict__ Wq, const float* __restrict__ Wk,
    const float* __restrict__ Wv, const float* __restrict__ Wo,
    const float* __restrict__ encW, const float* __restrict__ encB,
    const float* __restrict__ W1, const float* __restrict__ fb1,
    const float* __restrict__ W2, const float* __restrict__ fb2,
    const float* __restrict__ l1g, const float* __restrict__ l1b,
    const float* __restrict__ l2g, const float* __restrict__ l2b,
    const float* __restrict__ gW1,
    unsigned short* __restrict__ Mu, unsigned short* __restrict__ Pw,
    unsigned short* __restrict__ W1F, unsigned short* __restrict__ W2F,
    unsigned short* __restrict__ encWF, unsigned short* __restrict__ gW1F,
    float* __restrict__ encBf, float* __restrict__ fb1f, float* __restrict__ fb2f,
    float* __restrict__ l1gf, float* __restrict__ l1bf,
    float* __restrict__ l2gf, float* __restrict__ l2bf)
{
  int idx = blockIdx.x * 256 + threadIdx.x;      // 852*256 = 218112 exactly
  if (idx < 65536) {
    int e = idx & 7, lane = (idx >> 3) & 63, kk = (idx >> 9) & 3, nt = idx >> 11;
    int i = kk*32 + (lane >> 4)*8 + e;
    int q = nt*16 + (lane & 15);
    int h = q >> 7, c = q & 127;
    float a = 0.f;
    #pragma unroll 8
    for (int d = 0; d < DH; ++d)
      a += Wq[i*HD + h*DH + d] * Wk[c*HD + h*DH + d];
    Mu[idx] = f2b(a);
  } else if (idx < 131072) {
    int g2 = idx - 65536;
    int e = g2 & 7, lane = (g2 >> 3) & 63, kk = (g2 >> 9) & 15, nt = g2 >> 13;
    int q = kk*32 + (lane >> 4)*8 + e;
    int j = nt*16 + (lane & 15);
    int h = q >> 7, i = q & 127;
    float a = 0.f;
    #pragma unroll 8
    for (int d = 0; d < DH; ++d)
      a += Wv[i*HD + h*DH + d] * Wo[(h*DH + d)*HD + j];
    Pw[g2] = f2b(a);
  } else if (idx < 163840) {
    int g = idx - 131072;
    int e = g & 7, lane = (g >> 3) & 63, kk = (g >> 9) & 3, nt = g >> 11;
    int k = kk*32 + (lane >> 4)*8 + e;
    int n = nt*16 + (lane & 15);
    W1F[g] = f2b(W1[k*FF + n]);
  } else if (idx < 196608) {
    int g = idx - 163840;
    int e = g & 7, lane = (g >> 3) & 63, kk = (g >> 9) & 7, nt = g >> 12;
    int k = kk*32 + (lane >> 4)*8 + e;
    int n = nt*16 + (lane & 15);
    W2F[g] = f2b(W2[k*HD + n]);
  } else if (idx < 200704) {
    int g = idx - 196608;
    int e = g & 7, lane = (g >> 3) & 63, nt = g >> 9;
    int k = (lane >> 4)*8 + e;
    int n = nt*16 + (lane & 15);
    encWF[g] = (k < FD) ? f2b(encW[k*HD + n]) : (unsigned short)0;
  } else if (idx < 217088) {
    int g = idx - 200704;
    int e = g & 7, lane = (g >> 3) & 63, kk = (g >> 9) & 3, nt = g >> 11;
    int k = kk*32 + (lane >> 4)*8 + e;
    int n = nt*16 + (lane & 15);
    gW1F[g] = f2b(gW1[k*HD + n]);
  } else if (idx < 217216) { int t = idx - 217088; encBf[t] = encB[t]; }
  else if (idx < 217472)   { int t = idx - 217216; fb1f[t] = fb1[t]; }
  else if (idx < 217600)   { int t = idx - 217472; fb2f[t] = fb2[t]; }
  else if (idx < 217728)   { int t = idx - 217600; l1gf[t] = l1g[t]; }
  else if (idx < 217856)   { int t = idx - 217728; l1bf[t] = l1b[t]; }
  else if (idx < 217984)   { int t = idx - 217856; l2gf[t] = l2g[t]; }
  else                     { int t = idx - 217984; l2bf[t] = l2b[t]; }
}

// ---------------- fused transformer + GAT1-pre (8 nodes/block) --------------
// ALL LDS row strides are multiples of 8 shorts (16 B) so bs8 A-frag loads
// stay single ds_read_b128 (round-8 regression: 132/260/516 strides broke
// 16B alignment on odd rows -> split loads, -90 us).
__global__ __launch_bounds__(256) void k_xform(
    const float* __restrict__ xh, const float* __restrict__ xc,
    const unsigned short* __restrict__ MuF, const unsigned short* __restrict__ PwF,
    const unsigned short* __restrict__ W1F, const unsigned short* __restrict__ W2F,
    const unsigned short* __restrict__ encWF, const unsigned short* __restrict__ gW1F,
    const float* __restrict__ encBf,
    const float* __restrict__ fb1f, const float* __restrict__ fb2f,
    const float* __restrict__ l1gf, const float* __restrict__ l1bf,
    const float* __restrict__ l2gf, const float* __restrict__ l2bf,
    const float* __restrict__ asrc, const float* __restrict__ adrc,
    float* __restrict__ xl1, float* __restrict__ s1, float* __restrict__ d1)
{
  // big: hsB (ph1-5) then {r1F,h1s,h1B,f1B,r2F} (ph6-10)
  __shared__ __align__(16) char big[26112];
  __shared__ float hlastF[8][128];
  __shared__ unsigned short hlastB[16*136];    // rows 8-15 junk -> D discarded
  __shared__ float lgaw[8][NH][TT];
  __shared__ __align__(16) char regB[16896];   // xB -> usF -> wB -> xlF

  unsigned short* hsB = (unsigned short*)big;          // [(nl*12+t)][136]
  float* r1F = (float*)big;                            // [8][132] ph6-7
  float* h1s = (float*)(big + 4224);                   // [8][132] ph7-9
  unsigned short* h1B = (unsigned short*)(big + 8448); // [16][136] ph7-8
  unsigned short* f1B = (unsigned short*)(big + 12800);// [16][264] ph8-9
  float* r2F = (float*)(big + 8448);                   // [8][132] ph9-10 (over h1B)

  unsigned short* xB = (unsigned short*)regB;          // [96][40] ph0-1
  float* usF = (float*)regB;                           // [8][4][132] ph2-3
  unsigned short* wB = (unsigned short*)regB;          // [16][520] ph5-6
  float* xlF = (float*)regB;                           // [8][128] ph11

  const int tid  = threadIdx.x;
  const int w    = tid >> 6;
  const int lane = tid & 63;
  const int m0   = blockIdx.x * 8;
  const int arow = lane & 15, akg = lane >> 4;

  // --- phase 0: load x -> xB bf16, rows = t*8+nl, K zero-padded 16..31 ---
  #pragma unroll
  for (int k = 0; k < 6; ++k) {
    int idx = tid + k*256;
    int f = idx & 15, rest = idx >> 4;
    int nl = rest & 7, t = rest >> 3;
    int m = m0 + nl, b = m / NN, n = m - b*NN;
    float v = (f < 8) ? xh[(((size_t)b*TT + t)*NN + n)*8 + f]
                      : xc[(((size_t)b*TT + t)*NN + n)*8 + (f - 8)];
    xB[(t*8 + nl)*40 + f] = f2b(v);
  }
  #pragma unroll
  for (int k = 0; k < 6; ++k) {
    int idx = tid + k*256;
    xB[(idx >> 4)*40 + 16 + (idx & 15)] = 0;
  }
  __syncthreads();

  // --- phase 1: encoder via MFMA (96x128 = 6 mt x 8 nt tiles) ---
  {
    const bs8* ef = (const bs8*)encWF;
    bs8 b0 = ef[(2*w + 0)*64 + lane];
    bs8 b1 = ef[(2*w + 1)*64 + lane];
    int drow = akg*4, dc = arow;
    int j0 = (2*w + 0)*16 + dc, j1 = (2*w + 1)*16 + dc;
    float eb0 = encBf[j0], eb1 = encBf[j1];
    fvec4 z4 = {0.f, 0.f, 0.f, 0.f};
    #pragma unroll
    for (int mt = 0; mt < 6; ++mt) {
      bs8 af = *(const bs8*)&xB[(mt*16 + arow)*40 + akg*8];
      fvec4 d0 = mfma16(af, b0, z4);
      fvec4 d1 = mfma16(af, b1, z4);
      #pragma unroll
      for (int reg = 0; reg < 4; ++reg) {
        int gr = mt*16 + drow + reg;
        int t = gr >> 3, nl = gr & 7;
        float v0 = d0[reg] + eb0, v1 = d1[reg] + eb1;
        hsB[(nl*12 + t)*136 + j0] = f2b(v0);
        hsB[(nl*12 + t)*136 + j1] = f2b(v1);
        if (t == TT-1) {
          hlastF[nl][j0] = v0; hlastB[nl*136 + j0] = f2b(v0);
          hlastF[nl][j1] = v1; hlastB[nl*136 + j1] = f2b(v1);
        }
      }
    }
  }
  __syncthreads();                // xB dead

  // --- phase 2: u = h_last @ Mu via MFMA -> usF fp32 ---
  {
    bs8 af[4];
    #pragma unroll
    for (int kk = 0; kk < 4; ++kk)
      af[kk] = *(const bs8*)&hlastB[arow*136 + kk*32 + akg*8];
    const bs8* bp = (const bs8*)MuF;
    fvec4 acc[8];
    #pragma unroll
    for (int n8 = 0; n8 < 8; ++n8) {
      int nt = w*8 + n8;
      const bs8* bq = bp + nt*256 + lane;
      fvec4 a4 = {0.f, 0.f, 0.f, 0.f};
      #pragma unroll
      for (int kk = 0; kk < 4; ++kk)
        a4 = mfma16(af[kk], bq[kk*64], a4);
      acc[n8] = a4;
    }
    if (lane < 32) {
      int drow = akg*4, dc = arow;
      #pragma unroll
      for (int n8 = 0; n8 < 8; ++n8) {
        int col = (w*8 + n8)*16 + dc, hd = col >> 7, c = col & 127;
        #pragma unroll
        for (int reg = 0; reg < 4; ++reg)
          usF[((drow + reg)*4 + hd)*132 + c] = acc[n8][reg];
      }
    }
  }
  __syncthreads();

  // --- phase 3: logits (8n x 4h x 12t = 384 dots of K=128) ---
  #pragma unroll
  for (int pass = 0; pass < 2; ++pass) {
    int item = pass*256 + tid;
    if (item < 384) {
      int nl = item / 48, p = item - nl*48, hd = p / 12, t = p - hd*12;
      const float* up = &usF[(nl*4 + hd)*132];
      float a = 0.f;
      for (int i8 = 0; i8 < 16; ++i8) {
        bvec8 hb8 = *(const bvec8*)&hsB[(nl*12 + t)*136 + i8*8];
        const fvec4* uq = (const fvec4*)&up[i8*8];
        fvec4 u0 = uq[0], u1 = uq[1];
        a += b2f(hb8[0])*u0[0] + b2f(hb8[1])*u0[1] + b2f(hb8[2])*u0[2] + b2f(hb8[3])*u0[3]
           + b2f(hb8[4])*u1[0] + b2f(hb8[5])*u1[1] + b2f(hb8[6])*u1[2] + b2f(hb8[7])*u1[3];
      }
      lgaw[nl][hd][t] = a * 0.17677669529663687f;
    }
  }
  __syncthreads();

  // --- phase 4: softmax over t ---
  if (tid < 32) {
    int nl = tid >> 2, hd = tid & 3;
    float mx = -1e30f;
    #pragma unroll
    for (int t = 0; t < TT; ++t) mx = fmaxf(mx, lgaw[nl][hd][t]);
    float ex[TT], sm = 0.f;
    #pragma unroll
    for (int t = 0; t < TT; ++t) { ex[t] = expf(lgaw[nl][hd][t] - mx); sm += ex[t]; }
    float inv = 1.f / sm;
    #pragma unroll
    for (int t = 0; t < TT; ++t) lgaw[nl][hd][t] = ex[t] * inv;
  }
  __syncthreads();

  // --- phase 5: w_h = sum_t alpha*h_t -> wB bf16 (over usF) ---
  {
    int g = tid >> 7, j = tid & 127;
    #pragma unroll
    for (int r = 0; r < 4; ++r) {
      int nl = g*4 + r;
      float wacc[NH] = {0.f, 0.f, 0.f, 0.f};
      #pragma unroll
      for (int t = 0; t < TT; ++t) {
        float hv = b2f(hsB[(nl*12 + t)*136 + j]);
        #pragma unroll
        for (int hd = 0; hd < NH; ++hd) wacc[hd] += lgaw[nl][hd][t] * hv;
      }
      #pragma unroll
      for (int hd = 0; hd < NH; ++hd) wB[nl*520 + hd*128 + j] = f2b(wacc[hd]);
    }
  }
  __syncthreads();                // hsB dead after this point

  // --- phase 6: oa = w @ Pw via MFMA; r1 = h_last + oa -> r1F (over hsB) ---
  {
    fvec4 pacc0 = {0.f,0.f,0.f,0.f}, pacc1 = {0.f,0.f,0.f,0.f};
    const bs8* bp = (const bs8*)PwF;
    const bs8* bq0 = bp + (w*2 + 0)*1024 + lane;
    const bs8* bq1 = bp + (w*2 + 1)*1024 + lane;
    #pragma unroll
    for (int kk = 0; kk < 16; ++kk) {
      bs8 af = *(const bs8*)&wB[arow*520 + kk*32 + akg*8];
      pacc0 = mfma16(af, bq0[kk*64], pacc0);
      pacc1 = mfma16(af, bq1[kk*64], pacc1);
    }
    if (lane < 32) {
      int drow = akg*4, dc = arow;
      #pragma unroll
      for (int reg = 0; reg < 4; ++reg) {
        int nd = drow + reg;
        int c0 = (w*2 + 0)*16 + dc;
        int c1 = (w*2 + 1)*16 + dc;
        r1F[nd*132 + c0] = hlastF[nd][c0] + pacc0[reg];
        r1F[nd*132 + c1] = hlastF[nd][c1] + pacc1[reg];
      }
    }
  }
  __syncthreads();

  // --- phase 7: LN1 -> h1s fp32 + h1B bf16 ---
  {
    int nd = tid >> 5, l32 = tid & 31;
    float v[4], s = 0.f, q = 0.f;
    #pragma unroll
    for (int k = 0; k < 4; ++k) {
      v[k] = r1F[nd*132 + l32 + k*32];
      s += v[k]; q += v[k]*v[k];
    }
    #pragma unroll
    for (int off = 16; off > 0; off >>= 1) { s += __shfl_xor(s, off); q += __shfl_xor(q, off); }
    float mu = s*(1.f/128.f), var = q*(1.f/128.f) - mu*mu, rs = rsqrtf(var + 1e-5f);
    #pragma unroll
    for (int k = 0; k < 4; ++k) {
      int c = l32 + k*32;
      float hv = (v[k] - mu)*rs*l1gf[c] + l1bf[c];
      h1s[nd*132 + c] = hv;
      h1B[nd*136 + c] = f2b(hv);
    }
  }
  __syncthreads();

  // --- phase 8: FFN1 via MFMA (K=128, N=256), relu+bias fused -> f1B bf16 ---
  {
    bs8 af[4];
    #pragma unroll
    for (int kk = 0; kk < 4; ++kk)
      af[kk] = *(const bs8*)&h1B[arow*136 + kk*32 + akg*8];
    const bs8* bp = (const bs8*)W1F;
    #pragma unroll
    for (int n4 = 0; n4 < 4; ++n4) {
      int nt = w*4 + n4;
      const bs8* bq = bp + nt*256 + lane;
      fvec4 a4 = {0.f, 0.f, 0.f, 0.f};
      #pragma unroll
      for (int kk = 0; kk < 4; ++kk)
        a4 = mfma16(af[kk], bq[kk*64], a4);
      if (lane < 32) {
        int drow = akg*4, dc = arow;
        int n = nt*16 + dc;
        float bias = fb1f[n];
        #pragma unroll
        for (int reg = 0; reg < 4; ++reg)
          f1B[(drow + reg)*264 + n] = f2b(fmaxf(a4[reg] + bias, 0.f));
      }
    }
  }
  __syncthreads();

  // --- phase 9: FFN2 via MFMA (K=256, N=128) + residual -> r2F (over h1B) ---
  {
    const bs8* bp = (const bs8*)W2F;
    #pragma unroll
    for (int n2 = 0; n2 < 2; ++n2) {
      int nt = w*2 + n2;
      const bs8* bq = bp + nt*512 + lane;
      fvec4 a4 = {0.f, 0.f, 0.f, 0.f};
      #pragma unroll
      for (int kk = 0; kk < 8; ++kk) {
        bs8 af = *(const bs8*)&f1B[arow*264 + kk*32 + akg*8];
        a4 = mfma16(af, bq[kk*64], a4);
      }
      if (lane < 32) {
        int drow = akg*4, dc = arow;
        int c = nt*16 + dc;
        float fb2v = fb2f[c];
        #pragma unroll
        for (int reg = 0; reg < 4; ++reg) {
          int nd = drow + reg;
          r2F[nd*132 + c] = h1s[nd*132 + c] + fb2v + a4[reg];
        }
      }
    }
  }
  __syncthreads();

  // --- phase 10: LN2 -> hlastB bf16 (A-frags for GAT1 projection) ---
  {
    int nd = tid >> 5, l32 = tid & 31;
    float v[4], s = 0.f, q = 0.f;
    #pragma unroll
    for (int k = 0; k < 4; ++k) {
      v[k] = r2F[nd*132 + l32 + k*32];
      s += v[k]; q += v[k]*v[k];
    }
    #pragma unroll
    for (int off = 16; off > 0; off >>= 1) { s += __shfl_xor(s, off); q += __shfl_xor(q, off); }
    float mu = s*(1.f/128.f), var = q*(1.f/128.f) - mu*mu, rs = rsqrtf(var + 1e-5f);
    #pragma unroll
    for (int k = 0; k < 4; ++k) {
      int c = l32 + k*32;
      hlastB[nd*136 + c] = f2b((v[k] - mu)*rs*l2gf[c] + l2bf[c]);
    }
  }
  __syncthreads();

  // --- phase 11: xl1 = hlast @ gW1 via MFMA; s1/d1 reduce; globals out ---
  {
    bs8 af[4];
    #pragma unroll
    for (int kk = 0; kk < 4; ++kk)
      af[kk] = *(const bs8*)&hlastB[arow*136 + kk*32 + akg*8];
    const bs8* bp = (const bs8*)gW1F;
    #pragma unroll
    for (int n2 = 0; n2 < 2; ++n2) {
      int nt = w*2 + n2;
      const bs8* bq = bp + nt*256 + lane;
      fvec4 a4 = {0.f, 0.f, 0.f, 0.f};
      #pragma unroll
      for (int kk = 0; kk < 4; ++kk)
        a4 = mfma16(af[kk], bq[kk*64], a4);
      if (lane < 32) {
        int drow = akg*4, dc = arow;
        int c = nt*16 + dc;
        #pragma unroll
        for (int reg = 0; reg < 4; ++reg)
          xlF[(drow + reg)*128 + c] = a4[reg];
      }
    }
  }
  __syncthreads();
  {
    // coalesced xl1 write: 4 consecutive floats per thread
    fvec4 vv = ((const fvec4*)xlF)[tid];
    *(fvec4*)&xl1[(size_t)m0*HD + tid*4] = vv;
    // s1/d1: nd = tid>>5; 4 cols per lane (col = l32 + k*32)
    int nd = tid >> 5, l32 = tid & 31;
    float pa[4], pb[4];
    #pragma unroll
    for (int k = 0; k < 4; ++k) {
      float xv = xlF[nd*128 + l32 + k*32];
      pa[k] = xv * asrc[l32 + k*32];
      pb[k] = xv * adrc[l32 + k*32];
    }
    #pragma unroll
    for (int off = 16; off > 0; off >>= 1) {
      #pragma unroll
      for (int k = 0; k < 4; ++k) {
        pa[k] += __shfl_xor(pa[k], off);
        pb[k] += __shfl_xor(pb[k], off);
      }
    }
    if (l32 == 0) {
      int m = m0 + nd;
      #pragma unroll
      for (int k = 0; k < 4; ++k) {
        s1[m*NH + k] = pa[k];
        d1[m*NH + k] = pb[k];
      }
    }
  }
}

// ---------------- CSR build (batch-shared) ----------------------------------
__global__ __launch_bounds__(256) void k_zero(int* __restrict__ cnt)
{
  int i = blockIdx.x * 256 + threadIdx.x;
  if (i < NN) cnt[i] = 0;
}

__global__ __launch_bounds__(256) void k_hist(const int* __restrict__ e1,
                                              int* __restrict__ cnt)
{
  int i = blockIdx.x * 256 + threadIdx.x;
  if (i < EE) atomicAdd(&cnt[e1[i]], 1);
}

__global__ __launch_bounds__(1024) void k_scan(const int* __restrict__ cnt,
                                               int* __restrict__ row_ptr,
                                               int* __restrict__ cur)
{
  __shared__ int sm[1024];
  int tid = threadIdx.x;
  int base = tid * 10;
  int loc[10];
  int s = 0;
  #pragma unroll
  for (int k = 0; k < 10; ++k) {
    int idx = base + k;
    int v = (idx < NN) ? cnt[idx] : 0;
    loc[k] = s;
    s += v;
  }
  sm[tid] = s;
  __syncthreads();
  for (int off = 1; off < 1024; off <<= 1) {
    int t = (tid >= off) ? sm[tid - off] : 0;
    __syncthreads();
    sm[tid] += t;
    __syncthreads();
  }
  int segbase = sm[tid] - s;
  #pragma unroll
  for (int k = 0; k < 10; ++k) {
    int idx = base + k;
    if (idx < NN) { int o = segbase + loc[k]; row_ptr[idx] = o; cur[idx] = o; }
  }
  if (tid == 1023) row_ptr[NN] = sm[1023];
}

__global__ __launch_bounds__(256) void k_scatter(const int* __restrict__ e0,
                                                 const int* __restrict__ e1,
                                                 int* __restrict__ cur,
                                                 int* __restrict__ ssrc)
{
  int i = blockIdx.x * 256 + threadIdx.x;
  if (i >= EE) return;
  int pos = atomicAdd(&cur[e1[i]], 1);
  ssrc[pos] = e0[i];
}

// ---------------- GAT1 gather + GAT2 pre (fused; 1 node/block) --------------
__global__ __launch_bounds__(128) void k_g1(
    const int* __restrict__ row_ptr, const int* __restrict__ ssrc,
    const float* __restrict__ xl, const float* __restrict__ s1, const float* __restrict__ d1,
    const float* __restrict__ gb1, const float* __restrict__ gW2,
    const float* __restrict__ asr2, const float* __restrict__ adr2,
    float* __restrict__ xl2, float* __restrict__ s2, float* __restrict__ d2)
{
  __shared__ float g1s[HD];
  int j = threadIdx.x, m = blockIdx.x, h = j >> 5;
  int b = m / NN, n = m - b * NN, boff = b * NN;
  float dh = d1[m*NH + h];
  int r0 = row_ptr[n], r1 = row_ptr[n+1];
  float acc = 0.f, dsum = 0.f;
  for (int e = r0; e < r1; ++e) {
    int src = ssrc[e] + boff;
    float ev = expf(lrelu(s1[src*NH + h] + dh));
    acc  += ev * xl[(size_t)src*HD + j];
    dsum += ev;
  }
  float es = expf(lrelu(s1[m*NH + h] + dh));    // self loop
  acc  += es * xl[(size_t)m*HD + j];
  dsum += es;
  float v = acc / (dsum + 1e-16f) + gb1[j];
  g1s[j] = v > 0.f ? v : expm1f(v);             // ELU
  __syncthreads();
  if (j < GO) {
    float a = 0.f;
    for (int i = 0; i < HD; ++i) a += g1s[i] * gW2[i*GO + j];
    xl2[(size_t)m*GO + j] = a;
    float pa = a * asr2[j], pb = a * adr2[j];
    #pragma unroll
    for (int off = 32; off > 0; off >>= 1) { pa += __shfl_xor(pa, off); pb += __shfl_xor(pb, off); }
    if (j == 0) { s2[m] = pa; d2[m] = pb; }
  }
}

// ---------------- GAT2 gather + output projection ---------------------------
__global__ __launch_bounds__(64) void k_g2(
    const int* __restrict__ row_ptr, const int* __restrict__ ssrc,
    const float* __restrict__ xl2, const float* __restrict__ s2, const float* __restrict__ d2,
    const float* __restrict__ gb2, const float* __restrict__ oW, const float* __restrict__ ob,
    float* __restrict__ y)
{
  __shared__ float g2s[GO];
  int j = threadIdx.x, m = blockIdx.x;
  int b = m / NN, n = m - b * NN, boff = b * NN;
  float d2m = d2[m];
  int r0 = row_ptr[n], r1 = row_ptr[n+1];
  float acc = 0.f, dsum = 0.f;
  for (int e = r0; e < r1; ++e) {
    int src = ssrc[e] + boff;
    float ev = expf(lrelu(s2[src] + d2m));
    acc  += ev * xl2[(size_t)src*GO + j];
    dsum += ev;
  }
  float es = expf(lrelu(s2[m] + d2m));
  acc  += es * xl2[(size_t)m*GO + j];
  dsum += es;
  g2s[j] = acc / (dsum + 1e-16f) + gb2[j];
  __syncthreads();
  if (j < HR) {
    float a = ob[j];
    #pragma unroll
    for (int o2 = 0; o2 < GO; ++o2) a += g2s[o2] * oW[o2*HR + j];
    y[((size_t)b*HR + j)*NN + n] = a;
  }
}

// ---------------- launch ----------------------------------------------------
extern "C" void kernel_launch(void* const* d_in, const int* in_sizes, int n_in,
                              void* d_out, int out_size, void* d_ws, size_t ws_size,
                              hipStream_t stream)
{
  const int* ei = (const int*)d_in[2];
  const int* e0 = ei;
  const int* e1 = ei + EE;

  float* ws   = (float*)d_ws;
  float* xl1  = ws;                   // 40000*128
  float* xl2  = ws + 5120000;         // 40000*64
  float* ovl  = ws + 10240000;        // overlap region (weights, then CSR)
  float* s1   = ws + 15360000;        // 40000*4
  float* d1   = ws + 15520000;        // 40000*4
  float* s2   = ws + 15680000;        // 40000
  float* d2   = ws + 15720000;        // 40000

  // Weight buffers live [prep, xform] in the overlap region.
  unsigned short* Mu    = (unsigned short*)ovl;          // 65536 bf16 frags
  unsigned short* Pw    = Mu + 65536;                    // 65536
  unsigned short* W1F   = Mu + 131072;                   // 32768
  unsigned short* W2F   = Mu + 163840;                   // 32768
  unsigned short* encWF = Mu + 196608;                   // 4096
  unsigned short* gW1F  = Mu + 200704;                   // 16384
  float* encBf = (float*)(Mu + 217088);
  float* fb1f  = encBf + 128;
  float* fb2f  = fb1f + 256;
  float* l1gf  = fb2f + 128;
  float* l1bf  = l1gf + 128;
  float* l2gf  = l1bf + 128;
  float* l2bf  = l2gf + 128;

  // CSR arrays live [hist, end] in the SAME overlap region (stream-serial).
  int* cnt     = (int*)ovl;           // 10000
  int* row_ptr = cnt + 16384;         // 10001
  int* cur     = cnt + 32768;         // 10000
  int* ssrc    = cnt + 49152;         // 160000

  k_prep<<<852, 256, 0, stream>>>(
      (const float*)d_in[5], (const float*)d_in[6], (const float*)d_in[7], (const float*)d_in[8],
      (const float*)d_in[3], (const float*)d_in[4], (const float*)d_in[11], (const float*)d_in[12],
      (const float*)d_in[13], (const float*)d_in[14], (const float*)d_in[9], (const float*)d_in[10],
      (const float*)d_in[15], (const float*)d_in[16], (const float*)d_in[17],
      Mu, Pw, W1F, W2F, encWF, gW1F,
      encBf, fb1f, fb2f, l1gf, l1bf, l2gf, l2bf);

  k_xform<<<MM/8, 256, 0, stream>>>(
      (const float*)d_in[0], (const float*)d_in[1],
      Mu, Pw, W1F, W2F, encWF, gW1F,
      encBf, fb1f, fb2f, l1gf, l1bf, l2gf, l2bf,
      (const float*)d_in[18], (const float*)d_in[19],
      xl1, s1, d1);

  // CSR build (after xform: overlap region is free now)
  k_zero<<<(NN + 255)/256, 256, 0, stream>>>(cnt);
  k_hist<<<(EE + 255)/256, 256, 0, stream>>>(e1, cnt);
  k_scan<<<1, 1024, 0, stream>>>(cnt, row_ptr, cur);
  k_scatter<<<(EE + 255)/256, 256, 0, stream>>>(e0, e1, cur, ssrc);

  k_g1<<<MM, 128, 0, stream>>>(row_ptr, ssrc, xl1, s1, d1,
      (const float*)d_in[20], (const float*)d_in[21],
      (const float*)d_in[22], (const float*)d_in[23],
      xl2, s2, d2);

  k_g2<<<MM, 64, 0, stream>>>(row_ptr, ssrc, xl2, s2, d2,
      (const float*)d_in[24], (const float*)d_in[25], (const float*)d_in[26],
      (float*)d_out);
}

// Round 10
// 293.163 us; speedup vs baseline: 6.3295x; 1.1495x over previous
//
#include <hip/hip_runtime.h>
#include <hip/hip_bf16.h>

#define DEV static __device__ __forceinline__

constexpr int BB = 4;        // batches
constexpr int TT = 12;       // timesteps
constexpr int NN = 10000;    // nodes per batch
constexpr int FD = 16;       // input features (8+8)
constexpr int HD = 128;      // hidden
constexpr int NH = 4;        // attn heads
constexpr int DH = 32;       // head dim
constexpr int FF = 256;      // ffn hidden
constexpr int GO = 64;       // gat2 out
constexpr int HR = 24;       // horizon
constexpr int EE = 160000;   // edges per batch
constexpr int MM = BB * NN;  // total nodes

typedef unsigned short bvec8 __attribute__((ext_vector_type(8)));
typedef unsigned short usvec4 __attribute__((ext_vector_type(4)));
typedef float fvec4 __attribute__((ext_vector_type(4)));
typedef short bs8 __attribute__((ext_vector_type(8)));      // MFMA bf16 frag (4 VGPR)

DEV float lrelu(float x) { return x >= 0.f ? x : 0.2f * x; }

DEV float b2f(unsigned short u) {
  union { unsigned int i; float f; } x; x.i = ((unsigned int)u) << 16; return x.f;
}
DEV unsigned short f2b(float f) {
  union { float f; unsigned int i; } x; x.f = f;
  unsigned int r = x.i + 0x7FFFu + ((x.i >> 16) & 1u);
  return (unsigned short)(r >> 16);
}
DEV void up2(unsigned int u, float& lo, float& hi) {
  union { unsigned int i; float f; } a, b;
  a.i = u << 16; b.i = u & 0xFFFF0000u;
  lo = a.f; hi = b.f;
}

DEV fvec4 mfma16(bs8 a, bs8 b, fvec4 c) {
  return __builtin_amdgcn_mfma_f32_16x16x32_bf16(a, b, c, 0, 0, 0);
}

// ---------------- prep: fold + re-layout ALL transformer weights (fp32 in) --
// MFMA B-fragment order: frag idx = ((nt*nK + kk)*64 + lane), element e:
//   B[k][n] with k = kk*32 + (lane>>4)*8 + e, n = nt*16 + (lane&15).
__global__ __launch_bounds__(256) void k_prep(
    const float* __restrict__ Wq, const float* __restrict__ Wk,
    const float* __restrict__ Wv, const float* __restrict__ Wo,
    const float* __restrict__ encW, const float* __restrict__ encB,
    const float* __restrict__ W1, const float* __restrict__ fb1,
    const float* __restrict__ W2, const float* __restrict__ fb2,
    const float* __restrict__ l1g, const float* __restrict__ l1b,
    const float* __restrict__ l2g, const float* __restrict__ l2b,
    const float* __restrict__ gW1,
    unsigned short* __restrict__ Mu, unsigned short* __restrict__ Pw,
    unsigned short* __restrict__ W1F, unsigned short* __restrict__ W2F,
    unsigned short* __restrict__ encWF, unsigned short* __restrict__ gW1F,
    float* __restrict__ encBf, float* __restrict__ fb1f, float* __restrict__ fb2f,
    float* __restrict__ l1gf, float* __restrict__ l1bf,
    float* __restrict__ l2gf, float* __restrict__ l2bf)
{
  int idx = blockIdx.x * 256 + threadIdx.x;      // 852*256 = 218112 exactly
  if (idx < 65536) {
    int e = idx & 7, lane = (idx >> 3) & 63, kk = (idx >> 9) & 3, nt = idx >> 11;
    int i = kk*32 + (lane >> 4)*8 + e;
    int q = nt*16 + (lane & 15);
    int h = q >> 7, c = q & 127;
    float a = 0.f;
    #pragma unroll 8
    for (int d = 0; d < DH; ++d)
      a += Wq[i*HD + h*DH + d] * Wk[c*HD + h*DH + d];
    Mu[idx] = f2b(a);
  } else if (idx < 131072) {
    int g2 = idx - 65536;
    int e = g2 & 7, lane = (g2 >> 3) & 63, kk = (g2 >> 9) & 15, nt = g2 >> 13;
    int q = kk*32 + (lane >> 4)*8 + e;
    int j = nt*16 + (lane & 15);
    int h = q >> 7, i = q & 127;
    float a = 0.f;
    #pragma unroll 8
    for (int d = 0; d < DH; ++d)
      a += Wv[i*HD + h*DH + d] * Wo[(h*DH + d)*HD + j];
    Pw[g2] = f2b(a);
  } else if (idx < 163840) {
    int g = idx - 131072;
    int e = g & 7, lane = (g >> 3) & 63, kk = (g >> 9) & 3, nt = g >> 11;
    int k = kk*32 + (lane >> 4)*8 + e;
    int n = nt*16 + (lane & 15);
    W1F[g] = f2b(W1[k*FF + n]);
  } else if (idx < 196608) {
    int g = idx - 163840;
    int e = g & 7, lane = (g >> 3) & 63, kk = (g >> 9) & 7, nt = g >> 12;
    int k = kk*32 + (lane >> 4)*8 + e;
    int n = nt*16 + (lane & 15);
    W2F[g] = f2b(W2[k*HD + n]);
  } else if (idx < 200704) {
    int g = idx - 196608;
    int e = g & 7, lane = (g >> 3) & 63, nt = g >> 9;
    int k = (lane >> 4)*8 + e;
    int n = nt*16 + (lane & 15);
    encWF[g] = (k < FD) ? f2b(encW[k*HD + n]) : (unsigned short)0;
  } else if (idx < 217088) {
    int g = idx - 200704;
    int e = g & 7, lane = (g >> 3) & 63, kk = (g >> 9) & 3, nt = g >> 11;
    int k = kk*32 + (lane >> 4)*8 + e;
    int n = nt*16 + (lane & 15);
    gW1F[g] = f2b(gW1[k*HD + n]);
  } else if (idx < 217216) { int t = idx - 217088; encBf[t] = encB[t]; }
  else if (idx < 217472)   { int t = idx - 217216; fb1f[t] = fb1[t]; }
  else if (idx < 217600)   { int t = idx - 217472; fb2f[t] = fb2[t]; }
  else if (idx < 217728)   { int t = idx - 217600; l1gf[t] = l1g[t]; }
  else if (idx < 217856)   { int t = idx - 217728; l1bf[t] = l1b[t]; }
  else if (idx < 217984)   { int t = idx - 217856; l2gf[t] = l2g[t]; }
  else                     { int t = idx - 217984; l2bf[t] = l2b[t]; }
}

// ---------------- fused transformer + GAT1-pre (8 nodes/block) --------------
// ALL LDS row strides for bs8 A-frag loads are multiples of 8 shorts (16 B)
// so they stay single ds_read_b128 (round-8 lesson).
__global__ __launch_bounds__(256) void k_xform(
    const float* __restrict__ xh, const float* __restrict__ xc,
    const unsigned short* __restrict__ MuF, const unsigned short* __restrict__ PwF,
    const unsigned short* __restrict__ W1F, const unsigned short* __restrict__ W2F,
    const unsigned short* __restrict__ encWF, const unsigned short* __restrict__ gW1F,
    const float* __restrict__ encBf,
    const float* __restrict__ fb1f, const float* __restrict__ fb2f,
    const float* __restrict__ l1gf, const float* __restrict__ l1bf,
    const float* __restrict__ l2gf, const float* __restrict__ l2bf,
    const float* __restrict__ asrc, const float* __restrict__ adrc,
    unsigned short* __restrict__ xl1B, float* __restrict__ s1, float* __restrict__ d1)
{
  // big: hsB (ph1-5) then {r1F,h1s,h1B,f1B,r2F} (ph6-10)
  __shared__ __align__(16) char big[26112];
  __shared__ float hlastF[8][128];
  __shared__ unsigned short hlastB[16*136];    // rows 8-15 junk -> D discarded
  __shared__ float lgaw[8][NH][TT];
  __shared__ __align__(16) char regB[16896];   // xB -> usF -> wB -> xlF

  unsigned short* hsB = (unsigned short*)big;          // [(nl*12+t)][136]
  float* r1F = (float*)big;                            // [8][132] ph6-7
  float* h1s = (float*)(big + 4224);                   // [8][132] ph7-9
  unsigned short* h1B = (unsigned short*)(big + 8448); // [16][136] ph7-8
  unsigned short* f1B = (unsigned short*)(big + 12800);// [16][264] ph8-9
  float* r2F = (float*)(big + 8448);                   // [8][132] ph9-10 (over h1B)

  unsigned short* xB = (unsigned short*)regB;          // [96][40] ph0-1
  float* usF = (float*)regB;                           // [8][4][132] ph2-3
  unsigned short* wB = (unsigned short*)regB;          // [16][520] ph5-6
  float* xlF = (float*)regB;                           // [8][128] ph11

  const int tid  = threadIdx.x;
  const int w    = tid >> 6;
  const int lane = tid & 63;
  const int m0   = blockIdx.x * 8;
  const int arow = lane & 15, akg = lane >> 4;

  // --- phase 0: load x -> xB bf16, rows = t*8+nl, K zero-padded 16..31 ---
  #pragma unroll
  for (int k = 0; k < 6; ++k) {
    int idx = tid + k*256;
    int f = idx & 15, rest = idx >> 4;
    int nl = rest & 7, t = rest >> 3;
    int m = m0 + nl, b = m / NN, n = m - b*NN;
    float v = (f < 8) ? xh[(((size_t)b*TT + t)*NN + n)*8 + f]
                      : xc[(((size_t)b*TT + t)*NN + n)*8 + (f - 8)];
    xB[(t*8 + nl)*40 + f] = f2b(v);
  }
  #pragma unroll
  for (int k = 0; k < 6; ++k) {
    int idx = tid + k*256;
    xB[(idx >> 4)*40 + 16 + (idx & 15)] = 0;
  }
  __syncthreads();

  // --- phase 1: encoder via MFMA (96x128 = 6 mt x 8 nt tiles) ---
  {
    const bs8* ef = (const bs8*)encWF;
    bs8 b0 = ef[(2*w + 0)*64 + lane];
    bs8 b1 = ef[(2*w + 1)*64 + lane];
    int drow = akg*4, dc = arow;
    int j0 = (2*w + 0)*16 + dc, j1 = (2*w + 1)*16 + dc;
    float eb0 = encBf[j0], eb1 = encBf[j1];
    fvec4 z4 = {0.f, 0.f, 0.f, 0.f};
    #pragma unroll
    for (int mt = 0; mt < 6; ++mt) {
      bs8 af = *(const bs8*)&xB[(mt*16 + arow)*40 + akg*8];
      fvec4 d0 = mfma16(af, b0, z4);
      fvec4 d1 = mfma16(af, b1, z4);
      #pragma unroll
      for (int reg = 0; reg < 4; ++reg) {
        int gr = mt*16 + drow + reg;
        int t = gr >> 3, nl = gr & 7;
        float v0 = d0[reg] + eb0, v1 = d1[reg] + eb1;
        hsB[(nl*12 + t)*136 + j0] = f2b(v0);
        hsB[(nl*12 + t)*136 + j1] = f2b(v1);
        if (t == TT-1) {
          hlastF[nl][j0] = v0; hlastB[nl*136 + j0] = f2b(v0);
          hlastF[nl][j1] = v1; hlastB[nl*136 + j1] = f2b(v1);
        }
      }
    }
  }
  __syncthreads();                // xB dead

  // --- phase 2: u = h_last @ Mu via MFMA -> usF fp32 ---
  {
    bs8 af[4];
    #pragma unroll
    for (int kk = 0; kk < 4; ++kk)
      af[kk] = *(const bs8*)&hlastB[arow*136 + kk*32 + akg*8];
    const bs8* bp = (const bs8*)MuF;
    fvec4 acc[8];
    #pragma unroll
    for (int n8 = 0; n8 < 8; ++n8) {
      int nt = w*8 + n8;
      const bs8* bq = bp + nt*256 + lane;
      fvec4 a4 = {0.f, 0.f, 0.f, 0.f};
      #pragma unroll
      for (int kk = 0; kk < 4; ++kk)
        a4 = mfma16(af[kk], bq[kk*64], a4);
      acc[n8] = a4;
    }
    if (lane < 32) {
      int drow = akg*4, dc = arow;
      #pragma unroll
      for (int n8 = 0; n8 < 8; ++n8) {
        int col = (w*8 + n8)*16 + dc, hd = col >> 7, c = col & 127;
        #pragma unroll
        for (int reg = 0; reg < 4; ++reg)
          usF[((drow + reg)*4 + hd)*132 + c] = acc[n8][reg];
      }
    }
  }
  __syncthreads();

  // --- phase 3: logits (8n x 4h x 12t = 384 dots of K=128) ---
  #pragma unroll
  for (int pass = 0; pass < 2; ++pass) {
    int item = pass*256 + tid;
    if (item < 384) {
      int nl = item / 48, p = item - nl*48, hd = p / 12, t = p - hd*12;
      const float* up = &usF[(nl*4 + hd)*132];
      float a = 0.f;
      for (int i8 = 0; i8 < 16; ++i8) {
        bvec8 hb8 = *(const bvec8*)&hsB[(nl*12 + t)*136 + i8*8];
        const fvec4* uq = (const fvec4*)&up[i8*8];
        fvec4 u0 = uq[0], u1 = uq[1];
        a += b2f(hb8[0])*u0[0] + b2f(hb8[1])*u0[1] + b2f(hb8[2])*u0[2] + b2f(hb8[3])*u0[3]
           + b2f(hb8[4])*u1[0] + b2f(hb8[5])*u1[1] + b2f(hb8[6])*u1[2] + b2f(hb8[7])*u1[3];
      }
      lgaw[nl][hd][t] = a * 0.17677669529663687f;
    }
  }
  __syncthreads();

  // --- phase 4: softmax over t ---
  if (tid < 32) {
    int nl = tid >> 2, hd = tid & 3;
    float mx = -1e30f;
    #pragma unroll
    for (int t = 0; t < TT; ++t) mx = fmaxf(mx, lgaw[nl][hd][t]);
    float ex[TT], sm = 0.f;
    #pragma unroll
    for (int t = 0; t < TT; ++t) { ex[t] = expf(lgaw[nl][hd][t] - mx); sm += ex[t]; }
    float inv = 1.f / sm;
    #pragma unroll
    for (int t = 0; t < TT; ++t) lgaw[nl][hd][t] = ex[t] * inv;
  }
  __syncthreads();

  // --- phase 5: w_h = sum_t alpha*h_t -> wB bf16 (over usF) ---
  {
    int g = tid >> 7, j = tid & 127;
    #pragma unroll
    for (int r = 0; r < 4; ++r) {
      int nl = g*4 + r;
      float wacc[NH] = {0.f, 0.f, 0.f, 0.f};
      #pragma unroll
      for (int t = 0; t < TT; ++t) {
        float hv = b2f(hsB[(nl*12 + t)*136 + j]);
        #pragma unroll
        for (int hd = 0; hd < NH; ++hd) wacc[hd] += lgaw[nl][hd][t] * hv;
      }
      #pragma unroll
      for (int hd = 0; hd < NH; ++hd) wB[nl*520 + hd*128 + j] = f2b(wacc[hd]);
    }
  }
  __syncthreads();                // hsB dead after this point

  // --- phase 6: oa = w @ Pw via MFMA; r1 = h_last + oa -> r1F (over hsB) ---
  {
    fvec4 pacc0 = {0.f,0.f,0.f,0.f}, pacc1 = {0.f,0.f,0.f,0.f};
    const bs8* bp = (const bs8*)PwF;
    const bs8* bq0 = bp + (w*2 + 0)*1024 + lane;
    const bs8* bq1 = bp + (w*2 + 1)*1024 + lane;
    #pragma unroll
    for (int kk = 0; kk < 16; ++kk) {
      bs8 af = *(const bs8*)&wB[arow*520 + kk*32 + akg*8];
      pacc0 = mfma16(af, bq0[kk*64], pacc0);
      pacc1 = mfma16(af, bq1[kk*64], pacc1);
    }
    if (lane < 32) {
      int drow = akg*4, dc = arow;
      #pragma unroll
      for (int reg = 0; reg < 4; ++reg) {
        int nd = drow + reg;
        int c0 = (w*2 + 0)*16 + dc;
        int c1 = (w*2 + 1)*16 + dc;
        r1F[nd*132 + c0] = hlastF[nd][c0] + pacc0[reg];
        r1F[nd*132 + c1] = hlastF[nd][c1] + pacc1[reg];
      }
    }
  }
  __syncthreads();

  // --- phase 7: LN1 -> h1s fp32 + h1B bf16 ---
  {
    int nd = tid >> 5, l32 = tid & 31;
    float v[4], s = 0.f, q = 0.f;
    #pragma unroll
    for (int k = 0; k < 4; ++k) {
      v[k] = r1F[nd*132 + l32 + k*32];
      s += v[k]; q += v[k]*v[k];
    }
    #pragma unroll
    for (int off = 16; off > 0; off >>= 1) { s += __shfl_xor(s, off); q += __shfl_xor(q, off); }
    float mu = s*(1.f/128.f), var = q*(1.f/128.f) - mu*mu, rs = rsqrtf(var + 1e-5f);
    #pragma unroll
    for (int k = 0; k < 4; ++k) {
      int c = l32 + k*32;
      float hv = (v[k] - mu)*rs*l1gf[c] + l1bf[c];
      h1s[nd*132 + c] = hv;
      h1B[nd*136 + c] = f2b(hv);
    }
  }
  __syncthreads();

  // --- phase 8: FFN1 via MFMA (K=128, N=256), relu+bias fused -> f1B bf16 ---
  {
    bs8 af[4];
    #pragma unroll
    for (int kk = 0; kk < 4; ++kk)
      af[kk] = *(const bs8*)&h1B[arow*136 + kk*32 + akg*8];
    const bs8* bp = (const bs8*)W1F;
    #pragma unroll
    for (int n4 = 0; n4 < 4; ++n4) {
      int nt = w*4 + n4;
      const bs8* bq = bp + nt*256 + lane;
      fvec4 a4 = {0.f, 0.f, 0.f, 0.f};
      #pragma unroll
      for (int kk = 0; kk < 4; ++kk)
        a4 = mfma16(af[kk], bq[kk*64], a4);
      if (lane < 32) {
        int drow = akg*4, dc = arow;
        int n = nt*16 + dc;
        float bias = fb1f[n];
        #pragma unroll
        for (int reg = 0; reg < 4; ++reg)
          f1B[(drow + reg)*264 + n] = f2b(fmaxf(a4[reg] + bias, 0.f));
      }
    }
  }
  __syncthreads();

  // --- phase 9: FFN2 via MFMA (K=256, N=128) + residual -> r2F (over h1B) ---
  {
    const bs8* bp = (const bs8*)W2F;
    #pragma unroll
    for (int n2 = 0; n2 < 2; ++n2) {
      int nt = w*2 + n2;
      const bs8* bq = bp + nt*512 + lane;
      fvec4 a4 = {0.f, 0.f, 0.f, 0.f};
      #pragma unroll
      for (int kk = 0; kk < 8; ++kk) {
        bs8 af = *(const bs8*)&f1B[arow*264 + kk*32 + akg*8];
        a4 = mfma16(af, bq[kk*64], a4);
      }
      if (lane < 32) {
        int drow = akg*4, dc = arow;
        int c = nt*16 + dc;
        float fb2v = fb2f[c];
        #pragma unroll
        for (int reg = 0; reg < 4; ++reg) {
          int nd = drow + reg;
          r2F[nd*132 + c] = h1s[nd*132 + c] + fb2v + a4[reg];
        }
      }
    }
  }
  __syncthreads();

  // --- phase 10: LN2 -> hlastB bf16 (A-frags for GAT1 projection) ---
  {
    int nd = tid >> 5, l32 = tid & 31;
    float v[4], s = 0.f, q = 0.f;
    #pragma unroll
    for (int k = 0; k < 4; ++k) {
      v[k] = r2F[nd*132 + l32 + k*32];
      s += v[k]; q += v[k]*v[k];
    }
    #pragma unroll
    for (int off = 16; off > 0; off >>= 1) { s += __shfl_xor(s, off); q += __shfl_xor(q, off); }
    float mu = s*(1.f/128.f), var = q*(1.f/128.f) - mu*mu, rs = rsqrtf(var + 1e-5f);
    #pragma unroll
    for (int k = 0; k < 4; ++k) {
      int c = l32 + k*32;
      hlastB[nd*136 + c] = f2b((v[k] - mu)*rs*l2gf[c] + l2bf[c]);
    }
  }
  __syncthreads();

  // --- phase 11: xl1 = hlast @ gW1 via MFMA; s1/d1 reduce; globals out ---
  {
    bs8 af[4];
    #pragma unroll
    for (int kk = 0; kk < 4; ++kk)
      af[kk] = *(const bs8*)&hlastB[arow*136 + kk*32 + akg*8];
    const bs8* bp = (const bs8*)gW1F;
    #pragma unroll
    for (int n2 = 0; n2 < 2; ++n2) {
      int nt = w*2 + n2;
      const bs8* bq = bp + nt*256 + lane;
      fvec4 a4 = {0.f, 0.f, 0.f, 0.f};
      #pragma unroll
      for (int kk = 0; kk < 4; ++kk)
        a4 = mfma16(af[kk], bq[kk*64], a4);
      if (lane < 32) {
        int drow = akg*4, dc = arow;
        int c = nt*16 + dc;
        #pragma unroll
        for (int reg = 0; reg < 4; ++reg)
          xlF[(drow + reg)*128 + c] = a4[reg];
      }
    }
  }
  __syncthreads();
  {
    // xl1 write as packed bf16 (ushort4 = 8B/lane, coalesced)
    fvec4 vv = ((const fvec4*)xlF)[tid];
    usvec4 sv;
    #pragma unroll
    for (int k = 0; k < 4; ++k) sv[k] = f2b(vv[k]);
    *(usvec4*)&xl1B[(size_t)m0*HD + tid*4] = sv;
    // s1/d1 from fp32 xlF (scores stay full precision)
    int nd = tid >> 5, l32 = tid & 31;
    float pa[4], pb[4];
    #pragma unroll
    for (int k = 0; k < 4; ++k) {
      float xv = xlF[nd*128 + l32 + k*32];
      pa[k] = xv * asrc[l32 + k*32];
      pb[k] = xv * adrc[l32 + k*32];
    }
    #pragma unroll
    for (int off = 16; off > 0; off >>= 1) {
      #pragma unroll
      for (int k = 0; k < 4; ++k) {
        pa[k] += __shfl_xor(pa[k], off);
        pb[k] += __shfl_xor(pb[k], off);
      }
    }
    if (l32 == 0) {
      int m = m0 + nd;
      #pragma unroll
      for (int k = 0; k < 4; ++k) {
        s1[m*NH + k] = pa[k];
        d1[m*NH + k] = pb[k];
      }
    }
  }
}

// ---------------- CSR build (batch-shared) ----------------------------------
__global__ __launch_bounds__(256) void k_zero(int* __restrict__ cnt)
{
  int i = blockIdx.x * 256 + threadIdx.x;
  if (i < NN) cnt[i] = 0;
}

__global__ __launch_bounds__(256) void k_hist(const int* __restrict__ e1,
                                              int* __restrict__ cnt)
{
  int i = blockIdx.x * 256 + threadIdx.x;
  if (i < EE) atomicAdd(&cnt[e1[i]], 1);
}

__global__ __launch_bounds__(1024) void k_scan(const int* __restrict__ cnt,
                                               int* __restrict__ row_ptr,
                                               int* __restrict__ cur)
{
  __shared__ int sm[1024];
  int tid = threadIdx.x;
  int base = tid * 10;
  int loc[10];
  int s = 0;
  #pragma unroll
  for (int k = 0; k < 10; ++k) {
    int idx = base + k;
    int v = (idx < NN) ? cnt[idx] : 0;
    loc[k] = s;
    s += v;
  }
  sm[tid] = s;
  __syncthreads();
  for (int off = 1; off < 1024; off <<= 1) {
    int t = (tid >= off) ? sm[tid - off] : 0;
    __syncthreads();
    sm[tid] += t;
    __syncthreads();
  }
  int segbase = sm[tid] - s;
  #pragma unroll
  for (int k = 0; k < 10; ++k) {
    int idx = base + k;
    if (idx < NN) { int o = segbase + loc[k]; row_ptr[idx] = o; cur[idx] = o; }
  }
  if (tid == 1023) row_ptr[NN] = sm[1023];
}

__global__ __launch_bounds__(256) void k_scatter(const int* __restrict__ e0,
                                                 const int* __restrict__ e1,
                                                 int* __restrict__ cur,
                                                 int* __restrict__ ssrc)
{
  int i = blockIdx.x * 256 + threadIdx.x;
  if (i >= EE) return;
  int pos = atomicAdd(&cur[e1[i]], 1);
  ssrc[pos] = e0[i];
}

// ---------------- GAT1 gather + GAT2 pre (fused; 1 node/wave) ---------------
// 64 threads; each owns channels 2j, 2j+1 (uint load of bf16 pair; 256B/wave
// per edge, coalesced). Attention scores s1/d1 remain fp32.
__global__ __launch_bounds__(64) void k_g1(
    const int* __restrict__ row_ptr, const int* __restrict__ ssrc,
    const unsigned short* __restrict__ xlB,
    const float* __restrict__ s1, const float* __restrict__ d1,
    const float* __restrict__ gb1, const float* __restrict__ gW2,
    const float* __restrict__ asr2, const float* __restrict__ adr2,
    unsigned short* __restrict__ xl2B, float* __restrict__ s2, float* __restrict__ d2)
{
  __shared__ float g1s[HD];
  int j = threadIdx.x, m = blockIdx.x, h = j >> 4;   // ch 2j -> head (2j)>>5 = j>>4
  int b = m / NN, n = m - b * NN, boff = b * NN;
  float dh = d1[m*NH + h];
  int r0 = row_ptr[n], r1 = row_ptr[n+1];
  float acc0 = 0.f, acc1 = 0.f, dsum = 0.f;
  for (int e = r0; e < r1; ++e) {
    int src = ssrc[e] + boff;
    float ev = expf(lrelu(s1[src*NH + h] + dh));
    unsigned int u = *(const unsigned int*)&xlB[(size_t)src*HD + 2*j];
    float lo, hi; up2(u, lo, hi);
    acc0 += ev * lo; acc1 += ev * hi;
    dsum += ev;
  }
  {
    float es = expf(lrelu(s1[m*NH + h] + dh));       // self loop
    unsigned int u = *(const unsigned int*)&xlB[(size_t)m*HD + 2*j];
    float lo, hi; up2(u, lo, hi);
    acc0 += es * lo; acc1 += es * hi;
    dsum += es;
  }
  float inv = 1.f / (dsum + 1e-16f);
  float v0 = acc0 * inv + gb1[2*j];
  float v1 = acc1 * inv + gb1[2*j + 1];
  g1s[2*j]     = v0 > 0.f ? v0 : expm1f(v0);         // ELU
  g1s[2*j + 1] = v1 > 0.f ? v1 : expm1f(v1);
  __syncthreads();
  // GAT2 pre: xl2 = g1 @ gW2 (all 64 lanes), scores fp32 pre-rounding
  float a = 0.f;
  for (int i = 0; i < HD; ++i) a += g1s[i] * gW2[i*GO + j];
  xl2B[(size_t)m*GO + j] = f2b(a);
  float pa = a * asr2[j], pb = a * adr2[j];
  #pragma unroll
  for (int off = 32; off > 0; off >>= 1) { pa += __shfl_xor(pa, off); pb += __shfl_xor(pb, off); }
  if (j == 0) { s2[m] = pa; d2[m] = pb; }
}

// ---------------- GAT2 gather + output projection ---------------------------
__global__ __launch_bounds__(64) void k_g2(
    const int* __restrict__ row_ptr, const int* __restrict__ ssrc,
    const unsigned short* __restrict__ xl2B,
    const float* __restrict__ s2, const float* __restrict__ d2,
    const float* __restrict__ gb2, const float* __restrict__ oW, const float* __restrict__ ob,
    float* __restrict__ y)
{
  __shared__ float g2s[GO];
  int j = threadIdx.x, m = blockIdx.x;
  int b = m / NN, n = m - b * NN, boff = b * NN;
  float d2m = d2[m];
  int r0 = row_ptr[n], r1 = row_ptr[n+1];
  float acc = 0.f, dsum = 0.f;
  for (int e = r0; e < r1; ++e) {
    int src = ssrc[e] + boff;
    float ev = expf(lrelu(s2[src] + d2m));
    acc  += ev * b2f(xl2B[(size_t)src*GO + j]);
    dsum += ev;
  }
  float es = expf(lrelu(s2[m] + d2m));
  acc  += es * b2f(xl2B[(size_t)m*GO + j]);
  dsum += es;
  g2s[j] = acc / (dsum + 1e-16f) + gb2[j];
  __syncthreads();
  if (j < HR) {
    float a = ob[j];
    #pragma unroll
    for (int o2 = 0; o2 < GO; ++o2) a += g2s[o2] * oW[o2*HR + j];
    y[((size_t)b*HR + j)*NN + n] = a;
  }
}

// ---------------- launch ----------------------------------------------------
extern "C" void kernel_launch(void* const* d_in, const int* in_sizes, int n_in,
                              void* d_out, int out_size, void* d_ws, size_t ws_size,
                              hipStream_t stream)
{
  const int* ei = (const int*)d_in[2];
  const int* e0 = ei;
  const int* e1 = ei + EE;

  float* ws = (float*)d_ws;
  unsigned short* xl1B = (unsigned short*)ws;             // 40000*128 bf16
  unsigned short* xl2B = (unsigned short*)(ws + 2560000); // 40000*64 bf16
  float* ovl = ws + 3840000;          // overlap region (weights, then CSR)
  float* s1  = ws + 4200000;          // 40000*4
  float* d1  = ws + 4360000;          // 40000*4
  float* s2  = ws + 4520000;          // 40000
  float* d2  = ws + 4560000;          // 40000

  // Weight buffers live [prep, xform] in the overlap region.
  unsigned short* Mu    = (unsigned short*)ovl;          // 65536 bf16 frags
  unsigned short* Pw    = Mu + 65536;                    // 65536
  unsigned short* W1F   = Mu + 131072;                   // 32768
  unsigned short* W2F   = Mu + 163840;                   // 32768
  unsigned short* encWF = Mu + 196608;                   // 4096
  unsigned short* gW1F  = Mu + 200704;                   // 16384
  float* encBf = (float*)(Mu + 217088);
  float* fb1f  = encBf + 128;
  float* fb2f  = fb1f + 256;
  float* l1gf  = fb2f + 128;
  float* l1bf  = l1gf + 128;
  float* l2gf  = l1bf + 128;
  float* l2bf  = l2gf + 128;

  // CSR arrays live [hist, end] in the SAME overlap region (stream-serial).
  int* cnt     = (int*)ovl;           // 10000
  int* row_ptr = cnt + 16384;         // 10001
  int* cur     = cnt + 32768;         // 10000
  int* ssrc    = cnt + 49152;         // 160000

  k_prep<<<852, 256, 0, stream>>>(
      (const float*)d_in[5], (const float*)d_in[6], (const float*)d_in[7], (const float*)d_in[8],
      (const float*)d_in[3], (const float*)d_in[4], (const float*)d_in[11], (const float*)d_in[12],
      (const float*)d_in[13], (const float*)d_in[14], (const float*)d_in[9], (const float*)d_in[10],
      (const float*)d_in[15], (const float*)d_in[16], (const float*)d_in[17],
      Mu, Pw, W1F, W2F, encWF, gW1F,
      encBf, fb1f, fb2f, l1gf, l1bf, l2gf, l2bf);

  k_xform<<<MM/8, 256, 0, stream>>>(
      (const float*)d_in[0], (const float*)d_in[1],
      Mu, Pw, W1F, W2F, encWF, gW1F,
      encBf, fb1f, fb2f, l1gf, l1bf, l2gf, l2bf,
      (const float*)d_in[18], (const float*)d_in[19],
      xl1B, s1, d1);

  // CSR build (after xform: overlap region is free now)
  k_zero<<<(NN + 255)/256, 256, 0, stream>>>(cnt);
  k_hist<<<(EE + 255)/256, 256, 0, stream>>>(e1, cnt);
  k_scan<<<1, 1024, 0, stream>>>(cnt, row_ptr, cur);
  k_scatter<<<(EE + 255)/256, 256, 0, stream>>>(e0, e1, cur, ssrc);

  k_g1<<<MM, 64, 0, stream>>>(row_ptr, ssrc, xl1B, s1, d1,
      (const float*)d_in[20], (const float*)d_in[21],
      (const float*)d_in[22], (const float*)d_in[23],
      xl2B, s2, d2);

  k_g2<<<MM, 64, 0, stream>>>(row_ptr, ssrc, xl2B, s2, d2,
      (const float*)d_in[24], (const float*)d_in[25], (const float*)d_in[26],
      (float*)d_out);
}

// Round 11
// 280.651 us; speedup vs baseline: 6.6116x; 1.0446x over previous
//
#include <hip/hip_runtime.h>
#include <hip/hip_bf16.h>

#define DEV static __device__ __forceinline__

constexpr int BB = 4;        // batches
constexpr int TT = 12;       // timesteps
constexpr int NN = 10000;    // nodes per batch
constexpr int FD = 16;       // input features (8+8)
constexpr int HD = 128;      // hidden
constexpr int NH = 4;        // attn heads
constexpr int DH = 32;       // head dim
constexpr int FF = 256;      // ffn hidden
constexpr int GO = 64;       // gat2 out
constexpr int HR = 24;       // horizon
constexpr int EE = 160000;   // edges per batch
constexpr int MM = BB * NN;  // total nodes

typedef unsigned short bvec8 __attribute__((ext_vector_type(8)));
typedef unsigned short usvec4 __attribute__((ext_vector_type(4)));
typedef float fvec4 __attribute__((ext_vector_type(4)));
typedef short bs8 __attribute__((ext_vector_type(8)));      // MFMA bf16 frag (4 VGPR)

DEV float lrelu(float x) { return x >= 0.f ? x : 0.2f * x; }

DEV float b2f(unsigned short u) {
  union { unsigned int i; float f; } x; x.i = ((unsigned int)u) << 16; return x.f;
}
DEV unsigned short f2b(float f) {
  union { float f; unsigned int i; } x; x.f = f;
  unsigned int r = x.i + 0x7FFFu + ((x.i >> 16) & 1u);
  return (unsigned short)(r >> 16);
}
DEV void up2(unsigned int u, float& lo, float& hi) {
  union { unsigned int i; float f; } a, b;
  a.i = u << 16; b.i = u & 0xFFFF0000u;
  lo = a.f; hi = b.f;
}

DEV fvec4 mfma16(bs8 a, bs8 b, fvec4 c) {
  return __builtin_amdgcn_mfma_f32_16x16x32_bf16(a, b, c, 0, 0, 0);
}

// ---------------- prep: fold + re-layout ALL transformer weights (fp32 in) --
// MFMA B-fragment order: frag idx = ((nt*nK + kk)*64 + lane), element e:
//   B[k][n] with k = kk*32 + (lane>>4)*8 + e, n = nt*16 + (lane&15).
__global__ __launch_bounds__(256) void k_prep(
    const float* __restrict__ Wq, const float* __restrict__ Wk,
    const float* __restrict__ Wv, const float* __restrict__ Wo,
    const float* __restrict__ encW, const float* __restrict__ encB,
    const float* __restrict__ W1, const float* __restrict__ fb1,
    const float* __restrict__ W2, const float* __restrict__ fb2,
    const float* __restrict__ l1g, const float* __restrict__ l1b,
    const float* __restrict__ l2g, const float* __restrict__ l2b,
    const float* __restrict__ gW1,
    unsigned short* __restrict__ Mu, unsigned short* __restrict__ Pw,
    unsigned short* __restrict__ W1F, unsigned short* __restrict__ W2F,
    unsigned short* __restrict__ encWF, unsigned short* __restrict__ gW1F,
    float* __restrict__ encBf, float* __restrict__ fb1f, float* __restrict__ fb2f,
    float* __restrict__ l1gf, float* __restrict__ l1bf,
    float* __restrict__ l2gf, float* __restrict__ l2bf)
{
  int idx = blockIdx.x * 256 + threadIdx.x;      // 852*256 = 218112 exactly
  if (idx < 65536) {
    int e = idx & 7, lane = (idx >> 3) & 63, kk = (idx >> 9) & 3, nt = idx >> 11;
    int i = kk*32 + (lane >> 4)*8 + e;
    int q = nt*16 + (lane & 15);
    int h = q >> 7, c = q & 127;
    float a = 0.f;
    #pragma unroll 8
    for (int d = 0; d < DH; ++d)
      a += Wq[i*HD + h*DH + d] * Wk[c*HD + h*DH + d];
    Mu[idx] = f2b(a);
  } else if (idx < 131072) {
    int g2 = idx - 65536;
    int e = g2 & 7, lane = (g2 >> 3) & 63, kk = (g2 >> 9) & 15, nt = g2 >> 13;
    int q = kk*32 + (lane >> 4)*8 + e;
    int j = nt*16 + (lane & 15);
    int h = q >> 7, i = q & 127;
    float a = 0.f;
    #pragma unroll 8
    for (int d = 0; d < DH; ++d)
      a += Wv[i*HD + h*DH + d] * Wo[(h*DH + d)*HD + j];
    Pw[g2] = f2b(a);
  } else if (idx < 163840) {
    int g = idx - 131072;
    int e = g & 7, lane = (g >> 3) & 63, kk = (g >> 9) & 3, nt = g >> 11;
    int k = kk*32 + (lane >> 4)*8 + e;
    int n = nt*16 + (lane & 15);
    W1F[g] = f2b(W1[k*FF + n]);
  } else if (idx < 196608) {
    int g = idx - 163840;
    int e = g & 7, lane = (g >> 3) & 63, kk = (g >> 9) & 7, nt = g >> 12;
    int k = kk*32 + (lane >> 4)*8 + e;
    int n = nt*16 + (lane & 15);
    W2F[g] = f2b(W2[k*HD + n]);
  } else if (idx < 200704) {
    int g = idx - 196608;
    int e = g & 7, lane = (g >> 3) & 63, nt = g >> 9;
    int k = (lane >> 4)*8 + e;
    int n = nt*16 + (lane & 15);
    encWF[g] = (k < FD) ? f2b(encW[k*HD + n]) : (unsigned short)0;
  } else if (idx < 217088) {
    int g = idx - 200704;
    int e = g & 7, lane = (g >> 3) & 63, kk = (g >> 9) & 3, nt = g >> 11;
    int k = kk*32 + (lane >> 4)*8 + e;
    int n = nt*16 + (lane & 15);
    gW1F[g] = f2b(gW1[k*HD + n]);
  } else if (idx < 217216) { int t = idx - 217088; encBf[t] = encB[t]; }
  else if (idx < 217472)   { int t = idx - 217216; fb1f[t] = fb1[t]; }
  else if (idx < 217600)   { int t = idx - 217472; fb2f[t] = fb2[t]; }
  else if (idx < 217728)   { int t = idx - 217600; l1gf[t] = l1g[t]; }
  else if (idx < 217856)   { int t = idx - 217728; l1bf[t] = l1b[t]; }
  else if (idx < 217984)   { int t = idx - 217856; l2gf[t] = l2g[t]; }
  else                     { int t = idx - 217984; l2bf[t] = l2b[t]; }
}

// ---------------- fused transformer + GAT1-pre (8 nodes/block) --------------
// LDS diet: 38528 B -> 4 blocks/CU. MFMA A-operand rows 8-15 feed only
// DISCARDED D rows, so A-frag reads alias arow&7 onto the 8 real rows
// (no junk rows stored). All A-frag row strides are 16 B multiples.
__global__ __launch_bounds__(256) void k_xform(
    const float* __restrict__ xh, const float* __restrict__ xc,
    const unsigned short* __restrict__ MuF, const unsigned short* __restrict__ PwF,
    const unsigned short* __restrict__ W1F, const unsigned short* __restrict__ W2F,
    const unsigned short* __restrict__ encWF, const unsigned short* __restrict__ gW1F,
    const float* __restrict__ encBf,
    const float* __restrict__ fb1f, const float* __restrict__ fb2f,
    const float* __restrict__ l1gf, const float* __restrict__ l1bf,
    const float* __restrict__ l2gf, const float* __restrict__ l2bf,
    const float* __restrict__ asrc, const float* __restrict__ adrc,
    unsigned short* __restrict__ xl1B, float* __restrict__ s1, float* __restrict__ d1)
{
  // big: hsB (ph1-5) then {r1F,h1s,h1B,f1B,r2F} (ph6-10)
  __shared__ __align__(16) char big[26112];
  __shared__ unsigned short hlastB[8*136];     // bf16 h_last (A-frags + residual)
  __shared__ float lgaw[8][NH][TT];
  __shared__ __align__(16) char regB[8704];    // xB -> usB -> wB -> xlF

  unsigned short* hsB = (unsigned short*)big;          // [(nl*12+t)][136]
  float* r1F = (float*)big;                            // [8][132] ph6-7
  float* h1s = (float*)(big + 4224);                   // [8][132] ph7-9
  unsigned short* h1B = (unsigned short*)(big + 8448); // [8][136] ph7-8
  float* r2F = (float*)(big + 8448);                   // [8][132] ph9-10 (over h1B)
  unsigned short* f1B = (unsigned short*)(big + 12672);// [8][264] ph8-9

  unsigned short* xB  = (unsigned short*)regB;         // [96][40]  ph0-1
  unsigned short* usB = (unsigned short*)regB;         // [8*4][136] ph2-3 (bf16 u)
  unsigned short* wB  = (unsigned short*)regB;         // [8][520]  ph5-6
  float* xlF = (float*)regB;                           // [8][128]  ph11

  const int tid  = threadIdx.x;
  const int w    = tid >> 6;
  const int lane = tid & 63;
  const int m0   = blockIdx.x * 8;
  const int arow = lane & 15, akg = lane >> 4;
  const int ar8  = arow & 7;                   // aliased A-row (rows 8-15 -> 0-7)

  // --- phase 0: load x -> xB bf16, rows = t*8+nl, K zero-padded 16..31 ---
  #pragma unroll
  for (int k = 0; k < 6; ++k) {
    int idx = tid + k*256;
    int f = idx & 15, rest = idx >> 4;
    int nl = rest & 7, t = rest >> 3;
    int m = m0 + nl, b = m / NN, n = m - b*NN;
    float v = (f < 8) ? xh[(((size_t)b*TT + t)*NN + n)*8 + f]
                      : xc[(((size_t)b*TT + t)*NN + n)*8 + (f - 8)];
    xB[(t*8 + nl)*40 + f] = f2b(v);
  }
  #pragma unroll
  for (int k = 0; k < 6; ++k) {
    int idx = tid + k*256;
    xB[(idx >> 4)*40 + 16 + (idx & 15)] = 0;
  }
  __syncthreads();

  // --- phase 1: encoder via MFMA (96x128 = 6 mt x 8 nt tiles) ---
  {
    const bs8* ef = (const bs8*)encWF;
    bs8 b0 = ef[(2*w + 0)*64 + lane];
    bs8 b1 = ef[(2*w + 1)*64 + lane];
    int drow = akg*4, dc = arow;
    int j0 = (2*w + 0)*16 + dc, j1 = (2*w + 1)*16 + dc;
    float eb0 = encBf[j0], eb1 = encBf[j1];
    fvec4 z4 = {0.f, 0.f, 0.f, 0.f};
    #pragma unroll
    for (int mt = 0; mt < 6; ++mt) {
      bs8 af = *(const bs8*)&xB[(mt*16 + arow)*40 + akg*8];
      fvec4 d0 = mfma16(af, b0, z4);
      fvec4 d1 = mfma16(af, b1, z4);
      #pragma unroll
      for (int reg = 0; reg < 4; ++reg) {
        int gr = mt*16 + drow + reg;
        int t = gr >> 3, nl = gr & 7;
        float v0 = d0[reg] + eb0, v1 = d1[reg] + eb1;
        unsigned short s0 = f2b(v0), s1v = f2b(v1);
        hsB[(nl*12 + t)*136 + j0] = s0;
        hsB[(nl*12 + t)*136 + j1] = s1v;
        if (t == TT-1) {
          hlastB[nl*136 + j0] = s0;
          hlastB[nl*136 + j1] = s1v;
        }
      }
    }
  }
  __syncthreads();                // xB dead

  // --- phase 2: u = h_last @ Mu via MFMA -> usB bf16 ---
  {
    bs8 af[4];
    #pragma unroll
    for (int kk = 0; kk < 4; ++kk)
      af[kk] = *(const bs8*)&hlastB[ar8*136 + kk*32 + akg*8];
    const bs8* bp = (const bs8*)MuF;
    fvec4 acc[8];
    #pragma unroll
    for (int n8 = 0; n8 < 8; ++n8) {
      int nt = w*8 + n8;
      const bs8* bq = bp + nt*256 + lane;
      fvec4 a4 = {0.f, 0.f, 0.f, 0.f};
      #pragma unroll
      for (int kk = 0; kk < 4; ++kk)
        a4 = mfma16(af[kk], bq[kk*64], a4);
      acc[n8] = a4;
    }
    __syncthreads();              // xB fully read before usB overlay write
    if (lane < 32) {
      int drow = akg*4, dc = arow;
      #pragma unroll
      for (int n8 = 0; n8 < 8; ++n8) {
        int col = (w*8 + n8)*16 + dc, hd = col >> 7, c = col & 127;
        #pragma unroll
        for (int reg = 0; reg < 4; ++reg)
          usB[((drow + reg)*4 + hd)*136 + c] = f2b(acc[n8][reg]);
      }
    }
  }
  __syncthreads();

  // --- phase 3: logits (8n x 4h x 12t = 384 dots of K=128) ---
  #pragma unroll
  for (int pass = 0; pass < 2; ++pass) {
    int item = pass*256 + tid;
    if (item < 384) {
      int nl = item / 48, p = item - nl*48, hd = p / 12, t = p - hd*12;
      const unsigned short* up = &usB[(nl*4 + hd)*136];
      float a = 0.f;
      for (int i8 = 0; i8 < 16; ++i8) {
        bvec8 hb8 = *(const bvec8*)&hsB[(nl*12 + t)*136 + i8*8];
        bvec8 ub8 = *(const bvec8*)&up[i8*8];
        a += b2f(hb8[0])*b2f(ub8[0]) + b2f(hb8[1])*b2f(ub8[1])
           + b2f(hb8[2])*b2f(ub8[2]) + b2f(hb8[3])*b2f(ub8[3])
           + b2f(hb8[4])*b2f(ub8[4]) + b2f(hb8[5])*b2f(ub8[5])
           + b2f(hb8[6])*b2f(ub8[6]) + b2f(hb8[7])*b2f(ub8[7]);
      }
      lgaw[nl][hd][t] = a * 0.17677669529663687f;
    }
  }
  __syncthreads();

  // --- phase 4: softmax over t ---
  if (tid < 32) {
    int nl = tid >> 2, hd = tid & 3;
    float mx = -1e30f;
    #pragma unroll
    for (int t = 0; t < TT; ++t) mx = fmaxf(mx, lgaw[nl][hd][t]);
    float ex[TT], sm = 0.f;
    #pragma unroll
    for (int t = 0; t < TT; ++t) { ex[t] = expf(lgaw[nl][hd][t] - mx); sm += ex[t]; }
    float inv = 1.f / sm;
    #pragma unroll
    for (int t = 0; t < TT; ++t) lgaw[nl][hd][t] = ex[t] * inv;
  }
  __syncthreads();

  // --- phase 5: w_h = sum_t alpha*h_t -> wB bf16 (over usB) ---
  {
    int g = tid >> 7, j = tid & 127;
    #pragma unroll
    for (int r = 0; r < 4; ++r) {
      int nl = g*4 + r;
      float wacc[NH] = {0.f, 0.f, 0.f, 0.f};
      #pragma unroll
      for (int t = 0; t < TT; ++t) {
        float hv = b2f(hsB[(nl*12 + t)*136 + j]);
        #pragma unroll
        for (int hd = 0; hd < NH; ++hd) wacc[hd] += lgaw[nl][hd][t] * hv;
      }
      #pragma unroll
      for (int hd = 0; hd < NH; ++hd) wB[nl*520 + hd*128 + j] = f2b(wacc[hd]);
    }
  }
  __syncthreads();                // hsB dead after this point

  // --- phase 6: oa = w @ Pw via MFMA; r1 = h_last + oa -> r1F (over hsB) ---
  {
    fvec4 pacc0 = {0.f,0.f,0.f,0.f}, pacc1 = {0.f,0.f,0.f,0.f};
    const bs8* bp = (const bs8*)PwF;
    const bs8* bq0 = bp + (w*2 + 0)*1024 + lane;
    const bs8* bq1 = bp + (w*2 + 1)*1024 + lane;
    #pragma unroll
    for (int kk = 0; kk < 16; ++kk) {
      bs8 af = *(const bs8*)&wB[ar8*520 + kk*32 + akg*8];
      pacc0 = mfma16(af, bq0[kk*64], pacc0);
      pacc1 = mfma16(af, bq1[kk*64], pacc1);
    }
    __syncthreads();              // wB fully read before r1F overlay write
    if (lane < 32) {
      int drow = akg*4, dc = arow;
      #pragma unroll
      for (int reg = 0; reg < 4; ++reg) {
        int nd = drow + reg;
        int c0 = (w*2 + 0)*16 + dc;
        int c1 = (w*2 + 1)*16 + dc;
        r1F[nd*132 + c0] = b2f(hlastB[nd*136 + c0]) + pacc0[reg];
        r1F[nd*132 + c1] = b2f(hlastB[nd*136 + c1]) + pacc1[reg];
      }
    }
  }
  __syncthreads();

  // --- phase 7: LN1 -> h1s fp32 + h1B bf16 ---
  {
    int nd = tid >> 5, l32 = tid & 31;
    float v[4], s = 0.f, q = 0.f;
    #pragma unroll
    for (int k = 0; k < 4; ++k) {
      v[k] = r1F[nd*132 + l32 + k*32];
      s += v[k]; q += v[k]*v[k];
    }
    #pragma unroll
    for (int off = 16; off > 0; off >>= 1) { s += __shfl_xor(s, off); q += __shfl_xor(q, off); }
    float mu = s*(1.f/128.f), var = q*(1.f/128.f) - mu*mu, rs = rsqrtf(var + 1e-5f);
    #pragma unroll
    for (int k = 0; k < 4; ++k) {
      int c = l32 + k*32;
      float hv = (v[k] - mu)*rs*l1gf[c] + l1bf[c];
      h1s[nd*132 + c] = hv;
      h1B[nd*136 + c] = f2b(hv);
    }
  }
  __syncthreads();

  // --- phase 8: FFN1 via MFMA (K=128, N=256), relu+bias fused -> f1B bf16 ---
  {
    bs8 af[4];
    #pragma unroll
    for (int kk = 0; kk < 4; ++kk)
      af[kk] = *(const bs8*)&h1B[ar8*136 + kk*32 + akg*8];
    const bs8* bp = (const bs8*)W1F;
    #pragma unroll
    for (int n4 = 0; n4 < 4; ++n4) {
      int nt = w*4 + n4;
      const bs8* bq = bp + nt*256 + lane;
      fvec4 a4 = {0.f, 0.f, 0.f, 0.f};
      #pragma unroll
      for (int kk = 0; kk < 4; ++kk)
        a4 = mfma16(af[kk], bq[kk*64], a4);
      if (lane < 32) {
        int drow = akg*4, dc = arow;
        int n = nt*16 + dc;
        float bias = fb1f[n];
        #pragma unroll
        for (int reg = 0; reg < 4; ++reg)
          f1B[(drow + reg)*264 + n] = f2b(fmaxf(a4[reg] + bias, 0.f));
      }
    }
  }
  __syncthreads();

  // --- phase 9: FFN2 via MFMA (K=256, N=128) + residual -> r2F (over h1B) ---
  {
    const bs8* bp = (const bs8*)W2F;
    #pragma unroll
    for (int n2 = 0; n2 < 2; ++n2) {
      int nt = w*2 + n2;
      const bs8* bq = bp + nt*512 + lane;
      fvec4 a4 = {0.f, 0.f, 0.f, 0.f};
      #pragma unroll
      for (int kk = 0; kk < 8; ++kk) {
        bs8 af = *(const bs8*)&f1B[ar8*264 + kk*32 + akg*8];
        a4 = mfma16(af, bq[kk*64], a4);
      }
      if (lane < 32) {
        int drow = akg*4, dc = arow;
        int c = nt*16 + dc;
        float fb2v = fb2f[c];
        #pragma unroll
        for (int reg = 0; reg < 4; ++reg) {
          int nd = drow + reg;
          r2F[nd*132 + c] = h1s[nd*132 + c] + fb2v + a4[reg];
        }
      }
    }
  }
  __syncthreads();

  // --- phase 10: LN2 -> hlastB bf16 (A-frags for GAT1 projection) ---
  {
    int nd = tid >> 5, l32 = tid & 31;
    float v[4], s = 0.f, q = 0.f;
    #pragma unroll
    for (int k = 0; k < 4; ++k) {
      v[k] = r2F[nd*132 + l32 + k*32];
      s += v[k]; q += v[k]*v[k];
    }
    #pragma unroll
    for (int off = 16; off > 0; off >>= 1) { s += __shfl_xor(s, off); q += __shfl_xor(q, off); }
    float mu = s*(1.f/128.f), var = q*(1.f/128.f) - mu*mu, rs = rsqrtf(var + 1e-5f);
    #pragma unroll
    for (int k = 0; k < 4; ++k) {
      int c = l32 + k*32;
      hlastB[nd*136 + c] = f2b((v[k] - mu)*rs*l2gf[c] + l2bf[c]);
    }
  }
  __syncthreads();

  // --- phase 11: xl1 = hlast @ gW1 via MFMA; s1/d1 reduce; globals out ---
  {
    bs8 af[4];
    #pragma unroll
    for (int kk = 0; kk < 4; ++kk)
      af[kk] = *(const bs8*)&hlastB[ar8*136 + kk*32 + akg*8];
    const bs8* bp = (const bs8*)gW1F;
    #pragma unroll
    for (int n2 = 0; n2 < 2; ++n2) {
      int nt = w*2 + n2;
      const bs8* bq = bp + nt*256 + lane;
      fvec4 a4 = {0.f, 0.f, 0.f, 0.f};
      #pragma unroll
      for (int kk = 0; kk < 4; ++kk)
        a4 = mfma16(af[kk], bq[kk*64], a4);
      if (lane < 32) {
        int drow = akg*4, dc = arow;
        int c = nt*16 + dc;
        #pragma unroll
        for (int reg = 0; reg < 4; ++reg)
          xlF[(drow + reg)*128 + c] = a4[reg];
      }
    }
  }
  __syncthreads();
  {
    // xl1 write as packed bf16 (ushort4 = 8B/lane, coalesced)
    fvec4 vv = ((const fvec4*)xlF)[tid];
    usvec4 sv;
    #pragma unroll
    for (int k = 0; k < 4; ++k) sv[k] = f2b(vv[k]);
    *(usvec4*)&xl1B[(size_t)m0*HD + tid*4] = sv;
    // s1/d1 from fp32 xlF (scores stay full precision)
    int nd = tid >> 5, l32 = tid & 31;
    float pa[4], pb[4];
    #pragma unroll
    for (int k = 0; k < 4; ++k) {
      float xv = xlF[nd*128 + l32 + k*32];
      pa[k] = xv * asrc[l32 + k*32];
      pb[k] = xv * adrc[l32 + k*32];
    }
    #pragma unroll
    for (int off = 16; off > 0; off >>= 1) {
      #pragma unroll
      for (int k = 0; k < 4; ++k) {
        pa[k] += __shfl_xor(pa[k], off);
        pb[k] += __shfl_xor(pb[k], off);
      }
    }
    if (l32 == 0) {
      int m = m0 + nd;
      #pragma unroll
      for (int k = 0; k < 4; ++k) {
        s1[m*NH + k] = pa[k];
        d1[m*NH + k] = pb[k];
      }
    }
  }
}

// ---------------- CSR build (batch-shared) ----------------------------------
__global__ __launch_bounds__(256) void k_zero(int* __restrict__ cnt)
{
  int i = blockIdx.x * 256 + threadIdx.x;
  if (i < NN) cnt[i] = 0;
}

__global__ __launch_bounds__(256) void k_hist(const int* __restrict__ e1,
                                              int* __restrict__ cnt)
{
  int i = blockIdx.x * 256 + threadIdx.x;
  if (i < EE) atomicAdd(&cnt[e1[i]], 1);
}

__global__ __launch_bounds__(1024) void k_scan(const int* __restrict__ cnt,
                                               int* __restrict__ row_ptr,
                                               int* __restrict__ cur)
{
  __shared__ int sm[1024];
  int tid = threadIdx.x;
  int base = tid * 10;
  int loc[10];
  int s = 0;
  #pragma unroll
  for (int k = 0; k < 10; ++k) {
    int idx = base + k;
    int v = (idx < NN) ? cnt[idx] : 0;
    loc[k] = s;
    s += v;
  }
  sm[tid] = s;
  __syncthreads();
  for (int off = 1; off < 1024; off <<= 1) {
    int t = (tid >= off) ? sm[tid - off] : 0;
    __syncthreads();
    sm[tid] += t;
    __syncthreads();
  }
  int segbase = sm[tid] - s;
  #pragma unroll
  for (int k = 0; k < 10; ++k) {
    int idx = base + k;
    if (idx < NN) { int o = segbase + loc[k]; row_ptr[idx] = o; cur[idx] = o; }
  }
  if (tid == 1023) row_ptr[NN] = sm[1023];
}

__global__ __launch_bounds__(256) void k_scatter(const int* __restrict__ e0,
                                                 const int* __restrict__ e1,
                                                 int* __restrict__ cur,
                                                 int* __restrict__ ssrc)
{
  int i = blockIdx.x * 256 + threadIdx.x;
  if (i >= EE) return;
  int pos = atomicAdd(&cur[e1[i]], 1);
  ssrc[pos] = e0[i];
}

// ---------------- GAT1 gather + GAT2 pre (fused; 1 node/wave) ---------------
__global__ __launch_bounds__(64) void k_g1(
    const int* __restrict__ row_ptr, const int* __restrict__ ssrc,
    const unsigned short* __restrict__ xlB,
    const float* __restrict__ s1, const float* __restrict__ d1,
    const float* __restrict__ gb1, const float* __restrict__ gW2,
    const float* __restrict__ asr2, const float* __restrict__ adr2,
    unsigned short* __restrict__ xl2B, float* __restrict__ s2, float* __restrict__ d2)
{
  __shared__ float g1s[HD];
  int j = threadIdx.x, m = blockIdx.x, h = j >> 4;   // ch 2j -> head (2j)>>5 = j>>4
  int b = m / NN, n = m - b * NN, boff = b * NN;
  float dh = d1[m*NH + h];
  int r0 = row_ptr[n], r1 = row_ptr[n+1];
  float acc0 = 0.f, acc1 = 0.f, dsum = 0.f;
  for (int e = r0; e < r1; ++e) {
    int src = ssrc[e] + boff;
    float ev = expf(lrelu(s1[src*NH + h] + dh));
    unsigned int u = *(const unsigned int*)&xlB[(size_t)src*HD + 2*j];
    float lo, hi; up2(u, lo, hi);
    acc0 += ev * lo; acc1 += ev * hi;
    dsum += ev;
  }
  {
    float es = expf(lrelu(s1[m*NH + h] + dh));       // self loop
    unsigned int u = *(const unsigned int*)&xlB[(size_t)m*HD + 2*j];
    float lo, hi; up2(u, lo, hi);
    acc0 += es * lo; acc1 += es * hi;
    dsum += es;
  }
  float inv = 1.f / (dsum + 1e-16f);
  float v0 = acc0 * inv + gb1[2*j];
  float v1 = acc1 * inv + gb1[2*j + 1];
  g1s[2*j]     = v0 > 0.f ? v0 : expm1f(v0);         // ELU
  g1s[2*j + 1] = v1 > 0.f ? v1 : expm1f(v1);
  __syncthreads();
  // GAT2 pre: xl2 = g1 @ gW2 (all 64 lanes), scores fp32 pre-rounding
  float a = 0.f;
  for (int i = 0; i < HD; ++i) a += g1s[i] * gW2[i*GO + j];
  xl2B[(size_t)m*GO + j] = f2b(a);
  float pa = a * asr2[j], pb = a * adr2[j];
  #pragma unroll
  for (int off = 32; off > 0; off >>= 1) { pa += __shfl_xor(pa, off); pb += __shfl_xor(pb, off); }
  if (j == 0) { s2[m] = pa; d2[m] = pb; }
}

// ---------------- GAT2 gather + output projection ---------------------------
__global__ __launch_bounds__(64) void k_g2(
    const int* __restrict__ row_ptr, const int* __restrict__ ssrc,
    const unsigned short* __restrict__ xl2B,
    const float* __restrict__ s2, const float* __restrict__ d2,
    const float* __restrict__ gb2, const float* __restrict__ oW, const float* __restrict__ ob,
    float* __restrict__ y)
{
  __shared__ float g2s[GO];
  int j = threadIdx.x, m = blockIdx.x;
  int b = m / NN, n = m - b * NN, boff = b * NN;
  float d2m = d2[m];
  int r0 = row_ptr[n], r1 = row_ptr[n+1];
  float acc = 0.f, dsum = 0.f;
  for (int e = r0; e < r1; ++e) {
    int src = ssrc[e] + boff;
    float ev = expf(lrelu(s2[src] + d2m));
    acc  += ev * b2f(xl2B[(size_t)src*GO + j]);
    dsum += ev;
  }
  float es = expf(lrelu(s2[m] + d2m));
  acc  += es * b2f(xl2B[(size_t)m*GO + j]);
  dsum += es;
  g2s[j] = acc / (dsum + 1e-16f) + gb2[j];
  __syncthreads();
  if (j < HR) {
    float a = ob[j];
    #pragma unroll
    for (int o2 = 0; o2 < GO; ++o2) a += g2s[o2] * oW[o2*HR + j];
    y[((size_t)b*HR + j)*NN + n] = a;
  }
}

// ---------------- launch ----------------------------------------------------
extern "C" void kernel_launch(void* const* d_in, const int* in_sizes, int n_in,
                              void* d_out, int out_size, void* d_ws, size_t ws_size,
                              hipStream_t stream)
{
  const int* ei = (const int*)d_in[2];
  const int* e0 = ei;
  const int* e1 = ei + EE;

  float* ws = (float*)d_ws;
  unsigned short* xl1B = (unsigned short*)ws;             // 40000*128 bf16
  unsigned short* xl2B = (unsigned short*)(ws + 2560000); // 40000*64 bf16
  float* ovl = ws + 3840000;          // overlap region (weights, then CSR)
  float* s1  = ws + 4200000;          // 40000*4
  float* d1  = ws + 4360000;          // 40000*4
  float* s2  = ws + 4520000;          // 40000
  float* d2  = ws + 4560000;          // 40000

  // Weight buffers live [prep, xform] in the overlap region.
  unsigned short* Mu    = (unsigned short*)ovl;          // 65536 bf16 frags
  unsigned short* Pw    = Mu + 65536;                    // 65536
  unsigned short* W1F   = Mu + 131072;                   // 32768
  unsigned short* W2F   = Mu + 163840;                   // 32768
  unsigned short* encWF = Mu + 196608;                   // 4096
  unsigned short* gW1F  = Mu + 200704;                   // 16384
  float* encBf = (float*)(Mu + 217088);
  float* fb1f  = encBf + 128;
  float* fb2f  = fb1f + 256;
  float* l1gf  = fb2f + 128;
  float* l1bf  = l1gf + 128;
  float* l2gf  = l1bf + 128;
  float* l2bf  = l2gf + 128;

  // CSR arrays live [hist, end] in the SAME overlap region (stream-serial).
  int* cnt     = (int*)ovl;           // 10000
  int* row_ptr = cnt + 16384;         // 10001
  int* cur     = cnt + 32768;         // 10000
  int* ssrc    = cnt + 49152;         // 160000

  k_prep<<<852, 256, 0, stream>>>(
      (const float*)d_in[5], (const float*)d_in[6], (const float*)d_in[7], (const float*)d_in[8],
      (const float*)d_in[3], (const float*)d_in[4], (const float*)d_in[11], (const float*)d_in[12],
      (const float*)d_in[13], (const float*)d_in[14], (const float*)d_in[9], (const float*)d_in[10],
      (const float*)d_in[15], (const float*)d_in[16], (const float*)d_in[17],
      Mu, Pw, W1F, W2F, encWF, gW1F,
      encBf, fb1f, fb2f, l1gf, l1bf, l2gf, l2bf);

  k_xform<<<MM/8, 256, 0, stream>>>(
      (const float*)d_in[0], (const float*)d_in[1],
      Mu, Pw, W1F, W2F, encWF, gW1F,
      encBf, fb1f, fb2f, l1gf, l1bf, l2gf, l2bf,
      (const float*)d_in[18], (const float*)d_in[19],
      xl1B, s1, d1);

  // CSR build (after xform: overlap region is free now)
  k_zero<<<(NN + 255)/256, 256, 0, stream>>>(cnt);
  k_hist<<<(EE + 255)/256, 256, 0, stream>>>(e1, cnt);
  k_scan<<<1, 1024, 0, stream>>>(cnt, row_ptr, cur);
  k_scatter<<<(EE + 255)/256, 256, 0, stream>>>(e0, e1, cur, ssrc);

  k_g1<<<MM, 64, 0, stream>>>(row_ptr, ssrc, xl1B, s1, d1,
      (const float*)d_in[20], (const float*)d_in[21],
      (const float*)d_in[22], (const float*)d_in[23],
      xl2B, s2, d2);

  k_g2<<<MM, 64, 0, stream>>>(row_ptr, ssrc, xl2B, s2, d2,
      (const float*)d_in[24], (const float*)d_in[25], (const float*)d_in[26],
      (float*)d_out);
}

// Round 12
// 276.491 us; speedup vs baseline: 6.7111x; 1.0150x over previous
//
#include <hip/hip_runtime.h>
#include <hip/hip_bf16.h>

#define DEV static __device__ __forceinline__

constexpr int BB = 4;        // batches
constexpr int TT = 12;       // timesteps
constexpr int NN = 10000;    // nodes per batch
constexpr int FD = 16;       // input features (8+8)
constexpr int HD = 128;      // hidden
constexpr int NH = 4;        // attn heads
constexpr int DH = 32;       // head dim
constexpr int FF = 256;      // ffn hidden
constexpr int GO = 64;       // gat2 out
constexpr int HR = 24;       // horizon
constexpr int EE = 160000;   // edges per batch
constexpr int MM = BB * NN;  // total nodes

typedef unsigned short bvec8 __attribute__((ext_vector_type(8)));
typedef unsigned short usvec4 __attribute__((ext_vector_type(4)));
typedef float fvec4 __attribute__((ext_vector_type(4)));
typedef short bs8 __attribute__((ext_vector_type(8)));      // MFMA bf16 frag (4 VGPR)

DEV float lrelu(float x) { return x >= 0.f ? x : 0.2f * x; }

DEV float b2f(unsigned short u) {
  union { unsigned int i; float f; } x; x.i = ((unsigned int)u) << 16; return x.f;
}
DEV unsigned short f2b(float f) {
  union { float f; unsigned int i; } x; x.f = f;
  unsigned int r = x.i + 0x7FFFu + ((x.i >> 16) & 1u);
  return (unsigned short)(r >> 16);
}
DEV void up2(unsigned int u, float& lo, float& hi) {
  union { unsigned int i; float f; } a, b;
  a.i = u << 16; b.i = u & 0xFFFF0000u;
  lo = a.f; hi = b.f;
}

DEV fvec4 mfma16(bs8 a, bs8 b, fvec4 c) {
  return __builtin_amdgcn_mfma_f32_16x16x32_bf16(a, b, c, 0, 0, 0);
}

// ---------------- prep: fold + re-layout ALL transformer weights (fp32 in) --
// MFMA B-fragment order: frag idx = ((nt*nK + kk)*64 + lane), element e:
//   B[k][n] with k = kk*32 + (lane>>4)*8 + e, n = nt*16 + (lane&15).
__global__ __launch_bounds__(256) void k_prep(
    const float* __restrict__ Wq, const float* __restrict__ Wk,
    const float* __restrict__ Wv, const float* __restrict__ Wo,
    const float* __restrict__ encW, const float* __restrict__ encB,
    const float* __restrict__ W1, const float* __restrict__ fb1,
    const float* __restrict__ W2, const float* __restrict__ fb2,
    const float* __restrict__ l1g, const float* __restrict__ l1b,
    const float* __restrict__ l2g, const float* __restrict__ l2b,
    const float* __restrict__ gW1,
    unsigned short* __restrict__ Mu, unsigned short* __restrict__ Pw,
    unsigned short* __restrict__ W1F, unsigned short* __restrict__ W2F,
    unsigned short* __restrict__ encWF, unsigned short* __restrict__ gW1F,
    float* __restrict__ encBf, float* __restrict__ fb1f, float* __restrict__ fb2f,
    float* __restrict__ l1gf, float* __restrict__ l1bf,
    float* __restrict__ l2gf, float* __restrict__ l2bf)
{
  int idx = blockIdx.x * 256 + threadIdx.x;      // 852*256 = 218112 exactly
  if (idx < 65536) {
    int e = idx & 7, lane = (idx >> 3) & 63, kk = (idx >> 9) & 3, nt = idx >> 11;
    int i = kk*32 + (lane >> 4)*8 + e;
    int q = nt*16 + (lane & 15);
    int h = q >> 7, c = q & 127;
    float a = 0.f;
    #pragma unroll 8
    for (int d = 0; d < DH; ++d)
      a += Wq[i*HD + h*DH + d] * Wk[c*HD + h*DH + d];
    Mu[idx] = f2b(a);
  } else if (idx < 131072) {
    int g2 = idx - 65536;
    int e = g2 & 7, lane = (g2 >> 3) & 63, kk = (g2 >> 9) & 15, nt = g2 >> 13;
    int q = kk*32 + (lane >> 4)*8 + e;
    int j = nt*16 + (lane & 15);
    int h = q >> 7, i = q & 127;
    float a = 0.f;
    #pragma unroll 8
    for (int d = 0; d < DH; ++d)
      a += Wv[i*HD + h*DH + d] * Wo[(h*DH + d)*HD + j];
    Pw[g2] = f2b(a);
  } else if (idx < 163840) {
    int g = idx - 131072;
    int e = g & 7, lane = (g >> 3) & 63, kk = (g >> 9) & 3, nt = g >> 11;
    int k = kk*32 + (lane >> 4)*8 + e;
    int n = nt*16 + (lane & 15);
    W1F[g] = f2b(W1[k*FF + n]);
  } else if (idx < 196608) {
    int g = idx - 163840;
    int e = g & 7, lane = (g >> 3) & 63, kk = (g >> 9) & 7, nt = g >> 12;
    int k = kk*32 + (lane >> 4)*8 + e;
    int n = nt*16 + (lane & 15);
    W2F[g] = f2b(W2[k*HD + n]);
  } else if (idx < 200704) {
    int g = idx - 196608;
    int e = g & 7, lane = (g >> 3) & 63, nt = g >> 9;
    int k = (lane >> 4)*8 + e;
    int n = nt*16 + (lane & 15);
    encWF[g] = (k < FD) ? f2b(encW[k*HD + n]) : (unsigned short)0;
  } else if (idx < 217088) {
    int g = idx - 200704;
    int e = g & 7, lane = (g >> 3) & 63, kk = (g >> 9) & 3, nt = g >> 11;
    int k = kk*32 + (lane >> 4)*8 + e;
    int n = nt*16 + (lane & 15);
    gW1F[g] = f2b(gW1[k*HD + n]);
  } else if (idx < 217216) { int t = idx - 217088; encBf[t] = encB[t]; }
  else if (idx < 217472)   { int t = idx - 217216; fb1f[t] = fb1[t]; }
  else if (idx < 217600)   { int t = idx - 217472; fb2f[t] = fb2[t]; }
  else if (idx < 217728)   { int t = idx - 217600; l1gf[t] = l1g[t]; }
  else if (idx < 217856)   { int t = idx - 217728; l1bf[t] = l1b[t]; }
  else if (idx < 217984)   { int t = idx - 217856; l2gf[t] = l2g[t]; }
  else                     { int t = idx - 217984; l2bf[t] = l2b[t]; }
}

// ---------------- fused transformer + GAT1-pre (8 nodes/block) --------------
// LDS 38912 B -> 4 blocks/CU. A-frag rows beyond the real data feed only
// DISCARDED D rows (aliased in-bounds). All A-frag row strides 16B multiples.
__global__ __launch_bounds__(256) void k_xform(
    const float* __restrict__ xh, const float* __restrict__ xc,
    const unsigned short* __restrict__ MuF, const unsigned short* __restrict__ PwF,
    const unsigned short* __restrict__ W1F, const unsigned short* __restrict__ W2F,
    const unsigned short* __restrict__ encWF, const unsigned short* __restrict__ gW1F,
    const float* __restrict__ encBf,
    const float* __restrict__ fb1f, const float* __restrict__ fb2f,
    const float* __restrict__ l1gf, const float* __restrict__ l1bf,
    const float* __restrict__ l2gf, const float* __restrict__ l2bf,
    const float* __restrict__ asrc, const float* __restrict__ adrc,
    unsigned short* __restrict__ xl1B, float* __restrict__ s1, float* __restrict__ d1)
{
  // big: hsB (ph1-5) then {r1F,h1s,h1B,f1B,r2F} (ph6-10)
  __shared__ __align__(16) char big[26112];
  __shared__ unsigned short hlastB[8*136];     // bf16 h_last (A-frags + residual)
  __shared__ float lgaw[8][NH][TT];
  __shared__ __align__(16) char regB[8704];    // xB -> usB -> wB -> xlF

  unsigned short* hsB = (unsigned short*)big;          // [(nl*12+t)][136]
  float* r1F = (float*)big;                            // [8][132] ph6-7
  float* h1s = (float*)(big + 4224);                   // [8][132] ph7-9
  unsigned short* h1B = (unsigned short*)(big + 8448); // [8][136] ph7-8
  float* r2F = (float*)(big + 8448);                   // [8][132] ph9-10 (over h1B)
  unsigned short* f1B = (unsigned short*)(big + 12672);// [8][264] ph8-9

  unsigned short* xB  = (unsigned short*)regB;         // [96][40]  ph0-1
  unsigned short* usB = (unsigned short*)regB;         // [8*4][136] ph2-3 (bf16 u)
  unsigned short* wB  = (unsigned short*)regB;         // [8][520]  ph5-6
  float* xlF = (float*)regB;                           // [8][128]  ph11

  const int tid  = threadIdx.x;
  const int w    = tid >> 6;
  const int lane = tid & 63;
  const int m0   = blockIdx.x * 8;
  const int arow = lane & 15, akg = lane >> 4;
  const int ar8  = arow & 7;                   // aliased A-row (rows 8-15 -> 0-7)

  // --- phase 0: load x -> xB bf16, rows = t*8+nl, K zero-padded 16..31 ---
  #pragma unroll
  for (int k = 0; k < 6; ++k) {
    int idx = tid + k*256;
    int f = idx & 15, rest = idx >> 4;
    int nl = rest & 7, t = rest >> 3;
    int m = m0 + nl, b = m / NN, n = m - b*NN;
    float v = (f < 8) ? xh[(((size_t)b*TT + t)*NN + n)*8 + f]
                      : xc[(((size_t)b*TT + t)*NN + n)*8 + (f - 8)];
    xB[(t*8 + nl)*40 + f] = f2b(v);
  }
  #pragma unroll
  for (int k = 0; k < 6; ++k) {
    int idx = tid + k*256;
    xB[(idx >> 4)*40 + 16 + (idx & 15)] = 0;
  }
  __syncthreads();

  // --- phase 1: encoder via MFMA (96x128 = 6 mt x 8 nt tiles) ---
  {
    const bs8* ef = (const bs8*)encWF;
    bs8 b0 = ef[(2*w + 0)*64 + lane];
    bs8 b1 = ef[(2*w + 1)*64 + lane];
    int drow = akg*4, dc = arow;
    int j0 = (2*w + 0)*16 + dc, j1 = (2*w + 1)*16 + dc;
    float eb0 = encBf[j0], eb1 = encBf[j1];
    fvec4 z4 = {0.f, 0.f, 0.f, 0.f};
    #pragma unroll
    for (int mt = 0; mt < 6; ++mt) {
      bs8 af = *(const bs8*)&xB[(mt*16 + arow)*40 + akg*8];
      fvec4 d0 = mfma16(af, b0, z4);
      fvec4 d1 = mfma16(af, b1, z4);
      #pragma unroll
      for (int reg = 0; reg < 4; ++reg) {
        int gr = mt*16 + drow + reg;
        int t = gr >> 3, nl = gr & 7;
        float v0 = d0[reg] + eb0, v1 = d1[reg] + eb1;
        unsigned short s0 = f2b(v0), s1v = f2b(v1);
        hsB[(nl*12 + t)*136 + j0] = s0;
        hsB[(nl*12 + t)*136 + j1] = s1v;
        if (t == TT-1) {
          hlastB[nl*136 + j0] = s0;
          hlastB[nl*136 + j1] = s1v;
        }
      }
    }
  }
  __syncthreads();                // xB dead

  // --- phase 2: u = h_last @ Mu via MFMA -> usB bf16 [nl*4+hd][136] ---
  {
    bs8 af[4];
    #pragma unroll
    for (int kk = 0; kk < 4; ++kk)
      af[kk] = *(const bs8*)&hlastB[ar8*136 + kk*32 + akg*8];
    const bs8* bp = (const bs8*)MuF;
    fvec4 acc[8];
    #pragma unroll
    for (int n8 = 0; n8 < 8; ++n8) {
      int nt = w*8 + n8;
      const bs8* bq = bp + nt*256 + lane;
      fvec4 a4 = {0.f, 0.f, 0.f, 0.f};
      #pragma unroll
      for (int kk = 0; kk < 4; ++kk)
        a4 = mfma16(af[kk], bq[kk*64], a4);
      acc[n8] = a4;
    }
    __syncthreads();              // xB fully read before usB overlay write
    if (lane < 32) {
      int drow = akg*4, dc = arow;
      #pragma unroll
      for (int n8 = 0; n8 < 8; ++n8) {
        int col = (w*8 + n8)*16 + dc, hd = col >> 7, c = col & 127;
        #pragma unroll
        for (int reg = 0; reg < 4; ++reg)
          usB[((drow + reg)*4 + hd)*136 + c] = f2b(acc[n8][reg]);
      }
    }
  }
  __syncthreads();

  // --- phase 3: logits via MFMA. Per node: D[t][hd] = Ht(12x128) @ u^T.
  //     A rows = hsB t-rows (t>=12 aliased to t=0, D rows discarded);
  //     B cols = usB hd-rows (col&3 clamp, D cols 4-15 discarded).
  //     2 nodes per wave, 4 MFMA each. Replaces ~600 VALU insts/thread. ---
  {
    int ar12 = (arow < 12) ? arow : 0;
    #pragma unroll
    for (int r = 0; r < 2; ++r) {
      int nl = w*2 + r;
      const unsigned short* hb = &hsB[(nl*12 + ar12)*136 + akg*8];
      const unsigned short* ub = &usB[(nl*4 + (arow & 3))*136 + akg*8];
      fvec4 a4 = {0.f, 0.f, 0.f, 0.f};
      #pragma unroll
      for (int kk = 0; kk < 4; ++kk) {
        bs8 af = *(const bs8*)&hb[kk*32];
        bs8 bf = *(const bs8*)&ub[kk*32];
        a4 = mfma16(af, bf, a4);
      }
      if (arow < 4) {             // D col = hd
        #pragma unroll
        for (int reg = 0; reg < 4; ++reg) {
          int t = akg*4 + reg;
          if (t < TT) lgaw[nl][arow][t] = a4[reg] * 0.17677669529663687f;
        }
      }
    }
  }
  __syncthreads();

  // --- phase 4: softmax over t ---
  if (tid < 32) {
    int nl = tid >> 2, hd = tid & 3;
    float mx = -1e30f;
    #pragma unroll
    for (int t = 0; t < TT; ++t) mx = fmaxf(mx, lgaw[nl][hd][t]);
    float ex[TT], sm = 0.f;
    #pragma unroll
    for (int t = 0; t < TT; ++t) { ex[t] = expf(lgaw[nl][hd][t] - mx); sm += ex[t]; }
    float inv = 1.f / sm;
    #pragma unroll
    for (int t = 0; t < TT; ++t) lgaw[nl][hd][t] = ex[t] * inv;
  }
  __syncthreads();

  // --- phase 5: w_h = sum_t alpha*h_t -> wB bf16 (over usB) ---
  {
    int g = tid >> 7, j = tid & 127;
    #pragma unroll
    for (int r = 0; r < 4; ++r) {
      int nl = g*4 + r;
      float wacc[NH] = {0.f, 0.f, 0.f, 0.f};
      #pragma unroll
      for (int t = 0; t < TT; ++t) {
        float hv = b2f(hsB[(nl*12 + t)*136 + j]);
        #pragma unroll
        for (int hd = 0; hd < NH; ++hd) wacc[hd] += lgaw[nl][hd][t] * hv;
      }
      #pragma unroll
      for (int hd = 0; hd < NH; ++hd) wB[nl*520 + hd*128 + j] = f2b(wacc[hd]);
    }
  }
  __syncthreads();                // hsB dead after this point

  // --- phase 6: oa = w @ Pw via MFMA; r1 = h_last + oa -> r1F (over hsB) ---
  {
    fvec4 pacc0 = {0.f,0.f,0.f,0.f}, pacc1 = {0.f,0.f,0.f,0.f};
    const bs8* bp = (const bs8*)PwF;
    const bs8* bq0 = bp + (w*2 + 0)*1024 + lane;
    const bs8* bq1 = bp + (w*2 + 1)*1024 + lane;
    #pragma unroll
    for (int kk = 0; kk < 16; ++kk) {
      bs8 af = *(const bs8*)&wB[ar8*520 + kk*32 + akg*8];
      pacc0 = mfma16(af, bq0[kk*64], pacc0);
      pacc1 = mfma16(af, bq1[kk*64], pacc1);
    }
    __syncthreads();              // wB fully read before r1F overlay write
    if (lane < 32) {
      int drow = akg*4, dc = arow;
      #pragma unroll
      for (int reg = 0; reg < 4; ++reg) {
        int nd = drow + reg;
        int c0 = (w*2 + 0)*16 + dc;
        int c1 = (w*2 + 1)*16 + dc;
        r1F[nd*132 + c0] = b2f(hlastB[nd*136 + c0]) + pacc0[reg];
        r1F[nd*132 + c1] = b2f(hlastB[nd*136 + c1]) + pacc1[reg];
      }
    }
  }
  __syncthreads();

  // --- phase 7: LN1 -> h1s fp32 + h1B bf16 ---
  {
    int nd = tid >> 5, l32 = tid & 31;
    float v[4], s = 0.f, q = 0.f;
    #pragma unroll
    for (int k = 0; k < 4; ++k) {
      v[k] = r1F[nd*132 + l32 + k*32];
      s += v[k]; q += v[k]*v[k];
    }
    #pragma unroll
    for (int off = 16; off > 0; off >>= 1) { s += __shfl_xor(s, off); q += __shfl_xor(q, off); }
    float mu = s*(1.f/128.f), var = q*(1.f/128.f) - mu*mu, rs = rsqrtf(var + 1e-5f);
    #pragma unroll
    for (int k = 0; k < 4; ++k) {
      int c = l32 + k*32;
      float hv = (v[k] - mu)*rs*l1gf[c] + l1bf[c];
      h1s[nd*132 + c] = hv;
      h1B[nd*136 + c] = f2b(hv);
    }
  }
  __syncthreads();

  // --- phase 8: FFN1 via MFMA (K=128, N=256), relu+bias fused -> f1B bf16 ---
  {
    bs8 af[4];
    #pragma unroll
    for (int kk = 0; kk < 4; ++kk)
      af[kk] = *(const bs8*)&h1B[ar8*136 + kk*32 + akg*8];
    const bs8* bp = (const bs8*)W1F;
    #pragma unroll
    for (int n4 = 0; n4 < 4; ++n4) {
      int nt = w*4 + n4;
      const bs8* bq = bp + nt*256 + lane;
      fvec4 a4 = {0.f, 0.f, 0.f, 0.f};
      #pragma unroll
      for (int kk = 0; kk < 4; ++kk)
        a4 = mfma16(af[kk], bq[kk*64], a4);
      if (lane < 32) {
        int drow = akg*4, dc = arow;
        int n = nt*16 + dc;
        float bias = fb1f[n];
        #pragma unroll
        for (int reg = 0; reg < 4; ++reg)
          f1B[(drow + reg)*264 + n] = f2b(fmaxf(a4[reg] + bias, 0.f));
      }
    }
  }
  __syncthreads();

  // --- phase 9: FFN2 via MFMA (K=256, N=128) + residual -> r2F (over h1B) ---
  {
    const bs8* bp = (const bs8*)W2F;
    #pragma unroll
    for (int n2 = 0; n2 < 2; ++n2) {
      int nt = w*2 + n2;
      const bs8* bq = bp + nt*512 + lane;
      fvec4 a4 = {0.f, 0.f, 0.f, 0.f};
      #pragma unroll
      for (int kk = 0; kk < 8; ++kk) {
        bs8 af = *(const bs8*)&f1B[ar8*264 + kk*32 + akg*8];
        a4 = mfma16(af, bq[kk*64], a4);
      }
      if (lane < 32) {
        int drow = akg*4, dc = arow;
        int c = nt*16 + dc;
        float fb2v = fb2f[c];
        #pragma unroll
        for (int reg = 0; reg < 4; ++reg) {
          int nd = drow + reg;
          r2F[nd*132 + c] = h1s[nd*132 + c] + fb2v + a4[reg];
        }
      }
    }
  }
  __syncthreads();

  // --- phase 10: LN2 -> hlastB bf16 (A-frags for GAT1 projection) ---
  {
    int nd = tid >> 5, l32 = tid & 31;
    float v[4], s = 0.f, q = 0.f;
    #pragma unroll
    for (int k = 0; k < 4; ++k) {
      v[k] = r2F[nd*132 + l32 + k*32];
      s += v[k]; q += v[k]*v[k];
    }
    #pragma unroll
    for (int off = 16; off > 0; off >>= 1) { s += __shfl_xor(s, off); q += __shfl_xor(q, off); }
    float mu = s*(1.f/128.f), var = q*(1.f/128.f) - mu*mu, rs = rsqrtf(var + 1e-5f);
    #pragma unroll
    for (int k = 0; k < 4; ++k) {
      int c = l32 + k*32;
      hlastB[nd*136 + c] = f2b((v[k] - mu)*rs*l2gf[c] + l2bf[c]);
    }
  }
  __syncthreads();

  // --- phase 11: xl1 = hlast @ gW1 via MFMA; s1/d1 reduce; globals out ---
  {
    bs8 af[4];
    #pragma unroll
    for (int kk = 0; kk < 4; ++kk)
      af[kk] = *(const bs8*)&hlastB[ar8*136 + kk*32 + akg*8];
    const bs8* bp = (const bs8*)gW1F;
    #pragma unroll
    for (int n2 = 0; n2 < 2; ++n2) {
      int nt = w*2 + n2;
      const bs8* bq = bp + nt*256 + lane;
      fvec4 a4 = {0.f, 0.f, 0.f, 0.f};
      #pragma unroll
      for (int kk = 0; kk < 4; ++kk)
        a4 = mfma16(af[kk], bq[kk*64], a4);
      if (lane < 32) {
        int drow = akg*4, dc = arow;
        int c = nt*16 + dc;
        #pragma unroll
        for (int reg = 0; reg < 4; ++reg)
          xlF[(drow + reg)*128 + c] = a4[reg];
      }
    }
  }
  __syncthreads();
  {
    // xl1 write as packed bf16 (ushort4 = 8B/lane, coalesced)
    fvec4 vv = ((const fvec4*)xlF)[tid];
    usvec4 sv;
    #pragma unroll
    for (int k = 0; k < 4; ++k) sv[k] = f2b(vv[k]);
    *(usvec4*)&xl1B[(size_t)m0*HD + tid*4] = sv;
    // s1/d1 from fp32 xlF (scores stay full precision)
    int nd = tid >> 5, l32 = tid & 31;
    float pa[4], pb[4];
    #pragma unroll
    for (int k = 0; k < 4; ++k) {
      float xv = xlF[nd*128 + l32 + k*32];
      pa[k] = xv * asrc[l32 + k*32];
      pb[k] = xv * adrc[l32 + k*32];
    }
    #pragma unroll
    for (int off = 16; off > 0; off >>= 1) {
      #pragma unroll
      for (int k = 0; k < 4; ++k) {
        pa[k] += __shfl_xor(pa[k], off);
        pb[k] += __shfl_xor(pb[k], off);
      }
    }
    if (l32 == 0) {
      int m = m0 + nd;
      #pragma unroll
      for (int k = 0; k < 4; ++k) {
        s1[m*NH + k] = pa[k];
        d1[m*NH + k] = pb[k];
      }
    }
  }
}

// ---------------- CSR build (batch-shared) ----------------------------------
__global__ __launch_bounds__(256) void k_zero(int* __restrict__ cnt)
{
  int i = blockIdx.x * 256 + threadIdx.x;
  if (i < NN) cnt[i] = 0;
}

__global__ __launch_bounds__(256) void k_hist(const int* __restrict__ e1,
                                              int* __restrict__ cnt)
{
  int i = blockIdx.x * 256 + threadIdx.x;
  if (i < EE) atomicAdd(&cnt[e1[i]], 1);
}

__global__ __launch_bounds__(1024) void k_scan(const int* __restrict__ cnt,
                                               int* __restrict__ row_ptr,
                                               int* __restrict__ cur)
{
  __shared__ int sm[1024];
  int tid = threadIdx.x;
  int base = tid * 10;
  int loc[10];
  int s = 0;
  #pragma unroll
  for (int k = 0; k < 10; ++k) {
    int idx = base + k;
    int v = (idx < NN) ? cnt[idx] : 0;
    loc[k] = s;
    s += v;
  }
  sm[tid] = s;
  __syncthreads();
  for (int off = 1; off < 1024; off <<= 1) {
    int t = (tid >= off) ? sm[tid - off] : 0;
    __syncthreads();
    sm[tid] += t;
    __syncthreads();
  }
  int segbase = sm[tid] - s;
  #pragma unroll
  for (int k = 0; k < 10; ++k) {
    int idx = base + k;
    if (idx < NN) { int o = segbase + loc[k]; row_ptr[idx] = o; cur[idx] = o; }
  }
  if (tid == 1023) row_ptr[NN] = sm[1023];
}

__global__ __launch_bounds__(256) void k_scatter(const int* __restrict__ e0,
                                                 const int* __restrict__ e1,
                                                 int* __restrict__ cur,
                                                 int* __restrict__ ssrc)
{
  int i = blockIdx.x * 256 + threadIdx.x;
  if (i >= EE) return;
  int pos = atomicAdd(&cur[e1[i]], 1);
  ssrc[pos] = e0[i];
}

// ---------------- GAT1 gather + GAT2 pre (2 nodes/block, wave each) ---------
// 128 threads = 2 waves; each wave owns one node (TLP: 32 waves/CU).
// Edge loop unrolled x2 for memory-level parallelism.
__global__ __launch_bounds__(128) void k_g1(
    const int* __restrict__ row_ptr, const int* __restrict__ ssrc,
    const unsigned short* __restrict__ xlB,
    const float* __restrict__ s1, const float* __restrict__ d1,
    const float* __restrict__ gb1, const float* __restrict__ gW2,
    const float* __restrict__ asr2, const float* __restrict__ adr2,
    unsigned short* __restrict__ xl2B, float* __restrict__ s2, float* __restrict__ d2)
{
  __shared__ float g1s[2][HD];
  int tid = threadIdx.x;
  int half = tid >> 6;
  int j = tid & 63;
  int m = blockIdx.x * 2 + half;
  int h = j >> 4;                              // ch 2j -> head (2j)>>5 = j>>4
  int b = m / NN, n = m - b * NN, boff = b * NN;
  float dh = d1[m*NH + h];
  int r0 = row_ptr[n], r1 = row_ptr[n+1];
  float acc0 = 0.f, acc1 = 0.f, dsum = 0.f;
  int e = r0;
  for (; e + 2 <= r1; e += 2) {
    int sa = ssrc[e] + boff, sb = ssrc[e+1] + boff;
    float ka = s1[sa*NH + h], kb = s1[sb*NH + h];
    unsigned int ua = *(const unsigned int*)&xlB[(size_t)sa*HD + 2*j];
    unsigned int ub = *(const unsigned int*)&xlB[(size_t)sb*HD + 2*j];
    float eva = expf(lrelu(ka + dh));
    float evb = expf(lrelu(kb + dh));
    float lo, hi;
    up2(ua, lo, hi); acc0 += eva * lo; acc1 += eva * hi;
    up2(ub, lo, hi); acc0 += evb * lo; acc1 += evb * hi;
    dsum += eva + evb;
  }
  if (e < r1) {
    int sa = ssrc[e] + boff;
    float ev = expf(lrelu(s1[sa*NH + h] + dh));
    unsigned int u = *(const unsigned int*)&xlB[(size_t)sa*HD + 2*j];
    float lo, hi; up2(u, lo, hi);
    acc0 += ev * lo; acc1 += ev * hi;
    dsum += ev;
  }
  {
    float es = expf(lrelu(s1[m*NH + h] + dh));       // self loop
    unsigned int u = *(const unsigned int*)&xlB[(size_t)m*HD + 2*j];
    float lo, hi; up2(u, lo, hi);
    acc0 += es * lo; acc1 += es * hi;
    dsum += es;
  }
  float inv = 1.f / (dsum + 1e-16f);
  float v0 = acc0 * inv + gb1[2*j];
  float v1 = acc1 * inv + gb1[2*j + 1];
  g1s[half][2*j]     = v0 > 0.f ? v0 : expm1f(v0);   // ELU
  g1s[half][2*j + 1] = v1 > 0.f ? v1 : expm1f(v1);
  __syncthreads();
  // GAT2 pre: xl2 = g1 @ gW2 (64 lanes per node), scores fp32 pre-rounding
  float a = 0.f;
  for (int i = 0; i < HD; ++i) a += g1s[half][i] * gW2[i*GO + j];
  xl2B[(size_t)m*GO + j] = f2b(a);
  float pa = a * asr2[j], pb = a * adr2[j];
  #pragma unroll
  for (int off = 32; off > 0; off >>= 1) { pa += __shfl_xor(pa, off); pb += __shfl_xor(pb, off); }
  if (j == 0) { s2[m] = pa; d2[m] = pb; }
}

// ---------------- GAT2 gather + output projection (2 nodes/block) -----------
__global__ __launch_bounds__(128) void k_g2(
    const int* __restrict__ row_ptr, const int* __restrict__ ssrc,
    const unsigned short* __restrict__ xl2B,
    const float* __restrict__ s2, const float* __restrict__ d2,
    const float* __restrict__ gb2, const float* __restrict__ oW, const float* __restrict__ ob,
    float* __restrict__ y)
{
  __shared__ float g2s[2][GO];
  int tid = threadIdx.x;
  int half = tid >> 6;
  int j = tid & 63;
  int m = blockIdx.x * 2 + half;
  int b = m / NN, n = m - b * NN, boff = b * NN;
  float d2m = d2[m];
  int r0 = row_ptr[n], r1 = row_ptr[n+1];
  float acc = 0.f, dsum = 0.f;
  int e = r0;
  for (; e + 2 <= r1; e += 2) {
    int sa = ssrc[e] + boff, sb = ssrc[e+1] + boff;
    float ka = s2[sa], kb = s2[sb];
    unsigned short xa = xl2B[(size_t)sa*GO + j];
    unsigned short xb = xl2B[(size_t)sb*GO + j];
    float eva = expf(lrelu(ka + d2m));
    float evb = expf(lrelu(kb + d2m));
    acc  += eva * b2f(xa) + evb * b2f(xb);
    dsum += eva + evb;
  }
  if (e < r1) {
    int sa = ssrc[e] + boff;
    float ev = expf(lrelu(s2[sa] + d2m));
    acc  += ev * b2f(xl2B[(size_t)sa*GO + j]);
    dsum += ev;
  }
  float es = expf(lrelu(s2[m] + d2m));
  acc  += es * b2f(xl2B[(size_t)m*GO + j]);
  dsum += es;
  g2s[half][j] = acc / (dsum + 1e-16f) + gb2[j];
  __syncthreads();
  if (j < HR) {
    float a = ob[j];
    #pragma unroll
    for (int o2 = 0; o2 < GO; ++o2) a += g2s[half][o2] * oW[o2*HR + j];
    y[((size_t)b*HR + j)*NN + n] = a;
  }
}

// ---------------- launch ----------------------------------------------------
extern "C" void kernel_launch(void* const* d_in, const int* in_sizes, int n_in,
                              void* d_out, int out_size, void* d_ws, size_t ws_size,
                              hipStream_t stream)
{
  const int* ei = (const int*)d_in[2];
  const int* e0 = ei;
  const int* e1 = ei + EE;

  float* ws = (float*)d_ws;
  unsigned short* xl1B = (unsigned short*)ws;             // 40000*128 bf16
  unsigned short* xl2B = (unsigned short*)(ws + 2560000); // 40000*64 bf16
  float* ovl = ws + 3840000;          // overlap region (weights, then CSR)
  float* s1  = ws + 4200000;          // 40000*4
  float* d1  = ws + 4360000;          // 40000*4
  float* s2  = ws + 4520000;          // 40000
  float* d2  = ws + 4560000;          // 40000

  // Weight buffers live [prep, xform] in the overlap region.
  unsigned short* Mu    = (unsigned short*)ovl;          // 65536 bf16 frags
  unsigned short* Pw    = Mu + 65536;                    // 65536
  unsigned short* W1F   = Mu + 131072;                   // 32768
  unsigned short* W2F   = Mu + 163840;                   // 32768
  unsigned short* encWF = Mu + 196608;                   // 4096
  unsigned short* gW1F  = Mu + 200704;                   // 16384
  float* encBf = (float*)(Mu + 217088);
  float* fb1f  = encBf + 128;
  float* fb2f  = fb1f + 256;
  float* l1gf  = fb2f + 128;
  float* l1bf  = l1gf + 128;
  float* l2gf  = l1bf + 128;
  float* l2bf  = l2gf + 128;

  // CSR arrays live [hist, end] in the SAME overlap region (stream-serial).
  int* cnt     = (int*)ovl;           // 10000
  int* row_ptr = cnt + 16384;         // 10001
  int* cur     = cnt + 32768;         // 10000
  int* ssrc    = cnt + 49152;         // 160000

  k_prep<<<852, 256, 0, stream>>>(
      (const float*)d_in[5], (const float*)d_in[6], (const float*)d_in[7], (const float*)d_in[8],
      (const float*)d_in[3], (const float*)d_in[4], (const float*)d_in[11], (const float*)d_in[12],
      (const float*)d_in[13], (const float*)d_in[14], (const float*)d_in[9], (const float*)d_in[10],
      (const float*)d_in[15], (const float*)d_in[16], (const float*)d_in[17],
      Mu, Pw, W1F, W2F, encWF, gW1F,
      encBf, fb1f, fb2f, l1gf, l1bf, l2gf, l2bf);

  k_xform<<<MM/8, 256, 0, stream>>>(
      (const float*)d_in[0], (const float*)d_in[1],
      Mu, Pw, W1F, W2F, encWF, gW1F,
      encBf, fb1f, fb2f, l1gf, l1bf, l2gf, l2bf,
      (const float*)d_in[18], (const float*)d_in[19],
      xl1B, s1, d1);

  // CSR build (after xform: overlap region is free now)
  k_zero<<<(NN + 255)/256, 256, 0, stream>>>(cnt);
  k_hist<<<(EE + 255)/256, 256, 0, stream>>>(e1, cnt);
  k_scan<<<1, 1024, 0, stream>>>(cnt, row_ptr, cur);
  k_scatter<<<(EE + 255)/256, 256, 0, stream>>>(e0, e1, cur, ssrc);

  k_g1<<<MM/2, 128, 0, stream>>>(row_ptr, ssrc, xl1B, s1, d1,
      (const float*)d_in[20], (const float*)d_in[21],
      (const float*)d_in[22], (const float*)d_in[23],
      xl2B, s2, d2);

  k_g2<<<MM/2, 128, 0, stream>>>(row_ptr, ssrc, xl2B, s2, d2,
      (const float*)d_in[24], (const float*)d_in[25], (const float*)d_in[26],
      (float*)d_out);
}

// Round 13
// 245.011 us; speedup vs baseline: 7.5734x; 1.1285x over previous
//
#include <hip/hip_runtime.h>
#include <hip/hip_bf16.h>

#define DEV static __device__ __forceinline__

constexpr int BB = 4;        // batches
constexpr int TT = 12;       // timesteps
constexpr int NN = 10000;    // nodes per batch
constexpr int FD = 16;       // input features (8+8)
constexpr int HD = 128;      // hidden
constexpr int NH = 4;        // attn heads
constexpr int DH = 32;       // head dim
constexpr int FF = 256;      // ffn hidden
constexpr int GO = 64;       // gat2 out
constexpr int HR = 24;       // horizon
constexpr int EE = 160000;   // edges per batch
constexpr int MM = BB * NN;  // total nodes

typedef unsigned short bvec8 __attribute__((ext_vector_type(8)));
typedef unsigned short usvec4 __attribute__((ext_vector_type(4)));
typedef float fvec4 __attribute__((ext_vector_type(4)));
typedef short bs8 __attribute__((ext_vector_type(8)));      // MFMA bf16 frag (4 VGPR)

DEV float lrelu(float x) { return x >= 0.f ? x : 0.2f * x; }

DEV float b2f(unsigned short u) {
  union { unsigned int i; float f; } x; x.i = ((unsigned int)u) << 16; return x.f;
}
DEV unsigned short f2b(float f) {
  union { float f; unsigned int i; } x; x.f = f;
  unsigned int r = x.i + 0x7FFFu + ((x.i >> 16) & 1u);
  return (unsigned short)(r >> 16);
}
DEV void up2(unsigned int u, float& lo, float& hi) {
  union { unsigned int i; float f; } a, b;
  a.i = u << 16; b.i = u & 0xFFFF0000u;
  lo = a.f; hi = b.f;
}

DEV fvec4 mfma16(bs8 a, bs8 b, fvec4 c) {
  return __builtin_amdgcn_mfma_f32_16x16x32_bf16(a, b, c, 0, 0, 0);
}

// ---------------- prep: fold + re-layout ALL transformer weights (fp32 in) --
// MFMA B-fragment order: frag idx = ((nt*nK + kk)*64 + lane), element e:
//   B[k][n] with k = kk*32 + (lane>>4)*8 + e, n = nt*16 + (lane&15).
__global__ __launch_bounds__(256) void k_prep(
    const float* __restrict__ Wq, const float* __restrict__ Wk,
    const float* __restrict__ Wv, const float* __restrict__ Wo,
    const float* __restrict__ encW, const float* __restrict__ encB,
    const float* __restrict__ W1, const float* __restrict__ fb1,
    const float* __restrict__ W2, const float* __restrict__ fb2,
    const float* __restrict__ l1g, const float* __restrict__ l1b,
    const float* __restrict__ l2g, const float* __restrict__ l2b,
    const float* __restrict__ gW1,
    unsigned short* __restrict__ Mu, unsigned short* __restrict__ Pw,
    unsigned short* __restrict__ W1F, unsigned short* __restrict__ W2F,
    unsigned short* __restrict__ encWF, unsigned short* __restrict__ gW1F,
    float* __restrict__ encBf, float* __restrict__ fb1f, float* __restrict__ fb2f,
    float* __restrict__ l1gf, float* __restrict__ l1bf,
    float* __restrict__ l2gf, float* __restrict__ l2bf)
{
  int idx = blockIdx.x * 256 + threadIdx.x;      // 852*256 = 218112 exactly
  if (idx < 65536) {
    int e = idx & 7, lane = (idx >> 3) & 63, kk = (idx >> 9) & 3, nt = idx >> 11;
    int i = kk*32 + (lane >> 4)*8 + e;
    int q = nt*16 + (lane & 15);
    int h = q >> 7, c = q & 127;
    float a = 0.f;
    #pragma unroll 8
    for (int d = 0; d < DH; ++d)
      a += Wq[i*HD + h*DH + d] * Wk[c*HD + h*DH + d];
    Mu[idx] = f2b(a);
  } else if (idx < 131072) {
    int g2 = idx - 65536;
    int e = g2 & 7, lane = (g2 >> 3) & 63, kk = (g2 >> 9) & 15, nt = g2 >> 13;
    int q = kk*32 + (lane >> 4)*8 + e;
    int j = nt*16 + (lane & 15);
    int h = q >> 7, i = q & 127;
    float a = 0.f;
    #pragma unroll 8
    for (int d = 0; d < DH; ++d)
      a += Wv[i*HD + h*DH + d] * Wo[(h*DH + d)*HD + j];
    Pw[g2] = f2b(a);
  } else if (idx < 163840) {
    int g = idx - 131072;
    int e = g & 7, lane = (g >> 3) & 63, kk = (g >> 9) & 3, nt = g >> 11;
    int k = kk*32 + (lane >> 4)*8 + e;
    int n = nt*16 + (lane & 15);
    W1F[g] = f2b(W1[k*FF + n]);
  } else if (idx < 196608) {
    int g = idx - 163840;
    int e = g & 7, lane = (g >> 3) & 63, kk = (g >> 9) & 7, nt = g >> 12;
    int k = kk*32 + (lane >> 4)*8 + e;
    int n = nt*16 + (lane & 15);
    W2F[g] = f2b(W2[k*HD + n]);
  } else if (idx < 200704) {
    int g = idx - 196608;
    int e = g & 7, lane = (g >> 3) & 63, nt = g >> 9;
    int k = (lane >> 4)*8 + e;
    int n = nt*16 + (lane & 15);
    encWF[g] = (k < FD) ? f2b(encW[k*HD + n]) : (unsigned short)0;
  } else if (idx < 217088) {
    int g = idx - 200704;
    int e = g & 7, lane = (g >> 3) & 63, kk = (g >> 9) & 3, nt = g >> 11;
    int k = kk*32 + (lane >> 4)*8 + e;
    int n = nt*16 + (lane & 15);
    gW1F[g] = f2b(gW1[k*HD + n]);
  } else if (idx < 217216) { int t = idx - 217088; encBf[t] = encB[t]; }
  else if (idx < 217472)   { int t = idx - 217216; fb1f[t] = fb1[t]; }
  else if (idx < 217600)   { int t = idx - 217472; fb2f[t] = fb2[t]; }
  else if (idx < 217728)   { int t = idx - 217600; l1gf[t] = l1g[t]; }
  else if (idx < 217856)   { int t = idx - 217728; l1bf[t] = l1b[t]; }
  else if (idx < 217984)   { int t = idx - 217856; l2gf[t] = l2g[t]; }
  else                     { int t = idx - 217984; l2bf[t] = l2b[t]; }
}

// ---------------- fused transformer + GAT1-pre (8 nodes/block) --------------
// LDS 38912 B -> 4 blocks/CU. A-frag rows beyond the real data feed only
// DISCARDED D rows (aliased in-bounds). All A-frag row strides 16B multiples.
__global__ __launch_bounds__(256) void k_xform(
    const float* __restrict__ xh, const float* __restrict__ xc,
    const unsigned short* __restrict__ MuF, const unsigned short* __restrict__ PwF,
    const unsigned short* __restrict__ W1F, const unsigned short* __restrict__ W2F,
    const unsigned short* __restrict__ encWF, const unsigned short* __restrict__ gW1F,
    const float* __restrict__ encBf,
    const float* __restrict__ fb1f, const float* __restrict__ fb2f,
    const float* __restrict__ l1gf, const float* __restrict__ l1bf,
    const float* __restrict__ l2gf, const float* __restrict__ l2bf,
    const float* __restrict__ asrc, const float* __restrict__ adrc,
    unsigned short* __restrict__ xl1B, float* __restrict__ s1, float* __restrict__ d1)
{
  // big: hsB (ph1-5) then {r1F,h1s,h1B,f1B,r2F} (ph6-10)
  __shared__ __align__(16) char big[26112];
  __shared__ unsigned short hlastB[8*136];     // bf16 h_last (A-frags + residual)
  __shared__ float lgaw[8][NH][TT];
  __shared__ __align__(16) char regB[8704];    // xB -> usB -> wB -> xlF

  unsigned short* hsB = (unsigned short*)big;          // [(nl*12+t)][136]
  float* r1F = (float*)big;                            // [8][132] ph6-7
  float* h1s = (float*)(big + 4224);                   // [8][132] ph7-9
  unsigned short* h1B = (unsigned short*)(big + 8448); // [8][136] ph7-8
  float* r2F = (float*)(big + 8448);                   // [8][132] ph9-10 (over h1B)
  unsigned short* f1B = (unsigned short*)(big + 12672);// [8][264] ph8-9

  unsigned short* xB  = (unsigned short*)regB;         // [96][40]  ph0-1
  unsigned short* usB = (unsigned short*)regB;         // [8*4][136] ph2-3 (bf16 u)
  unsigned short* wB  = (unsigned short*)regB;         // [8][520]  ph5-6
  float* xlF = (float*)regB;                           // [8][128]  ph11

  const int tid  = threadIdx.x;
  const int w    = tid >> 6;
  const int lane = tid & 63;
  const int m0   = blockIdx.x * 8;
  const int arow = lane & 15, akg = lane >> 4;
  const int ar8  = arow & 7;                   // aliased A-row (rows 8-15 -> 0-7)

  // --- phase 0: load x -> xB bf16, rows = t*8+nl, K zero-padded 16..31 ---
  #pragma unroll
  for (int k = 0; k < 6; ++k) {
    int idx = tid + k*256;
    int f = idx & 15, rest = idx >> 4;
    int nl = rest & 7, t = rest >> 3;
    int m = m0 + nl, b = m / NN, n = m - b*NN;
    float v = (f < 8) ? xh[(((size_t)b*TT + t)*NN + n)*8 + f]
                      : xc[(((size_t)b*TT + t)*NN + n)*8 + (f - 8)];
    xB[(t*8 + nl)*40 + f] = f2b(v);
  }
  #pragma unroll
  for (int k = 0; k < 6; ++k) {
    int idx = tid + k*256;
    xB[(idx >> 4)*40 + 16 + (idx & 15)] = 0;
  }
  __syncthreads();

  // --- phase 1: encoder via MFMA (96x128 = 6 mt x 8 nt tiles) ---
  {
    const bs8* ef = (const bs8*)encWF;
    bs8 b0 = ef[(2*w + 0)*64 + lane];
    bs8 b1 = ef[(2*w + 1)*64 + lane];
    int drow = akg*4, dc = arow;
    int j0 = (2*w + 0)*16 + dc, j1 = (2*w + 1)*16 + dc;
    float eb0 = encBf[j0], eb1 = encBf[j1];
    fvec4 z4 = {0.f, 0.f, 0.f, 0.f};
    #pragma unroll
    for (int mt = 0; mt < 6; ++mt) {
      bs8 af = *(const bs8*)&xB[(mt*16 + arow)*40 + akg*8];
      fvec4 d0 = mfma16(af, b0, z4);
      fvec4 d1 = mfma16(af, b1, z4);
      #pragma unroll
      for (int reg = 0; reg < 4; ++reg) {
        int gr = mt*16 + drow + reg;
        int t = gr >> 3, nl = gr & 7;
        float v0 = d0[reg] + eb0, v1 = d1[reg] + eb1;
        unsigned short s0 = f2b(v0), s1v = f2b(v1);
        hsB[(nl*12 + t)*136 + j0] = s0;
        hsB[(nl*12 + t)*136 + j1] = s1v;
        if (t == TT-1) {
          hlastB[nl*136 + j0] = s0;
          hlastB[nl*136 + j1] = s1v;
        }
      }
    }
  }
  __syncthreads();                // xB dead

  // --- phase 2: u = h_last @ Mu via MFMA -> usB bf16 [nl*4+hd][136] ---
  {
    bs8 af[4];
    #pragma unroll
    for (int kk = 0; kk < 4; ++kk)
      af[kk] = *(const bs8*)&hlastB[ar8*136 + kk*32 + akg*8];
    const bs8* bp = (const bs8*)MuF;
    fvec4 acc[8];
    #pragma unroll
    for (int n8 = 0; n8 < 8; ++n8) {
      int nt = w*8 + n8;
      const bs8* bq = bp + nt*256 + lane;
      fvec4 a4 = {0.f, 0.f, 0.f, 0.f};
      #pragma unroll
      for (int kk = 0; kk < 4; ++kk)
        a4 = mfma16(af[kk], bq[kk*64], a4);
      acc[n8] = a4;
    }
    __syncthreads();              // xB fully read before usB overlay write
    if (lane < 32) {
      int drow = akg*4, dc = arow;
      #pragma unroll
      for (int n8 = 0; n8 < 8; ++n8) {
        int col = (w*8 + n8)*16 + dc, hd = col >> 7, c = col & 127;
        #pragma unroll
        for (int reg = 0; reg < 4; ++reg)
          usB[((drow + reg)*4 + hd)*136 + c] = f2b(acc[n8][reg]);
      }
    }
  }
  __syncthreads();

  // --- phase 3: logits via MFMA. Per node: D[t][hd] = Ht(12x128) @ u^T. ---
  {
    int ar12 = (arow < 12) ? arow : 0;
    #pragma unroll
    for (int r = 0; r < 2; ++r) {
      int nl = w*2 + r;
      const unsigned short* hb = &hsB[(nl*12 + ar12)*136 + akg*8];
      const unsigned short* ub = &usB[(nl*4 + (arow & 3))*136 + akg*8];
      fvec4 a4 = {0.f, 0.f, 0.f, 0.f};
      #pragma unroll
      for (int kk = 0; kk < 4; ++kk) {
        bs8 af = *(const bs8*)&hb[kk*32];
        bs8 bf = *(const bs8*)&ub[kk*32];
        a4 = mfma16(af, bf, a4);
      }
      if (arow < 4) {             // D col = hd
        #pragma unroll
        for (int reg = 0; reg < 4; ++reg) {
          int t = akg*4 + reg;
          if (t < TT) lgaw[nl][arow][t] = a4[reg] * 0.17677669529663687f;
        }
      }
    }
  }
  __syncthreads();

  // --- phase 4: softmax over t ---
  if (tid < 32) {
    int nl = tid >> 2, hd = tid & 3;
    float mx = -1e30f;
    #pragma unroll
    for (int t = 0; t < TT; ++t) mx = fmaxf(mx, lgaw[nl][hd][t]);
    float ex[TT], sm = 0.f;
    #pragma unroll
    for (int t = 0; t < TT; ++t) { ex[t] = expf(lgaw[nl][hd][t] - mx); sm += ex[t]; }
    float inv = 1.f / sm;
    #pragma unroll
    for (int t = 0; t < TT; ++t) lgaw[nl][hd][t] = ex[t] * inv;
  }
  __syncthreads();

  // --- phase 5: w_h = sum_t alpha*h_t -> wB bf16 (over usB) ---
  {
    int g = tid >> 7, j = tid & 127;
    #pragma unroll
    for (int r = 0; r < 4; ++r) {
      int nl = g*4 + r;
      float wacc[NH] = {0.f, 0.f, 0.f, 0.f};
      #pragma unroll
      for (int t = 0; t < TT; ++t) {
        float hv = b2f(hsB[(nl*12 + t)*136 + j]);
        #pragma unroll
        for (int hd = 0; hd < NH; ++hd) wacc[hd] += lgaw[nl][hd][t] * hv;
      }
      #pragma unroll
      for (int hd = 0; hd < NH; ++hd) wB[nl*520 + hd*128 + j] = f2b(wacc[hd]);
    }
  }
  __syncthreads();                // hsB dead after this point

  // --- phase 6: oa = w @ Pw via MFMA; r1 = h_last + oa -> r1F (over hsB) ---
  {
    fvec4 pacc0 = {0.f,0.f,0.f,0.f}, pacc1 = {0.f,0.f,0.f,0.f};
    const bs8* bp = (const bs8*)PwF;
    const bs8* bq0 = bp + (w*2 + 0)*1024 + lane;
    const bs8* bq1 = bp + (w*2 + 1)*1024 + lane;
    #pragma unroll
    for (int kk = 0; kk < 16; ++kk) {
      bs8 af = *(const bs8*)&wB[ar8*520 + kk*32 + akg*8];
      pacc0 = mfma16(af, bq0[kk*64], pacc0);
      pacc1 = mfma16(af, bq1[kk*64], pacc1);
    }
    __syncthreads();              // wB fully read before r1F overlay write
    if (lane < 32) {
      int drow = akg*4, dc = arow;
      #pragma unroll
      for (int reg = 0; reg < 4; ++reg) {
        int nd = drow + reg;
        int c0 = (w*2 + 0)*16 + dc;
        int c1 = (w*2 + 1)*16 + dc;
        r1F[nd*132 + c0] = b2f(hlastB[nd*136 + c0]) + pacc0[reg];
        r1F[nd*132 + c1] = b2f(hlastB[nd*136 + c1]) + pacc1[reg];
      }
    }
  }
  __syncthreads();

  // --- phase 7: LN1 -> h1s fp32 + h1B bf16 ---
  {
    int nd = tid >> 5, l32 = tid & 31;
    float v[4], s = 0.f, q = 0.f;
    #pragma unroll
    for (int k = 0; k < 4; ++k) {
      v[k] = r1F[nd*132 + l32 + k*32];
      s += v[k]; q += v[k]*v[k];
    }
    #pragma unroll
    for (int off = 16; off > 0; off >>= 1) { s += __shfl_xor(s, off); q += __shfl_xor(q, off); }
    float mu = s*(1.f/128.f), var = q*(1.f/128.f) - mu*mu, rs = rsqrtf(var + 1e-5f);
    #pragma unroll
    for (int k = 0; k < 4; ++k) {
      int c = l32 + k*32;
      float hv = (v[k] - mu)*rs*l1gf[c] + l1bf[c];
      h1s[nd*132 + c] = hv;
      h1B[nd*136 + c] = f2b(hv);
    }
  }
  __syncthreads();

  // --- phase 8: FFN1 via MFMA (K=128, N=256), relu+bias fused -> f1B bf16 ---
  {
    bs8 af[4];
    #pragma unroll
    for (int kk = 0; kk < 4; ++kk)
      af[kk] = *(const bs8*)&h1B[ar8*136 + kk*32 + akg*8];
    const bs8* bp = (const bs8*)W1F;
    #pragma unroll
    for (int n4 = 0; n4 < 4; ++n4) {
      int nt = w*4 + n4;
      const bs8* bq = bp + nt*256 + lane;
      fvec4 a4 = {0.f, 0.f, 0.f, 0.f};
      #pragma unroll
      for (int kk = 0; kk < 4; ++kk)
        a4 = mfma16(af[kk], bq[kk*64], a4);
      if (lane < 32) {
        int drow = akg*4, dc = arow;
        int n = nt*16 + dc;
        float bias = fb1f[n];
        #pragma unroll
        for (int reg = 0; reg < 4; ++reg)
          f1B[(drow + reg)*264 + n] = f2b(fmaxf(a4[reg] + bias, 0.f));
      }
    }
  }
  __syncthreads();

  // --- phase 9: FFN2 via MFMA (K=256, N=128) + residual -> r2F (over h1B) ---
  {
    const bs8* bp = (const bs8*)W2F;
    #pragma unroll
    for (int n2 = 0; n2 < 2; ++n2) {
      int nt = w*2 + n2;
      const bs8* bq = bp + nt*512 + lane;
      fvec4 a4 = {0.f, 0.f, 0.f, 0.f};
      #pragma unroll
      for (int kk = 0; kk < 8; ++kk) {
        bs8 af = *(const bs8*)&f1B[ar8*264 + kk*32 + akg*8];
        a4 = mfma16(af, bq[kk*64], a4);
      }
      if (lane < 32) {
        int drow = akg*4, dc = arow;
        int c = nt*16 + dc;
        float fb2v = fb2f[c];
        #pragma unroll
        for (int reg = 0; reg < 4; ++reg) {
          int nd = drow + reg;
          r2F[nd*132 + c] = h1s[nd*132 + c] + fb2v + a4[reg];
        }
      }
    }
  }
  __syncthreads();

  // --- phase 10: LN2 -> hlastB bf16 (A-frags for GAT1 projection) ---
  {
    int nd = tid >> 5, l32 = tid & 31;
    float v[4], s = 0.f, q = 0.f;
    #pragma unroll
    for (int k = 0; k < 4; ++k) {
      v[k] = r2F[nd*132 + l32 + k*32];
      s += v[k]; q += v[k]*v[k];
    }
    #pragma unroll
    for (int off = 16; off > 0; off >>= 1) { s += __shfl_xor(s, off); q += __shfl_xor(q, off); }
    float mu = s*(1.f/128.f), var = q*(1.f/128.f) - mu*mu, rs = rsqrtf(var + 1e-5f);
    #pragma unroll
    for (int k = 0; k < 4; ++k) {
      int c = l32 + k*32;
      hlastB[nd*136 + c] = f2b((v[k] - mu)*rs*l2gf[c] + l2bf[c]);
    }
  }
  __syncthreads();

  // --- phase 11: xl1 = hlast @ gW1 via MFMA; s1/d1 reduce; globals out ---
  {
    bs8 af[4];
    #pragma unroll
    for (int kk = 0; kk < 4; ++kk)
      af[kk] = *(const bs8*)&hlastB[ar8*136 + kk*32 + akg*8];
    const bs8* bp = (const bs8*)gW1F;
    #pragma unroll
    for (int n2 = 0; n2 < 2; ++n2) {
      int nt = w*2 + n2;
      const bs8* bq = bp + nt*256 + lane;
      fvec4 a4 = {0.f, 0.f, 0.f, 0.f};
      #pragma unroll
      for (int kk = 0; kk < 4; ++kk)
        a4 = mfma16(af[kk], bq[kk*64], a4);
      if (lane < 32) {
        int drow = akg*4, dc = arow;
        int c = nt*16 + dc;
        #pragma unroll
        for (int reg = 0; reg < 4; ++reg)
          xlF[(drow + reg)*128 + c] = a4[reg];
      }
    }
  }
  __syncthreads();
  {
    // xl1 write as packed bf16 (ushort4 = 8B/lane, coalesced)
    fvec4 vv = ((const fvec4*)xlF)[tid];
    usvec4 sv;
    #pragma unroll
    for (int k = 0; k < 4; ++k) sv[k] = f2b(vv[k]);
    *(usvec4*)&xl1B[(size_t)m0*HD + tid*4] = sv;
    // s1/d1 from fp32 xlF (scores stay full precision)
    int nd = tid >> 5, l32 = tid & 31;
    float pa[4], pb[4];
    #pragma unroll
    for (int k = 0; k < 4; ++k) {
      float xv = xlF[nd*128 + l32 + k*32];
      pa[k] = xv * asrc[l32 + k*32];
      pb[k] = xv * adrc[l32 + k*32];
    }
    #pragma unroll
    for (int off = 16; off > 0; off >>= 1) {
      #pragma unroll
      for (int k = 0; k < 4; ++k) {
        pa[k] += __shfl_xor(pa[k], off);
        pb[k] += __shfl_xor(pb[k], off);
      }
    }
    if (l32 == 0) {
      int m = m0 + nd;
      #pragma unroll
      for (int k = 0; k < 4; ++k) {
        s1[m*NH + k] = pa[k];
        d1[m*NH + k] = pb[k];
      }
    }
  }
}

// ---------------- CSR build (batch-shared) ----------------------------------
__global__ __launch_bounds__(256) void k_zero(int* __restrict__ cnt)
{
  int i = blockIdx.x * 256 + threadIdx.x;
  if (i < NN) cnt[i] = 0;
}

__global__ __launch_bounds__(256) void k_hist(const int* __restrict__ e1,
                                              int* __restrict__ cnt)
{
  int i = blockIdx.x * 256 + threadIdx.x;
  if (i < EE) atomicAdd(&cnt[e1[i]], 1);
}

__global__ __launch_bounds__(1024) void k_scan(const int* __restrict__ cnt,
                                               int* __restrict__ row_ptr,
                                               int* __restrict__ cur)
{
  __shared__ int sm[1024];
  int tid = threadIdx.x;
  int base = tid * 10;
  int loc[10];
  int s = 0;
  #pragma unroll
  for (int k = 0; k < 10; ++k) {
    int idx = base + k;
    int v = (idx < NN) ? cnt[idx] : 0;
    loc[k] = s;
    s += v;
  }
  sm[tid] = s;
  __syncthreads();
  for (int off = 1; off < 1024; off <<= 1) {
    int t = (tid >= off) ? sm[tid - off] : 0;
    __syncthreads();
    sm[tid] += t;
    __syncthreads();
  }
  int segbase = sm[tid] - s;
  #pragma unroll
  for (int k = 0; k < 10; ++k) {
    int idx = base + k;
    if (idx < NN) { int o = segbase + loc[k]; row_ptr[idx] = o; cur[idx] = o; }
  }
  if (tid == 1023) row_ptr[NN] = sm[1023];
}

__global__ __launch_bounds__(256) void k_scatter(const int* __restrict__ e0,
                                                 const int* __restrict__ e1,
                                                 int* __restrict__ cur,
                                                 int* __restrict__ ssrc)
{
  int i = blockIdx.x * 256 + threadIdx.x;
  if (i >= EE) return;
  int pos = atomicAdd(&cur[e1[i]], 1);
  ssrc[pos] = e0[i];
}

// ---------------- GAT1 gather + GAT2 pre (1 node/wave, 64 thr) --------------
// Single wave per node: no cross-wave barrier, per-node latency decoupled.
// Edge loop unrolled x2 for memory-level parallelism.
__global__ __launch_bounds__(64) void k_g1(
    const int* __restrict__ row_ptr, const int* __restrict__ ssrc,
    const unsigned short* __restrict__ xlB,
    const float* __restrict__ s1, const float* __restrict__ d1,
    const float* __restrict__ gb1, const float* __restrict__ gW2,
    const float* __restrict__ asr2, const float* __restrict__ adr2,
    unsigned short* __restrict__ xl2B, float* __restrict__ s2, float* __restrict__ d2)
{
  __shared__ float g1s[HD];
  int j = threadIdx.x, m = blockIdx.x, h = j >> 4;   // ch 2j -> head (2j)>>5 = j>>4
  int b = m / NN, n = m - b * NN, boff = b * NN;
  float dh = d1[m*NH + h];
  int r0 = row_ptr[n], r1 = row_ptr[n+1];
  float acc0 = 0.f, acc1 = 0.f, dsum = 0.f;
  int e = r0;
  for (; e + 2 <= r1; e += 2) {
    int sa = ssrc[e] + boff, sb = ssrc[e+1] + boff;
    float ka = s1[sa*NH + h], kb = s1[sb*NH + h];
    unsigned int ua = *(const unsigned int*)&xlB[(size_t)sa*HD + 2*j];
    unsigned int ub = *(const unsigned int*)&xlB[(size_t)sb*HD + 2*j];
    float eva = expf(lrelu(ka + dh));
    float evb = expf(lrelu(kb + dh));
    float lo, hi;
    up2(ua, lo, hi); acc0 += eva * lo; acc1 += eva * hi;
    up2(ub, lo, hi); acc0 += evb * lo; acc1 += evb * hi;
    dsum += eva + evb;
  }
  if (e < r1) {
    int sa = ssrc[e] + boff;
    float ev = expf(lrelu(s1[sa*NH + h] + dh));
    unsigned int u = *(const unsigned int*)&xlB[(size_t)sa*HD + 2*j];
    float lo, hi; up2(u, lo, hi);
    acc0 += ev * lo; acc1 += ev * hi;
    dsum += ev;
  }
  {
    float es = expf(lrelu(s1[m*NH + h] + dh));       // self loop
    unsigned int u = *(const unsigned int*)&xlB[(size_t)m*HD + 2*j];
    float lo, hi; up2(u, lo, hi);
    acc0 += es * lo; acc1 += es * hi;
    dsum += es;
  }
  float inv = 1.f / (dsum + 1e-16f);
  float v0 = acc0 * inv + gb1[2*j];
  float v1 = acc1 * inv + gb1[2*j + 1];
  g1s[2*j]     = v0 > 0.f ? v0 : expm1f(v0);         // ELU
  g1s[2*j + 1] = v1 > 0.f ? v1 : expm1f(v1);
  __syncthreads();
  // GAT2 pre: xl2 = g1 @ gW2 (all 64 lanes), scores fp32 pre-rounding
  float a = 0.f;
  for (int i = 0; i < HD; ++i) a += g1s[i] * gW2[i*GO + j];
  xl2B[(size_t)m*GO + j] = f2b(a);
  float pa = a * asr2[j], pb = a * adr2[j];
  #pragma unroll
  for (int off = 32; off > 0; off >>= 1) { pa += __shfl_xor(pa, off); pb += __shfl_xor(pb, off); }
  if (j == 0) { s2[m] = pa; d2[m] = pb; }
}

// ---------------- GAT2 gather + output projection (1 node/wave) -------------
__global__ __launch_bounds__(64) void k_g2(
    const int* __restrict__ row_ptr, const int* __restrict__ ssrc,
    const unsigned short* __restrict__ xl2B,
    const float* __restrict__ s2, const float* __restrict__ d2,
    const float* __restrict__ gb2, const float* __restrict__ oW, const float* __restrict__ ob,
    float* __restrict__ y)
{
  __shared__ float g2s[GO];
  int j = threadIdx.x, m = blockIdx.x;
  int b = m / NN, n = m - b * NN, boff = b * NN;
  float d2m = d2[m];
  int r0 = row_ptr[n], r1 = row_ptr[n+1];
  float acc = 0.f, dsum = 0.f;
  int e = r0;
  for (; e + 2 <= r1; e += 2) {
    int sa = ssrc[e] + boff, sb = ssrc[e+1] + boff;
    float ka = s2[sa], kb = s2[sb];
    unsigned short xa = xl2B[(size_t)sa*GO + j];
    unsigned short xb = xl2B[(size_t)sb*GO + j];
    float eva = expf(lrelu(ka + d2m));
    float evb = expf(lrelu(kb + d2m));
    acc  += eva * b2f(xa) + evb * b2f(xb);
    dsum += eva + evb;
  }
  if (e < r1) {
    int sa = ssrc[e] + boff;
    float ev = expf(lrelu(s2[sa] + d2m));
    acc  += ev * b2f(xl2B[(size_t)sa*GO + j]);
    dsum += ev;
  }
  float es = expf(lrelu(s2[m] + d2m));
  acc  += es * b2f(xl2B[(size_t)m*GO + j]);
  dsum += es;
  g2s[j] = acc / (dsum + 1e-16f) + gb2[j];
  __syncthreads();
  if (j < HR) {
    float a = ob[j];
    #pragma unroll
    for (int o2 = 0; o2 < GO; ++o2) a += g2s[o2] * oW[o2*HR + j];
    y[((size_t)b*HR + j)*NN + n] = a;
  }
}

// ---------------- launch ----------------------------------------------------
extern "C" void kernel_launch(void* const* d_in, const int* in_sizes, int n_in,
                              void* d_out, int out_size, void* d_ws, size_t ws_size,
                              hipStream_t stream)
{
  const int* ei = (const int*)d_in[2];
  const int* e0 = ei;
  const int* e1 = ei + EE;

  float* ws = (float*)d_ws;
  unsigned short* xl1B = (unsigned short*)ws;             // 40000*128 bf16
  unsigned short* xl2B = (unsigned short*)(ws + 2560000); // 40000*64 bf16
  float* ovl = ws + 3840000;          // overlap region (weights, then CSR)
  float* s1  = ws + 4200000;          // 40000*4
  float* d1  = ws + 4360000;          // 40000*4
  float* s2  = ws + 4520000;          // 40000
  float* d2  = ws + 4560000;          // 40000

  // Weight buffers live [prep, xform] in the overlap region.
  unsigned short* Mu    = (unsigned short*)ovl;          // 65536 bf16 frags
  unsigned short* Pw    = Mu + 65536;                    // 65536
  unsigned short* W1F   = Mu + 131072;                   // 32768
  unsigned short* W2F   = Mu + 163840;                   // 32768
  unsigned short* encWF = Mu + 196608;                   // 4096
  unsigned short* gW1F  = Mu + 200704;                   // 16384
  float* encBf = (float*)(Mu + 217088);
  float* fb1f  = encBf + 128;
  float* fb2f  = fb1f + 256;
  float* l1gf  = fb2f + 128;
  float* l1bf  = l1gf + 128;
  float* l2gf  = l1bf + 128;
  float* l2bf  = l2gf + 128;

  // CSR arrays live [hist, end] in the SAME overlap region (stream-serial).
  int* cnt     = (int*)ovl;           // 10000
  int* row_ptr = cnt + 16384;         // 10001
  int* cur     = cnt + 32768;         // 10000
  int* ssrc    = cnt + 49152;         // 160000

  k_prep<<<852, 256, 0, stream>>>(
      (const float*)d_in[5], (const float*)d_in[6], (const float*)d_in[7], (const float*)d_in[8],
      (const float*)d_in[3], (const float*)d_in[4], (const float*)d_in[11], (const float*)d_in[12],
      (const float*)d_in[13], (const float*)d_in[14], (const float*)d_in[9], (const float*)d_in[10],
      (const float*)d_in[15], (const float*)d_in[16], (const float*)d_in[17],
      Mu, Pw, W1F, W2F, encWF, gW1F,
      encBf, fb1f, fb2f, l1gf, l1bf, l2gf, l2bf);

  k_xform<<<MM/8, 256, 0, stream>>>(
      (const float*)d_in[0], (const float*)d_in[1],
      Mu, Pw, W1F, W2F, encWF, gW1F,
      encBf, fb1f, fb2f, l1gf, l1bf, l2gf, l2bf,
      (const float*)d_in[18], (const float*)d_in[19],
      xl1B, s1, d1);

  // CSR build (after xform: overlap region is free now)
  k_zero<<<(NN + 255)/256, 256, 0, stream>>>(cnt);
  k_hist<<<(EE + 255)/256, 256, 0, stream>>>(e1, cnt);
  k_scan<<<1, 1024, 0, stream>>>(cnt, row_ptr, cur);
  k_scatter<<<(EE + 255)/256, 256, 0, stream>>>(e0, e1, cur, ssrc);

  k_g1<<<MM, 64, 0, stream>>>(row_ptr, ssrc, xl1B, s1, d1,
      (const float*)d_in[20], (const float*)d_in[21],
      (const float*)d_in[22], (const float*)d_in[23],
      xl2B, s2, d2);

  k_g2<<<MM, 64, 0, stream>>>(row_ptr, ssrc, xl2B, s2, d2,
      (const float*)d_in[24], (const float*)d_in[25], (const float*)d_in[26],
      (float*)d_out);
}

// Round 14
// 240.233 us; speedup vs baseline: 7.7240x; 1.0199x over previous
//
#include <hip/hip_runtime.h>
#include <hip/hip_bf16.h>

#define DEV static __device__ __forceinline__

constexpr int BB = 4;        // batches
constexpr int TT = 12;       // timesteps
constexpr int NN = 10000;    // nodes per batch
constexpr int FD = 16;       // input features (8+8)
constexpr int HD = 128;      // hidden
constexpr int NH = 4;        // attn heads
constexpr int DH = 32;       // head dim
constexpr int FF = 256;      // ffn hidden
constexpr int GO = 64;       // gat2 out
constexpr int HR = 24;       // horizon
constexpr int EE = 160000;   // edges per batch
constexpr int MM = BB * NN;  // total nodes

typedef unsigned short bvec8 __attribute__((ext_vector_type(8)));
typedef unsigned short usvec4 __attribute__((ext_vector_type(4)));
typedef float fvec4 __attribute__((ext_vector_type(4)));
typedef short bs8 __attribute__((ext_vector_type(8)));      // MFMA bf16 frag (4 VGPR)

DEV float lrelu(float x) { return x >= 0.f ? x : 0.2f * x; }

DEV float b2f(unsigned short u) {
  union { unsigned int i; float f; } x; x.i = ((unsigned int)u) << 16; return x.f;
}
DEV unsigned short f2b(float f) {
  union { float f; unsigned int i; } x; x.f = f;
  unsigned int r = x.i + 0x7FFFu + ((x.i >> 16) & 1u);
  return (unsigned short)(r >> 16);
}
DEV void up2(unsigned int u, float& lo, float& hi) {
  union { unsigned int i; float f; } a, b;
  a.i = u << 16; b.i = u & 0xFFFF0000u;
  lo = a.f; hi = b.f;
}

DEV fvec4 mfma16(bs8 a, bs8 b, fvec4 c) {
  return __builtin_amdgcn_mfma_f32_16x16x32_bf16(a, b, c, 0, 0, 0);
}

// ---------------- prep: fold + re-layout ALL transformer weights (fp32 in) --
// Also zeroes the CSR histogram (tail blocks) -- saves a launch.
// MFMA B-fragment order: frag idx = ((nt*nK + kk)*64 + lane), element e:
//   B[k][n] with k = kk*32 + (lane>>4)*8 + e, n = nt*16 + (lane&15).
__global__ __launch_bounds__(256) void k_prep(
    const float* __restrict__ Wq, const float* __restrict__ Wk,
    const float* __restrict__ Wv, const float* __restrict__ Wo,
    const float* __restrict__ encW, const float* __restrict__ encB,
    const float* __restrict__ W1, const float* __restrict__ fb1,
    const float* __restrict__ W2, const float* __restrict__ fb2,
    const float* __restrict__ l1g, const float* __restrict__ l1b,
    const float* __restrict__ l2g, const float* __restrict__ l2b,
    const float* __restrict__ gW1,
    unsigned short* __restrict__ Mu, unsigned short* __restrict__ Pw,
    unsigned short* __restrict__ W1F, unsigned short* __restrict__ W2F,
    unsigned short* __restrict__ encWF, unsigned short* __restrict__ gW1F,
    float* __restrict__ encBf, float* __restrict__ fb1f, float* __restrict__ fb2f,
    float* __restrict__ l1gf, float* __restrict__ l1bf,
    float* __restrict__ l2gf, float* __restrict__ l2bf,
    int* __restrict__ cnt)
{
  int idx = blockIdx.x * 256 + threadIdx.x;      // 892*256 = 228352
  if (idx < 65536) {
    int e = idx & 7, lane = (idx >> 3) & 63, kk = (idx >> 9) & 3, nt = idx >> 11;
    int i = kk*32 + (lane >> 4)*8 + e;
    int q = nt*16 + (lane & 15);
    int h = q >> 7, c = q & 127;
    float a = 0.f;
    #pragma unroll 8
    for (int d = 0; d < DH; ++d)
      a += Wq[i*HD + h*DH + d] * Wk[c*HD + h*DH + d];
    Mu[idx] = f2b(a);
  } else if (idx < 131072) {
    int g2 = idx - 65536;
    int e = g2 & 7, lane = (g2 >> 3) & 63, kk = (g2 >> 9) & 15, nt = g2 >> 13;
    int q = kk*32 + (lane >> 4)*8 + e;
    int j = nt*16 + (lane & 15);
    int h = q >> 7, i = q & 127;
    float a = 0.f;
    #pragma unroll 8
    for (int d = 0; d < DH; ++d)
      a += Wv[i*HD + h*DH + d] * Wo[(h*DH + d)*HD + j];
    Pw[g2] = f2b(a);
  } else if (idx < 163840) {
    int g = idx - 131072;
    int e = g & 7, lane = (g >> 3) & 63, kk = (g >> 9) & 3, nt = g >> 11;
    int k = kk*32 + (lane >> 4)*8 + e;
    int n = nt*16 + (lane & 15);
    W1F[g] = f2b(W1[k*FF + n]);
  } else if (idx < 196608) {
    int g = idx - 163840;
    int e = g & 7, lane = (g >> 3) & 63, kk = (g >> 9) & 7, nt = g >> 12;
    int k = kk*32 + (lane >> 4)*8 + e;
    int n = nt*16 + (lane & 15);
    W2F[g] = f2b(W2[k*HD + n]);
  } else if (idx < 200704) {
    int g = idx - 196608;
    int e = g & 7, lane = (g >> 3) & 63, nt = g >> 9;
    int k = (lane >> 4)*8 + e;
    int n = nt*16 + (lane & 15);
    encWF[g] = (k < FD) ? f2b(encW[k*HD + n]) : (unsigned short)0;
  } else if (idx < 217088) {
    int g = idx - 200704;
    int e = g & 7, lane = (g >> 3) & 63, kk = (g >> 9) & 3, nt = g >> 11;
    int k = kk*32 + (lane >> 4)*8 + e;
    int n = nt*16 + (lane & 15);
    gW1F[g] = f2b(gW1[k*HD + n]);
  } else if (idx < 217216) { int t = idx - 217088; encBf[t] = encB[t]; }
  else if (idx < 217472)   { int t = idx - 217216; fb1f[t] = fb1[t]; }
  else if (idx < 217600)   { int t = idx - 217472; fb2f[t] = fb2[t]; }
  else if (idx < 217728)   { int t = idx - 217600; l1gf[t] = l1g[t]; }
  else if (idx < 217856)   { int t = idx - 217728; l1bf[t] = l1b[t]; }
  else if (idx < 217984)   { int t = idx - 217856; l2gf[t] = l2g[t]; }
  else if (idx < 218112)   { int t = idx - 217984; l2bf[t] = l2b[t]; }
  else { int t = idx - 218112; if (t < NN) cnt[t] = 0; }
}

// ---------------- fused transformer + GAT1-pre (8 nodes/block) --------------
// LDS 38912 B -> 4 blocks/CU. A-frag rows beyond the real data feed only
// DISCARDED D rows (aliased in-bounds). All A-frag row strides 16B multiples.
__global__ __launch_bounds__(256) void k_xform(
    const float* __restrict__ xh, const float* __restrict__ xc,
    const unsigned short* __restrict__ MuF, const unsigned short* __restrict__ PwF,
    const unsigned short* __restrict__ W1F, const unsigned short* __restrict__ W2F,
    const unsigned short* __restrict__ encWF, const unsigned short* __restrict__ gW1F,
    const float* __restrict__ encBf,
    const float* __restrict__ fb1f, const float* __restrict__ fb2f,
    const float* __restrict__ l1gf, const float* __restrict__ l1bf,
    const float* __restrict__ l2gf, const float* __restrict__ l2bf,
    const float* __restrict__ asrc, const float* __restrict__ adrc,
    unsigned short* __restrict__ xl1B, float* __restrict__ s1, float* __restrict__ d1)
{
  // big: hsB (ph1-5) then {r1F,h1s,h1B,f1B,r2F} (ph6-10)
  __shared__ __align__(16) char big[26112];
  __shared__ unsigned short hlastB[8*136];     // bf16 h_last (A-frags + residual)
  __shared__ float lgaw[8][NH][TT];
  __shared__ __align__(16) char regB[8704];    // xB -> usB -> wB -> xlF

  unsigned short* hsB = (unsigned short*)big;          // [(nl*12+t)][136]
  float* r1F = (float*)big;                            // [8][132] ph6-7
  float* h1s = (float*)(big + 4224);                   // [8][132] ph7-9
  unsigned short* h1B = (unsigned short*)(big + 8448); // [8][136] ph7-8
  float* r2F = (float*)(big + 8448);                   // [8][132] ph9-10 (over h1B)
  unsigned short* f1B = (unsigned short*)(big + 12672);// [8][264] ph8-9

  unsigned short* xB  = (unsigned short*)regB;         // [96][40]  ph0-1
  unsigned short* usB = (unsigned short*)regB;         // [8*4][136] ph2-3 (bf16 u)
  unsigned short* wB  = (unsigned short*)regB;         // [8][520]  ph5-6
  float* xlF = (float*)regB;                           // [8][128]  ph11

  const int tid  = threadIdx.x;
  const int w    = tid >> 6;
  const int lane = tid & 63;
  const int m0   = blockIdx.x * 8;
  const int arow = lane & 15, akg = lane >> 4;
  const int ar8  = arow & 7;                   // aliased A-row (rows 8-15 -> 0-7)

  // --- phase 0: load x -> xB bf16, rows = t*8+nl, K zero-padded 16..31 ---
  #pragma unroll
  for (int k = 0; k < 6; ++k) {
    int idx = tid + k*256;
    int f = idx & 15, rest = idx >> 4;
    int nl = rest & 7, t = rest >> 3;
    int m = m0 + nl, b = m / NN, n = m - b*NN;
    float v = (f < 8) ? xh[(((size_t)b*TT + t)*NN + n)*8 + f]
                      : xc[(((size_t)b*TT + t)*NN + n)*8 + (f - 8)];
    xB[(t*8 + nl)*40 + f] = f2b(v);
  }
  #pragma unroll
  for (int k = 0; k < 6; ++k) {
    int idx = tid + k*256;
    xB[(idx >> 4)*40 + 16 + (idx & 15)] = 0;
  }
  __syncthreads();

  // --- phase 1: encoder via MFMA (96x128 = 6 mt x 8 nt tiles) ---
  {
    const bs8* ef = (const bs8*)encWF;
    bs8 b0 = ef[(2*w + 0)*64 + lane];
    bs8 b1 = ef[(2*w + 1)*64 + lane];
    int drow = akg*4, dc = arow;
    int j0 = (2*w + 0)*16 + dc, j1 = (2*w + 1)*16 + dc;
    float eb0 = encBf[j0], eb1 = encBf[j1];
    fvec4 z4 = {0.f, 0.f, 0.f, 0.f};
    #pragma unroll
    for (int mt = 0; mt < 6; ++mt) {
      bs8 af = *(const bs8*)&xB[(mt*16 + arow)*40 + akg*8];
      fvec4 d0 = mfma16(af, b0, z4);
      fvec4 d1 = mfma16(af, b1, z4);
      #pragma unroll
      for (int reg = 0; reg < 4; ++reg) {
        int gr = mt*16 + drow + reg;
        int t = gr >> 3, nl = gr & 7;
        float v0 = d0[reg] + eb0, v1 = d1[reg] + eb1;
        unsigned short s0 = f2b(v0), s1v = f2b(v1);
        hsB[(nl*12 + t)*136 + j0] = s0;
        hsB[(nl*12 + t)*136 + j1] = s1v;
        if (t == TT-1) {
          hlastB[nl*136 + j0] = s0;
          hlastB[nl*136 + j1] = s1v;
        }
      }
    }
  }
  __syncthreads();                // xB dead

  // --- phase 2: u = h_last @ Mu via MFMA -> usB bf16 [nl*4+hd][136] ---
  {
    bs8 af[4];
    #pragma unroll
    for (int kk = 0; kk < 4; ++kk)
      af[kk] = *(const bs8*)&hlastB[ar8*136 + kk*32 + akg*8];
    const bs8* bp = (const bs8*)MuF;
    fvec4 acc[8];
    #pragma unroll
    for (int n8 = 0; n8 < 8; ++n8) {
      int nt = w*8 + n8;
      const bs8* bq = bp + nt*256 + lane;
      fvec4 a4 = {0.f, 0.f, 0.f, 0.f};
      #pragma unroll
      for (int kk = 0; kk < 4; ++kk)
        a4 = mfma16(af[kk], bq[kk*64], a4);
      acc[n8] = a4;
    }
    __syncthreads();              // xB fully read before usB overlay write
    if (lane < 32) {
      int drow = akg*4, dc = arow;
      #pragma unroll
      for (int n8 = 0; n8 < 8; ++n8) {
        int col = (w*8 + n8)*16 + dc, hd = col >> 7, c = col & 127;
        #pragma unroll
        for (int reg = 0; reg < 4; ++reg)
          usB[((drow + reg)*4 + hd)*136 + c] = f2b(acc[n8][reg]);
      }
    }
  }
  __syncthreads();

  // --- phase 3: logits via MFMA. Per node: D[t][hd] = Ht(12x128) @ u^T. ---
  {
    int ar12 = (arow < 12) ? arow : 0;
    #pragma unroll
    for (int r = 0; r < 2; ++r) {
      int nl = w*2 + r;
      const unsigned short* hb = &hsB[(nl*12 + ar12)*136 + akg*8];
      const unsigned short* ub = &usB[(nl*4 + (arow & 3))*136 + akg*8];
      fvec4 a4 = {0.f, 0.f, 0.f, 0.f};
      #pragma unroll
      for (int kk = 0; kk < 4; ++kk) {
        bs8 af = *(const bs8*)&hb[kk*32];
        bs8 bf = *(const bs8*)&ub[kk*32];
        a4 = mfma16(af, bf, a4);
      }
      if (arow < 4) {             // D col = hd
        #pragma unroll
        for (int reg = 0; reg < 4; ++reg) {
          int t = akg*4 + reg;
          if (t < TT) lgaw[nl][arow][t] = a4[reg] * 0.17677669529663687f;
        }
      }
    }
  }
  __syncthreads();

  // --- phase 4: softmax over t ---
  if (tid < 32) {
    int nl = tid >> 2, hd = tid & 3;
    float mx = -1e30f;
    #pragma unroll
    for (int t = 0; t < TT; ++t) mx = fmaxf(mx, lgaw[nl][hd][t]);
    float ex[TT], sm = 0.f;
    #pragma unroll
    for (int t = 0; t < TT; ++t) { ex[t] = expf(lgaw[nl][hd][t] - mx); sm += ex[t]; }
    float inv = 1.f / sm;
    #pragma unroll
    for (int t = 0; t < TT; ++t) lgaw[nl][hd][t] = ex[t] * inv;
  }
  __syncthreads();

  // --- phase 5: w_h = sum_t alpha*h_t -> wB bf16 (over usB) ---
  {
    int g = tid >> 7, j = tid & 127;
    #pragma unroll
    for (int r = 0; r < 4; ++r) {
      int nl = g*4 + r;
      float wacc[NH] = {0.f, 0.f, 0.f, 0.f};
      #pragma unroll
      for (int t = 0; t < TT; ++t) {
        float hv = b2f(hsB[(nl*12 + t)*136 + j]);
        #pragma unroll
        for (int hd = 0; hd < NH; ++hd) wacc[hd] += lgaw[nl][hd][t] * hv;
      }
      #pragma unroll
      for (int hd = 0; hd < NH; ++hd) wB[nl*520 + hd*128 + j] = f2b(wacc[hd]);
    }
  }
  __syncthreads();                // hsB dead after this point

  // --- phase 6: oa = w @ Pw via MFMA; r1 = h_last + oa -> r1F (over hsB) ---
  {
    fvec4 pacc0 = {0.f,0.f,0.f,0.f}, pacc1 = {0.f,0.f,0.f,0.f};
    const bs8* bp = (const bs8*)PwF;
    const bs8* bq0 = bp + (w*2 + 0)*1024 + lane;
    const bs8* bq1 = bp + (w*2 + 1)*1024 + lane;
    #pragma unroll
    for (int kk = 0; kk < 16; ++kk) {
      bs8 af = *(const bs8*)&wB[ar8*520 + kk*32 + akg*8];
      pacc0 = mfma16(af, bq0[kk*64], pacc0);
      pacc1 = mfma16(af, bq1[kk*64], pacc1);
    }
    __syncthreads();              // wB fully read before r1F overlay write
    if (lane < 32) {
      int drow = akg*4, dc = arow;
      #pragma unroll
      for (int reg = 0; reg < 4; ++reg) {
        int nd = drow + reg;
        int c0 = (w*2 + 0)*16 + dc;
        int c1 = (w*2 + 1)*16 + dc;
        r1F[nd*132 + c0] = b2f(hlastB[nd*136 + c0]) + pacc0[reg];
        r1F[nd*132 + c1] = b2f(hlastB[nd*136 + c1]) + pacc1[reg];
      }
    }
  }
  __syncthreads();

  // --- phase 7: LN1 -> h1s fp32 + h1B bf16 ---
  {
    int nd = tid >> 5, l32 = tid & 31;
    float v[4], s = 0.f, q = 0.f;
    #pragma unroll
    for (int k = 0; k < 4; ++k) {
      v[k] = r1F[nd*132 + l32 + k*32];
      s += v[k]; q += v[k]*v[k];
    }
    #pragma unroll
    for (int off = 16; off > 0; off >>= 1) { s += __shfl_xor(s, off); q += __shfl_xor(q, off); }
    float mu = s*(1.f/128.f), var = q*(1.f/128.f) - mu*mu, rs = rsqrtf(var + 1e-5f);
    #pragma unroll
    for (int k = 0; k < 4; ++k) {
      int c = l32 + k*32;
      float hv = (v[k] - mu)*rs*l1gf[c] + l1bf[c];
      h1s[nd*132 + c] = hv;
      h1B[nd*136 + c] = f2b(hv);
    }
  }
  __syncthreads();

  // --- phase 8: FFN1 via MFMA (K=128, N=256), relu+bias fused -> f1B bf16 ---
  {
    bs8 af[4];
    #pragma unroll
    for (int kk = 0; kk < 4; ++kk)
      af[kk] = *(const bs8*)&h1B[ar8*136 + kk*32 + akg*8];
    const bs8* bp = (const bs8*)W1F;
    #pragma unroll
    for (int n4 = 0; n4 < 4; ++n4) {
      int nt = w*4 + n4;
      const bs8* bq = bp + nt*256 + lane;
      fvec4 a4 = {0.f, 0.f, 0.f, 0.f};
      #pragma unroll
      for (int kk = 0; kk < 4; ++kk)
        a4 = mfma16(af[kk], bq[kk*64], a4);
      if (lane < 32) {
        int drow = akg*4, dc = arow;
        int n = nt*16 + dc;
        float bias = fb1f[n];
        #pragma unroll
        for (int reg = 0; reg < 4; ++reg)
          f1B[(drow + reg)*264 + n] = f2b(fmaxf(a4[reg] + bias, 0.f));
      }
    }
  }
  __syncthreads();

  // --- phase 9: FFN2 via MFMA (K=256, N=128) + residual -> r2F (over h1B) ---
  {
    const bs8* bp = (const bs8*)W2F;
    #pragma unroll
    for (int n2 = 0; n2 < 2; ++n2) {
      int nt = w*2 + n2;
      const bs8* bq = bp + nt*512 + lane;
      fvec4 a4 = {0.f, 0.f, 0.f, 0.f};
      #pragma unroll
      for (int kk = 0; kk < 8; ++kk) {
        bs8 af = *(const bs8*)&f1B[ar8*264 + kk*32 + akg*8];
        a4 = mfma16(af, bq[kk*64], a4);
      }
      if (lane < 32) {
        int drow = akg*4, dc = arow;
        int c = nt*16 + dc;
        float fb2v = fb2f[c];
        #pragma unroll
        for (int reg = 0; reg < 4; ++reg) {
          int nd = drow + reg;
          r2F[nd*132 + c] = h1s[nd*132 + c] + fb2v + a4[reg];
        }
      }
    }
  }
  __syncthreads();

  // --- phase 10: LN2 -> hlastB bf16 (A-frags for GAT1 projection) ---
  {
    int nd = tid >> 5, l32 = tid & 31;
    float v[4], s = 0.f, q = 0.f;
    #pragma unroll
    for (int k = 0; k < 4; ++k) {
      v[k] = r2F[nd*132 + l32 + k*32];
      s += v[k]; q += v[k]*v[k];
    }
    #pragma unroll
    for (int off = 16; off > 0; off >>= 1) { s += __shfl_xor(s, off); q += __shfl_xor(q, off); }
    float mu = s*(1.f/128.f), var = q*(1.f/128.f) - mu*mu, rs = rsqrtf(var + 1e-5f);
    #pragma unroll
    for (int k = 0; k < 4; ++k) {
      int c = l32 + k*32;
      hlastB[nd*136 + c] = f2b((v[k] - mu)*rs*l2gf[c] + l2bf[c]);
    }
  }
  __syncthreads();

  // --- phase 11: xl1 = hlast @ gW1 via MFMA; s1/d1 reduce; globals out ---
  {
    bs8 af[4];
    #pragma unroll
    for (int kk = 0; kk < 4; ++kk)
      af[kk] = *(const bs8*)&hlastB[ar8*136 + kk*32 + akg*8];
    const bs8* bp = (const bs8*)gW1F;
    #pragma unroll
    for (int n2 = 0; n2 < 2; ++n2) {
      int nt = w*2 + n2;
      const bs8* bq = bp + nt*256 + lane;
      fvec4 a4 = {0.f, 0.f, 0.f, 0.f};
      #pragma unroll
      for (int kk = 0; kk < 4; ++kk)
        a4 = mfma16(af[kk], bq[kk*64], a4);
      if (lane < 32) {
        int drow = akg*4, dc = arow;
        int c = nt*16 + dc;
        #pragma unroll
        for (int reg = 0; reg < 4; ++reg)
          xlF[(drow + reg)*128 + c] = a4[reg];
      }
    }
  }
  __syncthreads();
  {
    // xl1 write as packed bf16 (ushort4 = 8B/lane, coalesced)
    fvec4 vv = ((const fvec4*)xlF)[tid];
    usvec4 sv;
    #pragma unroll
    for (int k = 0; k < 4; ++k) sv[k] = f2b(vv[k]);
    *(usvec4*)&xl1B[(size_t)m0*HD + tid*4] = sv;
    // s1/d1 from fp32 xlF (scores stay full precision)
    int nd = tid >> 5, l32 = tid & 31;
    float pa[4], pb[4];
    #pragma unroll
    for (int k = 0; k < 4; ++k) {
      float xv = xlF[nd*128 + l32 + k*32];
      pa[k] = xv * asrc[l32 + k*32];
      pb[k] = xv * adrc[l32 + k*32];
    }
    #pragma unroll
    for (int off = 16; off > 0; off >>= 1) {
      #pragma unroll
      for (int k = 0; k < 4; ++k) {
        pa[k] += __shfl_xor(pa[k], off);
        pb[k] += __shfl_xor(pb[k], off);
      }
    }
    if (l32 == 0) {
      int m = m0 + nd;
      #pragma unroll
      for (int k = 0; k < 4; ++k) {
        s1[m*NH + k] = pa[k];
        d1[m*NH + k] = pb[k];
      }
    }
  }
}

// ---------------- CSR build (batch-shared; cnt zeroed by k_prep) ------------
__global__ __launch_bounds__(256) void k_hist(const int* __restrict__ e1,
                                              int* __restrict__ cnt)
{
  int i = blockIdx.x * 256 + threadIdx.x;
  if (i < EE) atomicAdd(&cnt[e1[i]], 1);
}

__global__ __launch_bounds__(1024) void k_scan(const int* __restrict__ cnt,
                                               int* __restrict__ row_ptr,
                                               int* __restrict__ cur)
{
  __shared__ int sm[1024];
  int tid = threadIdx.x;
  int base = tid * 10;
  int loc[10];
  int s = 0;
  #pragma unroll
  for (int k = 0; k < 10; ++k) {
    int idx = base + k;
    int v = (idx < NN) ? cnt[idx] : 0;
    loc[k] = s;
    s += v;
  }
  sm[tid] = s;
  __syncthreads();
  for (int off = 1; off < 1024; off <<= 1) {
    int t = (tid >= off) ? sm[tid - off] : 0;
    __syncthreads();
    sm[tid] += t;
    __syncthreads();
  }
  int segbase = sm[tid] - s;
  #pragma unroll
  for (int k = 0; k < 10; ++k) {
    int idx = base + k;
    if (idx < NN) { int o = segbase + loc[k]; row_ptr[idx] = o; cur[idx] = o; }
  }
  if (tid == 1023) row_ptr[NN] = sm[1023];
}

__global__ __launch_bounds__(256) void k_scatter(const int* __restrict__ e0,
                                                 const int* __restrict__ e1,
                                                 int* __restrict__ cur,
                                                 int* __restrict__ ssrc)
{
  int i = blockIdx.x * 256 + threadIdx.x;
  if (i >= EE) return;
  int pos = atomicAdd(&cur[e1[i]], 1);
  ssrc[pos] = e0[i];
}

// ---------------- GAT1 gather + GAT2 pre (1 node/wave, 64 thr) --------------
// Single wave per node; edge loop unrolled x4 for memory-level parallelism.
__global__ __launch_bounds__(64) void k_g1(
    const int* __restrict__ row_ptr, const int* __restrict__ ssrc,
    const unsigned short* __restrict__ xlB,
    const float* __restrict__ s1, const float* __restrict__ d1,
    const float* __restrict__ gb1, const float* __restrict__ gW2,
    const float* __restrict__ asr2, const float* __restrict__ adr2,
    unsigned short* __restrict__ xl2B, float* __restrict__ s2, float* __restrict__ d2)
{
  __shared__ float g1s[HD];
  int j = threadIdx.x, m = blockIdx.x, h = j >> 4;   // ch 2j -> head (2j)>>5 = j>>4
  int b = m / NN, n = m - b * NN, boff = b * NN;
  float dh = d1[m*NH + h];
  int r0 = row_ptr[n], r1 = row_ptr[n+1];
  float acc0 = 0.f, acc1 = 0.f, dsum = 0.f;
  int e = r0;
  for (; e + 4 <= r1; e += 4) {
    int sa = ssrc[e]   + boff, sb = ssrc[e+1] + boff;
    int sc = ssrc[e+2] + boff, sd = ssrc[e+3] + boff;
    float ka = s1[sa*NH + h], kb = s1[sb*NH + h];
    float kc = s1[sc*NH + h], kd = s1[sd*NH + h];
    unsigned int ua = *(const unsigned int*)&xlB[(size_t)sa*HD + 2*j];
    unsigned int ub = *(const unsigned int*)&xlB[(size_t)sb*HD + 2*j];
    unsigned int uc = *(const unsigned int*)&xlB[(size_t)sc*HD + 2*j];
    unsigned int ud = *(const unsigned int*)&xlB[(size_t)sd*HD + 2*j];
    float eva = expf(lrelu(ka + dh));
    float evb = expf(lrelu(kb + dh));
    float evc = expf(lrelu(kc + dh));
    float evd = expf(lrelu(kd + dh));
    float lo, hi;
    up2(ua, lo, hi); acc0 += eva * lo; acc1 += eva * hi;
    up2(ub, lo, hi); acc0 += evb * lo; acc1 += evb * hi;
    up2(uc, lo, hi); acc0 += evc * lo; acc1 += evc * hi;
    up2(ud, lo, hi); acc0 += evd * lo; acc1 += evd * hi;
    dsum += (eva + evb) + (evc + evd);
  }
  for (; e < r1; ++e) {
    int sa = ssrc[e] + boff;
    float ev = expf(lrelu(s1[sa*NH + h] + dh));
    unsigned int u = *(const unsigned int*)&xlB[(size_t)sa*HD + 2*j];
    float lo, hi; up2(u, lo, hi);
    acc0 += ev * lo; acc1 += ev * hi;
    dsum += ev;
  }
  {
    float es = expf(lrelu(s1[m*NH + h] + dh));       // self loop
    unsigned int u = *(const unsigned int*)&xlB[(size_t)m*HD + 2*j];
    float lo, hi; up2(u, lo, hi);
    acc0 += es * lo; acc1 += es * hi;
    dsum += es;
  }
  float inv = 1.f / (dsum + 1e-16f);
  float v0 = acc0 * inv + gb1[2*j];
  float v1 = acc1 * inv + gb1[2*j + 1];
  g1s[2*j]     = v0 > 0.f ? v0 : expm1f(v0);         // ELU
  g1s[2*j + 1] = v1 > 0.f ? v1 : expm1f(v1);
  __syncthreads();
  // GAT2 pre: xl2 = g1 @ gW2 (all 64 lanes), scores fp32 pre-rounding
  float a = 0.f;
  for (int i = 0; i < HD; ++i) a += g1s[i] * gW2[i*GO + j];
  xl2B[(size_t)m*GO + j] = f2b(a);
  float pa = a * asr2[j], pb = a * adr2[j];
  #pragma unroll
  for (int off = 32; off > 0; off >>= 1) { pa += __shfl_xor(pa, off); pb += __shfl_xor(pb, off); }
  if (j == 0) { s2[m] = pa; d2[m] = pb; }
}

// ---------------- GAT2 gather + output projection (1 node/wave) -------------
__global__ __launch_bounds__(64) void k_g2(
    const int* __restrict__ row_ptr, const int* __restrict__ ssrc,
    const unsigned short* __restrict__ xl2B,
    const float* __restrict__ s2, const float* __restrict__ d2,
    const float* __restrict__ gb2, const float* __restrict__ oW, const float* __restrict__ ob,
    float* __restrict__ y)
{
  __shared__ float g2s[GO];
  int j = threadIdx.x, m = blockIdx.x;
  int b = m / NN, n = m - b * NN, boff = b * NN;
  float d2m = d2[m];
  int r0 = row_ptr[n], r1 = row_ptr[n+1];
  float acc = 0.f, dsum = 0.f;
  int e = r0;
  for (; e + 4 <= r1; e += 4) {
    int sa = ssrc[e]   + boff, sb = ssrc[e+1] + boff;
    int sc = ssrc[e+2] + boff, sd = ssrc[e+3] + boff;
    float ka = s2[sa], kb = s2[sb], kc = s2[sc], kd = s2[sd];
    unsigned short xa = xl2B[(size_t)sa*GO + j];
    unsigned short xb = xl2B[(size_t)sb*GO + j];
    unsigned short xc2 = xl2B[(size_t)sc*GO + j];
    unsigned short xd = xl2B[(size_t)sd*GO + j];
    float eva = expf(lrelu(ka + d2m));
    float evb = expf(lrelu(kb + d2m));
    float evc = expf(lrelu(kc + d2m));
    float evd = expf(lrelu(kd + d2m));
    acc  += (eva * b2f(xa) + evb * b2f(xb)) + (evc * b2f(xc2) + evd * b2f(xd));
    dsum += (eva + evb) + (evc + evd);
  }
  for (; e < r1; ++e) {
    int sa = ssrc[e] + boff;
    float ev = expf(lrelu(s2[sa] + d2m));
    acc  += ev * b2f(xl2B[(size_t)sa*GO + j]);
    dsum += ev;
  }
  float es = expf(lrelu(s2[m] + d2m));
  acc  += es * b2f(xl2B[(size_t)m*GO + j]);
  dsum += es;
  g2s[j] = acc / (dsum + 1e-16f) + gb2[j];
  __syncthreads();
  if (j < HR) {
    float a = ob[j];
    #pragma unroll
    for (int o2 = 0; o2 < GO; ++o2) a += g2s[o2] * oW[o2*HR + j];
    y[((size_t)b*HR + j)*NN + n] = a;
  }
}

// ---------------- launch ----------------------------------------------------
extern "C" void kernel_launch(void* const* d_in, const int* in_sizes, int n_in,
                              void* d_out, int out_size, void* d_ws, size_t ws_size,
                              hipStream_t stream)
{
  const int* ei = (const int*)d_in[2];
  const int* e0 = ei;
  const int* e1 = ei + EE;

  float* ws = (float*)d_ws;
  unsigned short* xl1B = (unsigned short*)ws;             // 40000*128 bf16
  unsigned short* xl2B = (unsigned short*)(ws + 2560000); // 40000*64 bf16
  float* ovl = ws + 3840000;          // weights region
  float* s1  = ws + 4200000;          // 40000*4
  float* d1  = ws + 4360000;          // 40000*4
  float* s2  = ws + 4520000;          // 40000
  float* d2  = ws + 4560000;          // 40000
  // CSR region (dedicated; no aliasing -> cnt zeroed inside k_prep)
  int* cnt     = (int*)(ws + 4600000);   // 10000
  int* row_ptr = cnt + 16384;            // 10001
  int* cur     = cnt + 32768;            // 10000
  int* ssrc    = cnt + 49152;            // 160000

  // Weight buffers (fragment order) in ovl.
  unsigned short* Mu    = (unsigned short*)ovl;          // 65536 bf16 frags
  unsigned short* Pw    = Mu + 65536;                    // 65536
  unsigned short* W1F   = Mu + 131072;                   // 32768
  unsigned short* W2F   = Mu + 163840;                   // 32768
  unsigned short* encWF = Mu + 196608;                   // 4096
  unsigned short* gW1F  = Mu + 200704;                   // 16384
  float* encBf = (float*)(Mu + 217088);
  float* fb1f  = encBf + 128;
  float* fb2f  = fb1f + 256;
  float* l1gf  = fb2f + 128;
  float* l1bf  = l1gf + 128;
  float* l2gf  = l1bf + 128;
  float* l2bf  = l2gf + 128;

  k_prep<<<892, 256, 0, stream>>>(
      (const float*)d_in[5], (const float*)d_in[6], (const float*)d_in[7], (const float*)d_in[8],
      (const float*)d_in[3], (const float*)d_in[4], (const float*)d_in[11], (const float*)d_in[12],
      (const float*)d_in[13], (const float*)d_in[14], (const float*)d_in[9], (const float*)d_in[10],
      (const float*)d_in[15], (const float*)d_in[16], (const float*)d_in[17],
      Mu, Pw, W1F, W2F, encWF, gW1F,
      encBf, fb1f, fb2f, l1gf, l1bf, l2gf, l2bf, cnt);

  k_hist<<<(EE + 255)/256, 256, 0, stream>>>(e1, cnt);
  k_scan<<<1, 1024, 0, stream>>>(cnt, row_ptr, cur);
  k_scatter<<<(EE + 255)/256, 256, 0, stream>>>(e0, e1, cur, ssrc);

  k_xform<<<MM/8, 256, 0, stream>>>(
      (const float*)d_in[0], (const float*)d_in[1],
      Mu, Pw, W1F, W2F, encWF, gW1F,
      encBf, fb1f, fb2f, l1gf, l1bf, l2gf, l2bf,
      (const float*)d_in[18], (const float*)d_in[19],
      xl1B, s1, d1);

  k_g1<<<MM, 64, 0, stream>>>(row_ptr, ssrc, xl1B, s1, d1,
      (const float*)d_in[20], (const float*)d_in[21],
      (const float*)d_in[22], (const float*)d_in[23],
      xl2B, s2, d2);

  k_g2<<<MM, 64, 0, stream>>>(row_ptr, ssrc, xl2B, s2, d2,
      (const float*)d_in[24], (const float*)d_in[25], (const float*)d_in[26],
      (float*)d_out);
}